// Round 1
// baseline (1015.866 us; speedup 1.0000x reference)
//
#include <hip/hip_runtime.h>
#include <math.h>

#define BATCH 16
#define NPTS  1024
#define KNN   20
#define BNEPS 1e-5f

// ---------------------------------------------------------------- transpose
__global__ void transpose_x(const float* __restrict__ x, float* __restrict__ xt) {
  int i = blockIdx.x * 256 + threadIdx.x;
  if (i >= BATCH * NPTS * 3) return;
  int b = i / (NPTS * 3);
  int r = i - b * (NPTS * 3);
  int n = r / 3;
  int c = r - n * 3;
  xt[i] = x[(b * 3 + c) * NPTS + n];
}

// ---------------------------------------------------------------- xx = ||x||^2
__global__ void compute_xx(const float* __restrict__ feat, float* __restrict__ xx, int C) {
  int i = blockIdx.x * 256 + threadIdx.x;
  if (i >= BATCH * NPTS) return;
  const float* f = feat + (size_t)i * C;
  float s = 0.f;
  for (int c = 0; c < C; c++) s = fmaf(f[c], f[c], s);
  xx[i] = s;
}

// ---------------------------------------------------------------- pd = 2*X.X^T - xx_n - xx_m
// grid (16,16,BATCH), block 256
__global__ void gram_pd(const float* __restrict__ feat, const float* __restrict__ xx,
                        float* __restrict__ pd, int C) {
  __shared__ float As[16][68];
  __shared__ float Bs[16][68];
  int b = blockIdx.z;
  const float* F  = feat + (size_t)b * NPTS * C;
  const float* xb = xx + b * NPTS;
  int m0 = blockIdx.y * 64, n0 = blockIdx.x * 64;
  int tid = threadIdx.x, tx = tid & 15, ty = tid >> 4;
  float acc[4][4] = {};
  for (int k0 = 0; k0 < C; k0 += 16) {
#pragma unroll
    for (int l = 0; l < 4; l++) {
      int e = tid + l * 256;
      int m = e >> 4, k = e & 15;
      float av = 0.f, bv = 0.f;
      if (k0 + k < C) {
        av = F[(size_t)(m0 + m) * C + k0 + k];
        bv = F[(size_t)(n0 + m) * C + k0 + k];
      }
      As[k][m] = av;
      Bs[k][m] = bv;
    }
    __syncthreads();
#pragma unroll
    for (int kk = 0; kk < 16; kk++) {
      float4 ra = *(const float4*)&As[kk][ty * 4];
      float4 rb = *(const float4*)&Bs[kk][tx * 4];
      float a[4] = {ra.x, ra.y, ra.z, ra.w};
      float w[4] = {rb.x, rb.y, rb.z, rb.w};
#pragma unroll
      for (int i2 = 0; i2 < 4; i2++)
#pragma unroll
        for (int j = 0; j < 4; j++)
          acc[i2][j] = fmaf(a[i2], w[j], acc[i2][j]);
    }
    __syncthreads();
  }
#pragma unroll
  for (int i2 = 0; i2 < 4; i2++) {
    int m = m0 + ty * 4 + i2;
    float xm = xb[m];
#pragma unroll
    for (int j = 0; j < 4; j++) {
      int n = n0 + tx * 4 + j;
      pd[((size_t)b * NPTS + m) * NPTS + n] = fmaf(2.f, acc[i2][j], -xm) - xb[n];
    }
  }
}

// ---------------------------------------------------------------- top-20 per row (wave per row)
__global__ void topk20(const float* __restrict__ pd, int* __restrict__ idx) {
  int tid = threadIdx.x, lane = tid & 63, w = tid >> 6;
  int row = blockIdx.x * 4 + w;  // 0..16383
  const float* p = pd + (size_t)row * NPTS;
  float v[16];
#pragma unroll
  for (int s = 0; s < 16; s++) v[s] = p[lane + s * 64];
  int* o = idx + row * KNN;
  for (int j = 0; j < KNN; j++) {
    float bv = v[0];
    int bs = 0;
#pragma unroll
    for (int s = 1; s < 16; s++)
      if (v[s] > bv) { bv = v[s]; bs = s; }
    int bi = bs * 64 + lane;
#pragma unroll
    for (int off = 32; off; off >>= 1) {
      float ov = __shfl_xor(bv, off);
      int   oi = __shfl_xor(bi, off);
      if (ov > bv || (ov == bv && oi < bi)) { bv = ov; bi = oi; }
    }
    if (lane == 0) o[j] = bi;
    if ((bi & 63) == lane) v[bi >> 6] = -INFINITY;
  }
}

// ---------------------------------------------------------------- W2 = [wl ; wr-wl]
__global__ void prep_w2(const float* __restrict__ w, float* __restrict__ W2, int C, int O) {
  int i = blockIdx.x * 256 + threadIdx.x;
  if (i >= O * C) return;
  int o = i / C, c = i - o * C;
  float wl = w[o * 2 * C + c];
  float wr = w[o * 2 * C + C + c];
  W2[(size_t)o * C + c]       = wl;
  W2[(size_t)(O + o) * C + c] = wr - wl;
}

// ---------------------------------------------------------------- GEMM: feat[16384,K] @ W2[2O,K]^T
// grid (2O/64, 256), block 256. cols < O -> Ab, cols >= O -> Bb
__global__ void gemm_ab(const float* __restrict__ feat, const float* __restrict__ W2,
                        float* __restrict__ Ab, float* __restrict__ Bb, int K, int O) {
  __shared__ float As[16][68];
  __shared__ float Ws[16][68];
  int n0 = blockIdx.x * 64, m0 = blockIdx.y * 64;
  int tid = threadIdx.x, tx = tid & 15, ty = tid >> 4;
  float acc[4][4] = {};
  for (int k0 = 0; k0 < K; k0 += 16) {
#pragma unroll
    for (int l = 0; l < 4; l++) {
      int e = tid + l * 256;
      int m = e >> 4, k = e & 15;
      As[k][m] = (k0 + k < K) ? feat[(size_t)(m0 + m) * K + k0 + k] : 0.f;
      Ws[k][m] = (k0 + k < K) ? W2[(size_t)(n0 + m) * K + k0 + k] : 0.f;
    }
    __syncthreads();
#pragma unroll
    for (int kk = 0; kk < 16; kk++) {
      float4 ra = *(const float4*)&As[kk][ty * 4];
      float4 rb = *(const float4*)&Ws[kk][tx * 4];
      float a[4] = {ra.x, ra.y, ra.z, ra.w};
      float w[4] = {rb.x, rb.y, rb.z, rb.w};
#pragma unroll
      for (int i2 = 0; i2 < 4; i2++)
#pragma unroll
        for (int j = 0; j < 4; j++)
          acc[i2][j] = fmaf(a[i2], w[j], acc[i2][j]);
    }
    __syncthreads();
  }
#pragma unroll
  for (int i2 = 0; i2 < 4; i2++) {
    int row = m0 + ty * 4 + i2;
#pragma unroll
    for (int j = 0; j < 4; j++) {
      int col = n0 + tx * 4 + j;
      if (col < O) Ab[(size_t)row * O + col] = acc[i2][j];
      else         Bb[(size_t)row * O + (col - O)] = acc[i2][j];
    }
  }
}

// ---------------------------------------------------------------- gather + max_k + BN + LReLU
__global__ void gather_max_bn(const float* __restrict__ Ab, const float* __restrict__ Bb,
                              const int* __restrict__ idx, const float* __restrict__ bnp,
                              float* __restrict__ out, int O) {
  int tid = threadIdx.x;
  int npb = 256 / O;
  int local_n = tid / O;
  int o = tid - local_n * O;
  int pt = blockIdx.x * npb + local_n;  // 0..16383
  int b = pt >> 10;
  const int* ix = idx + pt * KNN;
  const float* Abase = Ab + ((size_t)(b << 10)) * O;
  float m = -INFINITY;
#pragma unroll 4
  for (int k = 0; k < KNN; k++)
    m = fmaxf(m, Abase[(size_t)ix[k] * O + o]);
  float h = m + Bb[(size_t)pt * O + o];
  float g = bnp[o], bt = bnp[O + o], mu = bnp[2 * O + o], va = bnp[3 * O + o];
  float y = g * (h - mu) * rsqrtf(va + BNEPS) + bt;
  out[(size_t)pt * O + o] = y >= 0.f ? y : 0.2f * y;
}

// ---------------------------------------------------------------- cat @ w5^T + BN5 + LReLU
// grid (16, 256), block 256
__global__ void gemm_w5k(const float* __restrict__ h1, const float* __restrict__ h2,
                         const float* __restrict__ h3, const float* __restrict__ h4,
                         const float* __restrict__ w5, const float* __restrict__ bn5,
                         float* __restrict__ h5) {
  __shared__ float As[16][68];
  __shared__ float Ws[16][68];
  int n0 = blockIdx.x * 64, m0 = blockIdx.y * 64;
  int tid = threadIdx.x, tx = tid & 15, ty = tid >> 4;
  float acc[4][4] = {};
  for (int k0 = 0; k0 < 512; k0 += 16) {
#pragma unroll
    for (int l = 0; l < 4; l++) {
      int e = tid + l * 256;
      int m = e >> 4, k = e & 15;
      int c = k0 + k;
      int row = m0 + m;
      float av;
      if (c < 64)       av = h1[(size_t)row * 64 + c];
      else if (c < 128) av = h2[(size_t)row * 64 + (c - 64)];
      else if (c < 256) av = h3[(size_t)row * 128 + (c - 128)];
      else              av = h4[(size_t)row * 256 + (c - 256)];
      As[k][m] = av;
      Ws[k][m] = w5[(size_t)(n0 + m) * 512 + c];
    }
    __syncthreads();
#pragma unroll
    for (int kk = 0; kk < 16; kk++) {
      float4 ra = *(const float4*)&As[kk][ty * 4];
      float4 rb = *(const float4*)&Ws[kk][tx * 4];
      float a[4] = {ra.x, ra.y, ra.z, ra.w};
      float w[4] = {rb.x, rb.y, rb.z, rb.w};
#pragma unroll
      for (int i2 = 0; i2 < 4; i2++)
#pragma unroll
        for (int j = 0; j < 4; j++)
          acc[i2][j] = fmaf(a[i2], w[j], acc[i2][j]);
    }
    __syncthreads();
  }
#pragma unroll
  for (int i2 = 0; i2 < 4; i2++) {
    int row = m0 + ty * 4 + i2;
#pragma unroll
    for (int j = 0; j < 4; j++) {
      int col = n0 + tx * 4 + j;
      float g = bn5[col], bt = bn5[1024 + col], mu = bn5[2048 + col], va = bn5[3072 + col];
      float y = g * (acc[i2][j] - mu) * rsqrtf(va + BNEPS) + bt;
      h5[(size_t)row * 1024 + col] = y >= 0.f ? y : 0.2f * y;
    }
  }
}

// ---------------------------------------------------------------- max + mean pool over N
// grid (4, BATCH), block 256
__global__ void pool_kernel(const float* __restrict__ h5, float* __restrict__ pooled) {
  int c = blockIdx.x * 256 + threadIdx.x;  // 0..1023
  int b = blockIdx.y;
  const float* p = h5 + (size_t)b * NPTS * 1024 + c;
  float mx = -INFINITY, sm = 0.f;
  for (int n = 0; n < NPTS; n++) {
    float v = p[(size_t)n * 1024];
    mx = fmaxf(mx, v);
    sm += v;
  }
  pooled[b * 2048 + c] = mx;
  pooled[b * 2048 + 1024 + c] = sm * (1.f / 1024.f);
}

// ---------------------------------------------------------------- FC: wave per output
// act=1: bn(s + bias) then lrelu ; act=0: s + bias
__global__ void fc_kernel(const float* __restrict__ in, const float* __restrict__ w,
                          const float* __restrict__ bias, const float* __restrict__ bnp,
                          float* __restrict__ out, int Cin, int Cout, int act) {
  int g = blockIdx.x * blockDim.x + threadIdx.x;
  int wid = g >> 6, lane = g & 63;
  if (wid >= BATCH * Cout) return;
  int b = wid / Cout, o = wid - b * Cout;
  const float* xp = in + (size_t)b * Cin;
  const float* wp = w + (size_t)o * Cin;
  float s = 0.f;
  for (int c = lane; c < Cin; c += 64) s = fmaf(xp[c], wp[c], s);
#pragma unroll
  for (int off = 32; off; off >>= 1) s += __shfl_xor(s, off);
  if (lane == 0) {
    if (bias) s += bias[o];
    if (act) {
      float gm = bnp[o], bt = bnp[Cout + o], mu = bnp[2 * Cout + o], va = bnp[3 * Cout + o];
      s = gm * (s - mu) * rsqrtf(va + BNEPS) + bt;
      s = s >= 0.f ? s : 0.2f * s;
    }
    out[wid] = s;
  }
}

// ================================================================ launch
extern "C" void kernel_launch(void* const* d_in, const int* in_sizes, int n_in,
                              void* d_out, int out_size, void* d_ws, size_t ws_size,
                              hipStream_t stream) {
  const float* x   = (const float*)d_in[0];
  const float* w1  = (const float*)d_in[1];
  const float* w2  = (const float*)d_in[2];
  const float* w3  = (const float*)d_in[3];
  const float* w4  = (const float*)d_in[4];
  const float* w5  = (const float*)d_in[5];
  const float* bn1 = (const float*)d_in[6];
  const float* bn2 = (const float*)d_in[7];
  const float* bn3 = (const float*)d_in[8];
  const float* bn4 = (const float*)d_in[9];
  const float* bn5 = (const float*)d_in[10];
  const float* bn6 = (const float*)d_in[11];
  const float* bn7 = (const float*)d_in[12];
  const float* l1w = (const float*)d_in[13];
  const float* l2w = (const float*)d_in[14];
  const float* l2b = (const float*)d_in[15];
  const float* l3w = (const float*)d_in[16];
  const float* l3b = (const float*)d_in[17];
  float* out = (float*)d_out;

  float* ws = (float*)d_ws;
  size_t off = 0;
  float* xt = ws + off;  off += (size_t)BATCH * NPTS * 3;      // 49152
  float* xx = ws + off;  off += (size_t)BATCH * NPTS;          // 16384
  float* W2 = ws + off;  off += (size_t)512 * 128;             // max 2O*C
  float* Ab = ws + off;  off += (size_t)BATCH * NPTS * 256;
  float* Bb = ws + off;  off += (size_t)BATCH * NPTS * 256;
  float* h1 = ws + off;  off += (size_t)BATCH * NPTS * 64;
  float* h2 = ws + off;  off += (size_t)BATCH * NPTS * 64;
  float* h3 = ws + off;  off += (size_t)BATCH * NPTS * 128;
  float* h4 = ws + off;  off += (size_t)BATCH * NPTS * 256;
  float* pd = ws + off;  off += (size_t)BATCH * NPTS * NPTS;   // reused as h5
  float* pooled = ws + off; off += (size_t)BATCH * 2048;
  float* f1 = ws + off;  off += (size_t)BATCH * 512;
  float* f2 = ws + off;  off += (size_t)BATCH * 256;
  int* idx = (int*)(ws + off);                                  // BATCH*NPTS*KNN ints
  float* h5 = pd;

  transpose_x<<<(BATCH * NPTS * 3 + 255) / 256, 256, 0, stream>>>(x, xt);

  struct Stage { const float* feat; int C; int O; const float* w; const float* bnp; float* hout; };
  Stage stages[4] = {
    {xt, 3,   64,  w1, bn1, h1},
    {h1, 64,  64,  w2, bn2, h2},
    {h2, 64,  128, w3, bn3, h3},
    {h3, 128, 256, w4, bn4, h4},
  };
  for (int s = 0; s < 4; s++) {
    Stage st = stages[s];
    compute_xx<<<(BATCH * NPTS + 255) / 256, 256, 0, stream>>>(st.feat, xx, st.C);
    gram_pd<<<dim3(16, 16, BATCH), 256, 0, stream>>>(st.feat, xx, pd, st.C);
    topk20<<<(BATCH * NPTS) / 4, 256, 0, stream>>>(pd, idx);
    prep_w2<<<(st.O * st.C + 255) / 256, 256, 0, stream>>>(st.w, W2, st.C, st.O);
    gemm_ab<<<dim3(2 * st.O / 64, (BATCH * NPTS) / 64), 256, 0, stream>>>(st.feat, W2, Ab, Bb, st.C, st.O);
    int npb = 256 / st.O;
    gather_max_bn<<<(BATCH * NPTS) / npb, 256, 0, stream>>>(Ab, Bb, idx, st.bnp, st.hout, st.O);
  }

  gemm_w5k<<<dim3(16, (BATCH * NPTS) / 64), 256, 0, stream>>>(h1, h2, h3, h4, w5, bn5, h5);
  pool_kernel<<<dim3(4, BATCH), 256, 0, stream>>>(h5, pooled);

  fc_kernel<<<(BATCH * 512 * 64) / 256, 256, 0, stream>>>(pooled, l1w, nullptr, bn6, f1, 2048, 512, 1);
  fc_kernel<<<(BATCH * 256 * 64) / 256, 256, 0, stream>>>(f1, l2w, l2b, bn7, f2, 512, 256, 1);
  fc_kernel<<<(BATCH * 40 * 64 + 255) / 256, 256, 0, stream>>>(f2, l3w, l3b, nullptr, out, 256, 40, 0);
}

// Round 2
// 814.423 us; speedup vs baseline: 1.2473x; 1.2473x over previous
//
#include <hip/hip_runtime.h>
#include <math.h>

#define BATCH 16
#define NPTS  1024
#define KNN   20
#define BNEPS 1e-5f

typedef __attribute__((ext_vector_type(8))) short bf16x8;
typedef __attribute__((ext_vector_type(4))) float f32x4;

__device__ __forceinline__ float bf2f(unsigned short h) {
  return __uint_as_float(((unsigned int)h) << 16);
}
__device__ __forceinline__ unsigned short f2bf(float f) {
  unsigned int u = __float_as_uint(f);
  u += 0x7fffu + ((u >> 16) & 1u);
  return (unsigned short)(u >> 16);
}

// ---------------------------------------------------------------- transpose
__global__ void transpose_x(const float* __restrict__ x, float* __restrict__ xt) {
  int i = blockIdx.x * 256 + threadIdx.x;
  if (i >= BATCH * NPTS * 3) return;
  int b = i / (NPTS * 3);
  int r = i - b * (NPTS * 3);
  int n = r / 3;
  int c = r - n * 3;
  xt[i] = x[(b * 3 + c) * NPTS + n];
}

// ---------------------------------------------------------------- w5 split to bf16 hi/lo
__global__ void split_w5(const float* __restrict__ w5, unsigned short* __restrict__ H,
                         unsigned short* __restrict__ L) {
  int i = blockIdx.x * 256 + threadIdx.x;
  if (i >= 1024 * 512) return;
  float v = w5[i];
  unsigned short h = f2bf(v);
  H[i] = h;
  L[i] = f2bf(v - bf2f(h));
}

// ---------------------------------------------------------------- xx = ||x||^2 (f32 feat)
__global__ void compute_xx(const float* __restrict__ feat, int ld, int C, float* __restrict__ xx) {
  int i = blockIdx.x * 256 + threadIdx.x;
  if (i >= BATCH * NPTS) return;
  const float* f = feat + (size_t)i * ld;
  float s = 0.f;
  for (int c = 0; c < C; c++) s = fmaf(f[c], f[c], s);
  xx[i] = s;
}

// ---------------------------------------------------------------- xx from bf16 hi/lo feat
__global__ void compute_xx_bf(const unsigned short* __restrict__ H, const unsigned short* __restrict__ L,
                              int ld, int C, float* __restrict__ xx) {
  int i = blockIdx.x * 256 + threadIdx.x;
  if (i >= BATCH * NPTS) return;
  const unsigned short* hp = H + (size_t)i * ld;
  const unsigned short* lp = L + (size_t)i * ld;
  float s = 0.f;
  for (int c = 0; c < C; c++) {
    float a = bf2f(hp[c]) + bf2f(lp[c]);
    s = fmaf(a, a, s);
  }
  xx[i] = s;
}

// ---------------------------------------------------------------- pd = 2*X.X^T - xx_n - xx_m (f32 feat)
__global__ void gram_pd(const float* __restrict__ feat, int ld, int C, const float* __restrict__ xx,
                        float* __restrict__ pd) {
  __shared__ float As[16][68];
  __shared__ float Bs[16][68];
  int b = blockIdx.z;
  const float* xb = xx + b * NPTS;
  int m0 = blockIdx.y * 64, n0 = blockIdx.x * 64;
  int tid = threadIdx.x, tx = tid & 15, ty = tid >> 4;
  float acc[4][4] = {};
  for (int k0 = 0; k0 < C; k0 += 16) {
#pragma unroll
    for (int l = 0; l < 4; l++) {
      int e = tid + l * 256;
      int m = e >> 4, k = e & 15;
      float av = 0.f, bv = 0.f;
      if (k0 + k < C) {
        av = feat[(size_t)(b * NPTS + m0 + m) * ld + k0 + k];
        bv = feat[(size_t)(b * NPTS + n0 + m) * ld + k0 + k];
      }
      As[k][m] = av;
      Bs[k][m] = bv;
    }
    __syncthreads();
#pragma unroll
    for (int kk = 0; kk < 16; kk++) {
      float4 ra = *(const float4*)&As[kk][ty * 4];
      float4 rb = *(const float4*)&Bs[kk][tx * 4];
      float a[4] = {ra.x, ra.y, ra.z, ra.w};
      float w[4] = {rb.x, rb.y, rb.z, rb.w};
#pragma unroll
      for (int i2 = 0; i2 < 4; i2++)
#pragma unroll
        for (int j = 0; j < 4; j++)
          acc[i2][j] = fmaf(a[i2], w[j], acc[i2][j]);
    }
    __syncthreads();
  }
#pragma unroll
  for (int i2 = 0; i2 < 4; i2++) {
    int m = m0 + ty * 4 + i2;
    float xm = xb[m];
#pragma unroll
    for (int j = 0; j < 4; j++) {
      int n = n0 + tx * 4 + j;
      pd[((size_t)b * NPTS + m) * NPTS + n] = fmaf(2.f, acc[i2][j], -xm) - xb[n];
    }
  }
}

// ---------------------------------------------------------------- pd from bf16 hi/lo feat
__global__ void gram_pd_bf(const unsigned short* __restrict__ H, const unsigned short* __restrict__ L,
                           int ld, int C, const float* __restrict__ xx, float* __restrict__ pd) {
  __shared__ float As[16][68];
  __shared__ float Bs[16][68];
  int b = blockIdx.z;
  const float* xb = xx + b * NPTS;
  int m0 = blockIdx.y * 64, n0 = blockIdx.x * 64;
  int tid = threadIdx.x, tx = tid & 15, ty = tid >> 4;
  float acc[4][4] = {};
  for (int k0 = 0; k0 < C; k0 += 16) {
#pragma unroll
    for (int l = 0; l < 4; l++) {
      int e = tid + l * 256;
      int m = e >> 4, k = e & 15;
      size_t ia = (size_t)(b * NPTS + m0 + m) * ld + k0 + k;
      size_t ib = (size_t)(b * NPTS + n0 + m) * ld + k0 + k;
      As[k][m] = bf2f(H[ia]) + bf2f(L[ia]);
      Bs[k][m] = bf2f(H[ib]) + bf2f(L[ib]);
    }
    __syncthreads();
#pragma unroll
    for (int kk = 0; kk < 16; kk++) {
      float4 ra = *(const float4*)&As[kk][ty * 4];
      float4 rb = *(const float4*)&Bs[kk][tx * 4];
      float a[4] = {ra.x, ra.y, ra.z, ra.w};
      float w[4] = {rb.x, rb.y, rb.z, rb.w};
#pragma unroll
      for (int i2 = 0; i2 < 4; i2++)
#pragma unroll
        for (int j = 0; j < 4; j++)
          acc[i2][j] = fmaf(a[i2], w[j], acc[i2][j]);
    }
    __syncthreads();
  }
#pragma unroll
  for (int i2 = 0; i2 < 4; i2++) {
    int m = m0 + ty * 4 + i2;
    float xm = xb[m];
#pragma unroll
    for (int j = 0; j < 4; j++) {
      int n = n0 + tx * 4 + j;
      pd[((size_t)b * NPTS + m) * NPTS + n] = fmaf(2.f, acc[i2][j], -xm) - xb[n];
    }
  }
}

// ---------------------------------------------------------------- top-20 per row (wave per row)
__global__ void topk20(const float* __restrict__ pd, int* __restrict__ idx) {
  int tid = threadIdx.x, lane = tid & 63, w = tid >> 6;
  int row = blockIdx.x * 4 + w;
  const float* p = pd + (size_t)row * NPTS;
  float v[16];
#pragma unroll
  for (int s = 0; s < 16; s++) v[s] = p[lane + s * 64];
  int* o = idx + row * KNN;
  for (int j = 0; j < KNN; j++) {
    float bv = v[0];
    int bs = 0;
#pragma unroll
    for (int s = 1; s < 16; s++)
      if (v[s] > bv) { bv = v[s]; bs = s; }
    int bi = bs * 64 + lane;
#pragma unroll
    for (int off = 32; off; off >>= 1) {
      float ov = __shfl_xor(bv, off);
      int   oi = __shfl_xor(bi, off);
      if (ov > bv || (ov == bv && oi < bi)) { bv = ov; bi = oi; }
    }
    if (lane == 0) o[j] = bi;
    if ((bi & 63) == lane) v[bi >> 6] = -INFINITY;
  }
}

// ---------------------------------------------------------------- W2 = [wl ; wr-wl] (f32 + bf16 hi/lo)
__global__ void prep_w2(const float* __restrict__ w, float* __restrict__ W2f,
                        unsigned short* __restrict__ W2H, unsigned short* __restrict__ W2L,
                        int C, int O) {
  int i = blockIdx.x * 256 + threadIdx.x;
  if (i >= O * C) return;
  int o = i / C, c = i - o * C;
  float wl = w[o * 2 * C + c];
  float d  = w[o * 2 * C + C + c] - wl;
  W2f[(size_t)o * C + c]       = wl;
  W2f[(size_t)(O + o) * C + c] = d;
  unsigned short h1 = f2bf(wl);
  W2H[(size_t)o * C + c] = h1;
  W2L[(size_t)o * C + c] = f2bf(wl - bf2f(h1));
  unsigned short h2 = f2bf(d);
  W2H[(size_t)(O + o) * C + c] = h2;
  W2L[(size_t)(O + o) * C + c] = f2bf(d - bf2f(h2));
}

// ---------------------------------------------------------------- f32 GEMM for stage 1 (K=3)
__global__ void gemm_ab_f32(const float* __restrict__ feat, const float* __restrict__ W2,
                            float* __restrict__ Ab, float* __restrict__ Bb, int K, int O) {
  __shared__ float As[16][68];
  __shared__ float Ws[16][68];
  int n0 = blockIdx.x * 64, m0 = blockIdx.y * 64;
  int tid = threadIdx.x, tx = tid & 15, ty = tid >> 4;
  float acc[4][4] = {};
  for (int k0 = 0; k0 < K; k0 += 16) {
#pragma unroll
    for (int l = 0; l < 4; l++) {
      int e = tid + l * 256;
      int m = e >> 4, k = e & 15;
      As[k][m] = (k0 + k < K) ? feat[(size_t)(m0 + m) * K + k0 + k] : 0.f;
      Ws[k][m] = (k0 + k < K) ? W2[(size_t)(n0 + m) * K + k0 + k] : 0.f;
    }
    __syncthreads();
#pragma unroll
    for (int kk = 0; kk < 16; kk++) {
      float4 ra = *(const float4*)&As[kk][ty * 4];
      float4 rb = *(const float4*)&Ws[kk][tx * 4];
      float a[4] = {ra.x, ra.y, ra.z, ra.w};
      float w[4] = {rb.x, rb.y, rb.z, rb.w};
#pragma unroll
      for (int i2 = 0; i2 < 4; i2++)
#pragma unroll
        for (int j = 0; j < 4; j++)
          acc[i2][j] = fmaf(a[i2], w[j], acc[i2][j]);
    }
    __syncthreads();
  }
#pragma unroll
  for (int i2 = 0; i2 < 4; i2++) {
    int row = m0 + ty * 4 + i2;
#pragma unroll
    for (int j = 0; j < 4; j++) {
      int col = n0 + tx * 4 + j;
      if (col < O) Ab[(size_t)row * O + col] = acc[i2][j];
      else         Bb[(size_t)row * O + (col - O)] = acc[i2][j];
    }
  }
}

// ---------------------------------------------------------------- bf16x3 MFMA GEMM: C = A*B^T
// A:[M,K] hi/lo bf16 (lda), B:[N,K] hi/lo bf16 (ldb). 128x128 tile, BK=32, 256 thr.
// EPI=0: out0 = lrelu(bn(acc)) [ldc=N]; EPI=1: split cols O=N/2 -> out0/out1.
template<int EPI>
__global__ __launch_bounds__(256) void mfma_gemm(
    const unsigned short* __restrict__ AH, const unsigned short* __restrict__ AL, int lda,
    const unsigned short* __restrict__ BH, const unsigned short* __restrict__ BL, int ldb,
    int K, int N, const float* __restrict__ bnp,
    float* __restrict__ out0, float* __restrict__ out1) {
  __shared__ unsigned short lds[4][128 * 32];
  int tid = threadIdx.x;
  int lane = tid & 63, w = tid >> 6;
  int n0 = blockIdx.x * 128, m0 = blockIdx.y * 128;
  int wrow = (w >> 1) * 64, wcol = (w & 1) * 64;

  f32x4 acc[4][4];
#pragma unroll
  for (int m = 0; m < 4; m++)
#pragma unroll
    for (int n = 0; n < 4; n++) acc[m][n] = (f32x4){0.f, 0.f, 0.f, 0.f};

  // wave w stages tile w: 0=AH rows, 1=AL rows, 2=BH rows, 3=BL rows
  const unsigned short* gsrc = (w == 0) ? AH : (w == 1) ? AL : (w == 2) ? BH : BL;
  int ld = (w < 2) ? lda : ldb;
  int b0 = (w < 2) ? m0 : n0;
  int srow = lane >> 2;        // 0..15 within each 1KB issue
  int physChunk = lane & 3;    // 16B chunk within 64B row

  int fr = lane & 15, ko = lane >> 4;

  for (int kt = 0; kt < K; kt += 32) {
#pragma unroll
    for (int i = 0; i < 8; i++) {
      int row = i * 16 + srow;
      int lchunk = physChunk ^ (row & 3);  // pre-swizzled source -> swizzled LDS layout
      const unsigned short* g = gsrc + (size_t)(b0 + row) * ld + kt + lchunk * 8;
      unsigned short* l = &lds[w][i * 512];  // wave-uniform base; HW adds lane*16B
      __builtin_amdgcn_global_load_lds(
          (const __attribute__((address_space(1))) unsigned int*)g,
          (__attribute__((address_space(3))) unsigned int*)l, 16, 0, 0);
    }
    __syncthreads();

    bf16x8 ah[4], al[4], bh[4], bl[4];
#pragma unroll
    for (int m = 0; m < 4; m++) {
      int row = wrow + m * 16 + fr;
      int off = row * 64 + ((ko ^ (row & 3)) * 16);
      ah[m] = *(const bf16x8*)((const char*)&lds[0][0] + off);
      al[m] = *(const bf16x8*)((const char*)&lds[1][0] + off);
    }
#pragma unroll
    for (int n = 0; n < 4; n++) {
      int row = wcol + n * 16 + fr;
      int off = row * 64 + ((ko ^ (row & 3)) * 16);
      bh[n] = *(const bf16x8*)((const char*)&lds[2][0] + off);
      bl[n] = *(const bf16x8*)((const char*)&lds[3][0] + off);
    }
#pragma unroll
    for (int m = 0; m < 4; m++)
#pragma unroll
      for (int n = 0; n < 4; n++) {
        acc[m][n] = __builtin_amdgcn_mfma_f32_16x16x32_bf16(ah[m], bh[n], acc[m][n], 0, 0, 0);
        acc[m][n] = __builtin_amdgcn_mfma_f32_16x16x32_bf16(al[m], bh[n], acc[m][n], 0, 0, 0);
        acc[m][n] = __builtin_amdgcn_mfma_f32_16x16x32_bf16(ah[m], bl[n], acc[m][n], 0, 0, 0);
      }
    __syncthreads();
  }

  // epilogue: C/D layout col = lane&15, row = (lane>>4)*4 + reg
  int fq = lane >> 4;
#pragma unroll
  for (int n = 0; n < 4; n++) {
    int gc = n0 + wcol + n * 16 + fr;
    if (EPI == 0) {
      float g = bnp[gc], bt = bnp[N + gc], mu = bnp[2 * N + gc], va = bnp[3 * N + gc];
      float sc = g * rsqrtf(va + BNEPS);
#pragma unroll
      for (int m = 0; m < 4; m++)
#pragma unroll
        for (int r = 0; r < 4; r++) {
          int gr = m0 + wrow + m * 16 + fq * 4 + r;
          float y = sc * (acc[m][n][r] - mu) + bt;
          out0[(size_t)gr * N + gc] = y >= 0.f ? y : 0.2f * y;
        }
    } else {
      int O = N >> 1;
      float* dst = (gc < O) ? out0 : out1;
      int cc = (gc < O) ? gc : gc - O;
#pragma unroll
      for (int m = 0; m < 4; m++)
#pragma unroll
        for (int r = 0; r < 4; r++) {
          int gr = m0 + wrow + m * 16 + fq * 4 + r;
          dst[(size_t)gr * O + cc] = acc[m][n][r];
        }
    }
  }
}

// ---------------------------------------------------------------- gather + max_k + BN + LReLU -> bf16 hi/lo cat
__global__ void gather_max_bn(const float* __restrict__ Ab, const float* __restrict__ Bb,
                              const int* __restrict__ idx, const float* __restrict__ bnp,
                              unsigned short* __restrict__ catH, unsigned short* __restrict__ catL,
                              int co, int O) {
  int tid = threadIdx.x;
  int npb = 256 / O;
  int local_n = tid / O;
  int o = tid - local_n * O;
  int pt = blockIdx.x * npb + local_n;
  int b = pt >> 10;
  const int* ix = idx + pt * KNN;
  const float* Abase = Ab + ((size_t)(b << 10)) * O;
  float m = -INFINITY;
#pragma unroll 4
  for (int k = 0; k < KNN; k++)
    m = fmaxf(m, Abase[(size_t)ix[k] * O + o]);
  float h = m + Bb[(size_t)pt * O + o];
  float g = bnp[o], bt = bnp[O + o], mu = bnp[2 * O + o], va = bnp[3 * O + o];
  float y = g * (h - mu) * rsqrtf(va + BNEPS) + bt;
  y = y >= 0.f ? y : 0.2f * y;
  unsigned short hh = f2bf(y);
  size_t dst = (size_t)pt * 512 + co + o;
  catH[dst] = hh;
  catL[dst] = f2bf(y - bf2f(hh));
}

// ---------------------------------------------------------------- max + mean pool over N
__global__ void pool_kernel(const float* __restrict__ h5, float* __restrict__ pooled) {
  int c = blockIdx.x * 256 + threadIdx.x;
  int b = blockIdx.y;
  const float* p = h5 + (size_t)b * NPTS * 1024 + c;
  float mx = -INFINITY, sm = 0.f;
  for (int n = 0; n < NPTS; n++) {
    float v = p[(size_t)n * 1024];
    mx = fmaxf(mx, v);
    sm += v;
  }
  pooled[b * 2048 + c] = mx;
  pooled[b * 2048 + 1024 + c] = sm * (1.f / 1024.f);
}

// ---------------------------------------------------------------- FC: wave per output
__global__ void fc_kernel(const float* __restrict__ in, const float* __restrict__ w,
                          const float* __restrict__ bias, const float* __restrict__ bnp,
                          float* __restrict__ out, int Cin, int Cout, int act) {
  int g = blockIdx.x * blockDim.x + threadIdx.x;
  int wid = g >> 6, lane = g & 63;
  if (wid >= BATCH * Cout) return;
  int b = wid / Cout, o = wid - b * Cout;
  const float* xp = in + (size_t)b * Cin;
  const float* wp = w + (size_t)o * Cin;
  float s = 0.f;
  for (int c = lane; c < Cin; c += 64) s = fmaf(xp[c], wp[c], s);
#pragma unroll
  for (int off = 32; off; off >>= 1) s += __shfl_xor(s, off);
  if (lane == 0) {
    if (bias) s += bias[o];
    if (act) {
      float gm = bnp[o], bt = bnp[Cout + o], mu = bnp[2 * Cout + o], va = bnp[3 * Cout + o];
      s = gm * (s - mu) * rsqrtf(va + BNEPS) + bt;
      s = s >= 0.f ? s : 0.2f * s;
    }
    out[wid] = s;
  }
}

// ================================================================ launch
extern "C" void kernel_launch(void* const* d_in, const int* in_sizes, int n_in,
                              void* d_out, int out_size, void* d_ws, size_t ws_size,
                              hipStream_t stream) {
  const float* x   = (const float*)d_in[0];
  const float* w1  = (const float*)d_in[1];
  const float* w2  = (const float*)d_in[2];
  const float* w3  = (const float*)d_in[3];
  const float* w4  = (const float*)d_in[4];
  const float* w5  = (const float*)d_in[5];
  const float* bn1 = (const float*)d_in[6];
  const float* bn2 = (const float*)d_in[7];
  const float* bn3 = (const float*)d_in[8];
  const float* bn4 = (const float*)d_in[9];
  const float* bn5 = (const float*)d_in[10];
  const float* bn6 = (const float*)d_in[11];
  const float* bn7 = (const float*)d_in[12];
  const float* l1w = (const float*)d_in[13];
  const float* l2w = (const float*)d_in[14];
  const float* l2b = (const float*)d_in[15];
  const float* l3w = (const float*)d_in[16];
  const float* l3b = (const float*)d_in[17];
  float* out = (float*)d_out;

  float* ws = (float*)d_ws;
  size_t off = 0;
  float* xt  = ws + off; off += (size_t)BATCH * NPTS * 3;        // 49152
  float* xx  = ws + off; off += (size_t)BATCH * NPTS;            // 16384
  float* W2f = ws + off; off += (size_t)512 * 128;               // 65536
  unsigned short* W2H = (unsigned short*)(ws + off); off += (size_t)512 * 128 / 2;
  unsigned short* W2L = (unsigned short*)(ws + off); off += (size_t)512 * 128 / 2;
  unsigned short* w5H = (unsigned short*)(ws + off); off += (size_t)1024 * 512 / 2;
  unsigned short* w5L = (unsigned short*)(ws + off); off += (size_t)1024 * 512 / 2;
  float* Ab  = ws + off; off += (size_t)BATCH * NPTS * 256;
  float* Bb  = ws + off; off += (size_t)BATCH * NPTS * 256;
  unsigned short* catH = (unsigned short*)(ws + off); off += (size_t)BATCH * NPTS * 512 / 2;
  unsigned short* catL = (unsigned short*)(ws + off); off += (size_t)BATCH * NPTS * 512 / 2;
  float* pd  = ws + off; off += (size_t)BATCH * NPTS * NPTS;     // reused as h5
  float* pooled = ws + off; off += (size_t)BATCH * 2048;
  float* f1  = ws + off; off += (size_t)BATCH * 512;
  float* f2  = ws + off; off += (size_t)BATCH * 256;
  int* idx = (int*)(ws + off);
  float* h5 = pd;

  transpose_x<<<(BATCH * NPTS * 3 + 255) / 256, 256, 0, stream>>>(x, xt);
  split_w5<<<(1024 * 512) / 256, 256, 0, stream>>>(w5, w5H, w5L);

  // ---------------- stage 1 (f32 path, K=3)
  compute_xx<<<64, 256, 0, stream>>>(xt, 3, 3, xx);
  gram_pd<<<dim3(16, 16, BATCH), 256, 0, stream>>>(xt, 3, 3, xx, pd);
  topk20<<<(BATCH * NPTS) / 4, 256, 0, stream>>>(pd, idx);
  prep_w2<<<(64 * 3 + 255) / 256, 256, 0, stream>>>(w1, W2f, W2H, W2L, 3, 64);
  gemm_ab_f32<<<dim3(2, (BATCH * NPTS) / 64), 256, 0, stream>>>(xt, W2f, Ab, Bb, 3, 64);
  gather_max_bn<<<(BATCH * NPTS) / 4, 256, 0, stream>>>(Ab, Bb, idx, bn1, catH, catL, 0, 64);

  // ---------------- stages 2..4 (bf16x3 MFMA path)
  struct Stage { int co; int C; int O; const float* w; const float* bnp; int hco; };
  Stage st[3] = {
    {0,   64,  64,  w2, bn2, 64},
    {64,  64,  128, w3, bn3, 128},
    {128, 128, 256, w4, bn4, 256},
  };
  for (int s = 0; s < 3; s++) {
    int C = st[s].C, O = st[s].O, co = st[s].co;
    compute_xx_bf<<<64, 256, 0, stream>>>(catH + co, catL + co, 512, C, xx);
    gram_pd_bf<<<dim3(16, 16, BATCH), 256, 0, stream>>>(catH + co, catL + co, 512, C, xx, pd);
    topk20<<<(BATCH * NPTS) / 4, 256, 0, stream>>>(pd, idx);
    prep_w2<<<(O * C + 255) / 256, 256, 0, stream>>>(st[s].w, W2f, W2H, W2L, C, O);
    mfma_gemm<1><<<dim3(2 * O / 128, (BATCH * NPTS) / 128), 256, 0, stream>>>(
        catH + co, catL + co, 512, W2H, W2L, C, C, 2 * O, nullptr, Ab, Bb);
    int npb = 256 / O;
    gather_max_bn<<<(BATCH * NPTS) / npb, 256, 0, stream>>>(Ab, Bb, idx, st[s].bnp, catH, catL, st[s].hco, O);
  }

  // ---------------- w5 GEMM (bf16x3 MFMA) + BN5 + LReLU
  mfma_gemm<0><<<dim3(8, (BATCH * NPTS) / 128), 256, 0, stream>>>(
      catH, catL, 512, w5H, w5L, 512, 512, 1024, bn5, h5, nullptr);

  pool_kernel<<<dim3(4, BATCH), 256, 0, stream>>>(h5, pooled);

  fc_kernel<<<(BATCH * 512 * 64) / 256, 256, 0, stream>>>(pooled, l1w, nullptr, bn6, f1, 2048, 512, 1);
  fc_kernel<<<(BATCH * 256 * 64) / 256, 256, 0, stream>>>(f1, l2w, l2b, bn7, f2, 512, 256, 1);
  fc_kernel<<<(BATCH * 40 * 64 + 255) / 256, 256, 0, stream>>>(f2, l3w, l3b, nullptr, out, 256, 40, 0);
}

// Round 3
// 693.553 us; speedup vs baseline: 1.4647x; 1.1743x over previous
//
#include <hip/hip_runtime.h>
#include <math.h>

#define BATCH 16
#define NPTS  1024
#define KNN   20
#define BNEPS 1e-5f

typedef __attribute__((ext_vector_type(8))) short bf16x8;
typedef __attribute__((ext_vector_type(4))) float f32x4;

__device__ __forceinline__ float bf2f(unsigned short h) {
  return __uint_as_float(((unsigned int)h) << 16);
}
__device__ __forceinline__ unsigned short f2bf(float f) {
  unsigned int u = __float_as_uint(f);
  u += 0x7fffu + ((u >> 16) & 1u);
  return (unsigned short)(u >> 16);
}

// ---------------------------------------------------------------- transpose
__global__ void transpose_x(const float* __restrict__ x, float* __restrict__ xt) {
  int i = blockIdx.x * 256 + threadIdx.x;
  if (i >= BATCH * NPTS * 3) return;
  int b = i / (NPTS * 3);
  int r = i - b * (NPTS * 3);
  int n = r / 3;
  int c = r - n * 3;
  xt[i] = x[(b * 3 + c) * NPTS + n];
}

// ---------------------------------------------------------------- w5 split to bf16 hi/lo
__global__ void split_w5(const float* __restrict__ w5, unsigned short* __restrict__ H,
                         unsigned short* __restrict__ L) {
  int i = blockIdx.x * 256 + threadIdx.x;
  if (i >= 1024 * 512) return;
  float v = w5[i];
  unsigned short h = f2bf(v);
  H[i] = h;
  L[i] = f2bf(v - bf2f(h));
}

// ---------------------------------------------------------------- xx = ||x||^2 (f32 feat)
__global__ void compute_xx(const float* __restrict__ feat, int ld, int C, float* __restrict__ xx) {
  int i = blockIdx.x * 256 + threadIdx.x;
  if (i >= BATCH * NPTS) return;
  const float* f = feat + (size_t)i * ld;
  float s = 0.f;
  for (int c = 0; c < C; c++) s = fmaf(f[c], f[c], s);
  xx[i] = s;
}

// ---------------------------------------------------------------- xx from bf16 hi/lo feat (vectorized)
__global__ void compute_xx_bf(const unsigned short* __restrict__ H, const unsigned short* __restrict__ L,
                              int ld, int C, float* __restrict__ xx) {
  int i = blockIdx.x * 256 + threadIdx.x;
  if (i >= BATCH * NPTS) return;
  const bf16x8* hp = (const bf16x8*)(H + (size_t)i * ld);
  const bf16x8* lp = (const bf16x8*)(L + (size_t)i * ld);
  float s = 0.f;
  for (int c8 = 0; c8 < C / 8; c8++) {
    bf16x8 h8 = hp[c8];
    bf16x8 l8 = lp[c8];
#pragma unroll
    for (int e = 0; e < 8; e++) {
      float a = bf2f((unsigned short)h8[e]) + bf2f((unsigned short)l8[e]);
      s = fmaf(a, a, s);
    }
  }
  xx[i] = s;
}

// ---------------------------------------------------------------- pd = 2*X.X^T - xx_n - xx_m (f32 feat, stage 1)
__global__ void gram_pd(const float* __restrict__ feat, int ld, int C, const float* __restrict__ xx,
                        float* __restrict__ pd) {
  __shared__ float As[16][68];
  __shared__ float Bs[16][68];
  int b = blockIdx.z;
  const float* xb = xx + b * NPTS;
  int m0 = blockIdx.y * 64, n0 = blockIdx.x * 64;
  int tid = threadIdx.x, tx = tid & 15, ty = tid >> 4;
  float acc[4][4] = {};
  for (int k0 = 0; k0 < C; k0 += 16) {
#pragma unroll
    for (int l = 0; l < 4; l++) {
      int e = tid + l * 256;
      int m = e >> 4, k = e & 15;
      float av = 0.f, bv = 0.f;
      if (k0 + k < C) {
        av = feat[(size_t)(b * NPTS + m0 + m) * ld + k0 + k];
        bv = feat[(size_t)(b * NPTS + n0 + m) * ld + k0 + k];
      }
      As[k][m] = av;
      Bs[k][m] = bv;
    }
    __syncthreads();
#pragma unroll
    for (int kk = 0; kk < 16; kk++) {
      float4 ra = *(const float4*)&As[kk][ty * 4];
      float4 rb = *(const float4*)&Bs[kk][tx * 4];
      float a[4] = {ra.x, ra.y, ra.z, ra.w};
      float w[4] = {rb.x, rb.y, rb.z, rb.w};
#pragma unroll
      for (int i2 = 0; i2 < 4; i2++)
#pragma unroll
        for (int j = 0; j < 4; j++)
          acc[i2][j] = fmaf(a[i2], w[j], acc[i2][j]);
    }
    __syncthreads();
  }
#pragma unroll
  for (int i2 = 0; i2 < 4; i2++) {
    int m = m0 + ty * 4 + i2;
    float xm = xb[m];
#pragma unroll
    for (int j = 0; j < 4; j++) {
      int n = n0 + tx * 4 + j;
      pd[((size_t)b * NPTS + m) * NPTS + n] = fmaf(2.f, acc[i2][j], -xm) - xb[n];
    }
  }
}

// ---------------------------------------------------------------- Gram via bf16x3 MFMA (stages 2-4)
// H/L: [B*N, ld] bf16 hi/lo cat features (already offset to stage's column).
// pd[b][m][n] = 2*dot(f_m, f_n) - xx[m] - xx[n]
__global__ __launch_bounds__(256) void gram_mfma(
    const unsigned short* __restrict__ H, const unsigned short* __restrict__ L,
    int ld, int C, const float* __restrict__ xx, float* __restrict__ pd) {
  __shared__ unsigned short lds[4][128 * 32];
  int tid = threadIdx.x;
  int lane = tid & 63, w = tid >> 6;
  int b = blockIdx.z;
  int n0 = blockIdx.x * 128, m0 = blockIdx.y * 128;
  int base = b * NPTS;
  int wrow = (w >> 1) * 64, wcol = (w & 1) * 64;

  f32x4 acc[4][4];
#pragma unroll
  for (int m = 0; m < 4; m++)
#pragma unroll
    for (int n = 0; n < 4; n++) acc[m][n] = (f32x4){0.f, 0.f, 0.f, 0.f};

  // wave w stages: 0=AH(m0), 1=AL(m0), 2=BH(n0), 3=BL(n0)
  const unsigned short* gsrc = (w == 0 || w == 2) ? H : L;
  int b0 = (w < 2) ? m0 : n0;
  int srow = lane >> 2;
  int physChunk = lane & 3;
  int fr = lane & 15, ko = lane >> 4;

  for (int kt = 0; kt < C; kt += 32) {
#pragma unroll
    for (int i = 0; i < 8; i++) {
      int row = i * 16 + srow;
      int lchunk = physChunk ^ (row & 3);
      const unsigned short* g = gsrc + (size_t)(base + b0 + row) * ld + kt + lchunk * 8;
      unsigned short* l = &lds[w][i * 512];
      __builtin_amdgcn_global_load_lds(
          (const __attribute__((address_space(1))) unsigned int*)g,
          (__attribute__((address_space(3))) unsigned int*)l, 16, 0, 0);
    }
    __syncthreads();

    bf16x8 ah[4], al[4], bh[4], bl[4];
#pragma unroll
    for (int m = 0; m < 4; m++) {
      int row = wrow + m * 16 + fr;
      int off = row * 64 + ((ko ^ (row & 3)) * 16);
      ah[m] = *(const bf16x8*)((const char*)&lds[0][0] + off);
      al[m] = *(const bf16x8*)((const char*)&lds[1][0] + off);
    }
#pragma unroll
    for (int n = 0; n < 4; n++) {
      int row = wcol + n * 16 + fr;
      int off = row * 64 + ((ko ^ (row & 3)) * 16);
      bh[n] = *(const bf16x8*)((const char*)&lds[2][0] + off);
      bl[n] = *(const bf16x8*)((const char*)&lds[3][0] + off);
    }
#pragma unroll
    for (int m = 0; m < 4; m++)
#pragma unroll
      for (int n = 0; n < 4; n++) {
        acc[m][n] = __builtin_amdgcn_mfma_f32_16x16x32_bf16(ah[m], bh[n], acc[m][n], 0, 0, 0);
        acc[m][n] = __builtin_amdgcn_mfma_f32_16x16x32_bf16(al[m], bh[n], acc[m][n], 0, 0, 0);
        acc[m][n] = __builtin_amdgcn_mfma_f32_16x16x32_bf16(ah[m], bl[n], acc[m][n], 0, 0, 0);
      }
    __syncthreads();
  }

  int fq = lane >> 4;
#pragma unroll
  for (int n = 0; n < 4; n++) {
    int gc = n0 + wcol + n * 16 + fr;
    float xn = xx[base + gc];
#pragma unroll
    for (int m = 0; m < 4; m++)
#pragma unroll
      for (int r = 0; r < 4; r++) {
        int gr = m0 + wrow + m * 16 + fq * 4 + r;
        pd[((size_t)(base + gr)) * NPTS + gc] = fmaf(2.f, acc[m][n][r], -xx[base + gr]) - xn;
      }
  }
}

// ---------------------------------------------------------------- top-20 per row (wave per row)
// static-index removal: v[] stays in VGPRs (no scratch)
__global__ void topk20(const float* __restrict__ pd, int* __restrict__ idx) {
  int tid = threadIdx.x, lane = tid & 63, w = tid >> 6;
  int row = blockIdx.x * 4 + w;
  const float* p = pd + (size_t)row * NPTS;
  float v[16];
#pragma unroll
  for (int s = 0; s < 16; s++) v[s] = p[lane + s * 64];
  int* o = idx + row * KNN;
  for (int j = 0; j < KNN; j++) {
    float bv = v[0];
    int bs = 0;
#pragma unroll
    for (int s = 1; s < 16; s++)
      if (v[s] > bv) { bv = v[s]; bs = s; }
    int bi = bs * 64 + lane;
#pragma unroll
    for (int off = 32; off; off >>= 1) {
      float ov = __shfl_xor(bv, off);
      int   oi = __shfl_xor(bi, off);
      if (ov > bv || (ov == bv && oi < bi)) { bv = ov; bi = oi; }
    }
    if (lane == 0) o[j] = bi;
    int ds_ = bi >> 6;                 // wave-uniform
    bool mine = (bi & 63) == lane;
#pragma unroll
    for (int s = 0; s < 16; s++)
      if (mine && s == ds_) v[s] = -INFINITY;
  }
}

// ---------------------------------------------------------------- W2 = [wl ; wr-wl] (f32 + bf16 hi/lo)
__global__ void prep_w2(const float* __restrict__ w, float* __restrict__ W2f,
                        unsigned short* __restrict__ W2H, unsigned short* __restrict__ W2L,
                        int C, int O) {
  int i = blockIdx.x * 256 + threadIdx.x;
  if (i >= O * C) return;
  int o = i / C, c = i - o * C;
  float wl = w[o * 2 * C + c];
  float d  = w[o * 2 * C + C + c] - wl;
  W2f[(size_t)o * C + c]       = wl;
  W2f[(size_t)(O + o) * C + c] = d;
  unsigned short h1 = f2bf(wl);
  W2H[(size_t)o * C + c] = h1;
  W2L[(size_t)o * C + c] = f2bf(wl - bf2f(h1));
  unsigned short h2 = f2bf(d);
  W2H[(size_t)(O + o) * C + c] = h2;
  W2L[(size_t)(O + o) * C + c] = f2bf(d - bf2f(h2));
}

// ---------------------------------------------------------------- f32 GEMM for stage 1 (K=3)
__global__ void gemm_ab_f32(const float* __restrict__ feat, const float* __restrict__ W2,
                            float* __restrict__ Ab, float* __restrict__ Bb, int K, int O) {
  __shared__ float As[16][68];
  __shared__ float Ws[16][68];
  int n0 = blockIdx.x * 64, m0 = blockIdx.y * 64;
  int tid = threadIdx.x, tx = tid & 15, ty = tid >> 4;
  float acc[4][4] = {};
  for (int k0 = 0; k0 < K; k0 += 16) {
#pragma unroll
    for (int l = 0; l < 4; l++) {
      int e = tid + l * 256;
      int m = e >> 4, k = e & 15;
      As[k][m] = (k0 + k < K) ? feat[(size_t)(m0 + m) * K + k0 + k] : 0.f;
      Ws[k][m] = (k0 + k < K) ? W2[(size_t)(n0 + m) * K + k0 + k] : 0.f;
    }
    __syncthreads();
#pragma unroll
    for (int kk = 0; kk < 16; kk++) {
      float4 ra = *(const float4*)&As[kk][ty * 4];
      float4 rb = *(const float4*)&Ws[kk][tx * 4];
      float a[4] = {ra.x, ra.y, ra.z, ra.w};
      float w[4] = {rb.x, rb.y, rb.z, rb.w};
#pragma unroll
      for (int i2 = 0; i2 < 4; i2++)
#pragma unroll
        for (int j = 0; j < 4; j++)
          acc[i2][j] = fmaf(a[i2], w[j], acc[i2][j]);
    }
    __syncthreads();
  }
#pragma unroll
  for (int i2 = 0; i2 < 4; i2++) {
    int row = m0 + ty * 4 + i2;
#pragma unroll
    for (int j = 0; j < 4; j++) {
      int col = n0 + tx * 4 + j;
      if (col < O) Ab[(size_t)row * O + col] = acc[i2][j];
      else         Bb[(size_t)row * O + (col - O)] = acc[i2][j];
    }
  }
}

// ---------------------------------------------------------------- bf16x3 MFMA GEMM: C = A*B^T
template<int EPI>
__global__ __launch_bounds__(256) void mfma_gemm(
    const unsigned short* __restrict__ AH, const unsigned short* __restrict__ AL, int lda,
    const unsigned short* __restrict__ BH, const unsigned short* __restrict__ BL, int ldb,
    int K, int N, const float* __restrict__ bnp,
    float* __restrict__ out0, float* __restrict__ out1) {
  __shared__ unsigned short lds[4][128 * 32];
  int tid = threadIdx.x;
  int lane = tid & 63, w = tid >> 6;
  int n0 = blockIdx.x * 128, m0 = blockIdx.y * 128;
  int wrow = (w >> 1) * 64, wcol = (w & 1) * 64;

  f32x4 acc[4][4];
#pragma unroll
  for (int m = 0; m < 4; m++)
#pragma unroll
    for (int n = 0; n < 4; n++) acc[m][n] = (f32x4){0.f, 0.f, 0.f, 0.f};

  const unsigned short* gsrc = (w == 0) ? AH : (w == 1) ? AL : (w == 2) ? BH : BL;
  int ld = (w < 2) ? lda : ldb;
  int b0 = (w < 2) ? m0 : n0;
  int srow = lane >> 2;
  int physChunk = lane & 3;
  int fr = lane & 15, ko = lane >> 4;

  for (int kt = 0; kt < K; kt += 32) {
#pragma unroll
    for (int i = 0; i < 8; i++) {
      int row = i * 16 + srow;
      int lchunk = physChunk ^ (row & 3);
      const unsigned short* g = gsrc + (size_t)(b0 + row) * ld + kt + lchunk * 8;
      unsigned short* l = &lds[w][i * 512];
      __builtin_amdgcn_global_load_lds(
          (const __attribute__((address_space(1))) unsigned int*)g,
          (__attribute__((address_space(3))) unsigned int*)l, 16, 0, 0);
    }
    __syncthreads();

    bf16x8 ah[4], al[4], bh[4], bl[4];
#pragma unroll
    for (int m = 0; m < 4; m++) {
      int row = wrow + m * 16 + fr;
      int off = row * 64 + ((ko ^ (row & 3)) * 16);
      ah[m] = *(const bf16x8*)((const char*)&lds[0][0] + off);
      al[m] = *(const bf16x8*)((const char*)&lds[1][0] + off);
    }
#pragma unroll
    for (int n = 0; n < 4; n++) {
      int row = wcol + n * 16 + fr;
      int off = row * 64 + ((ko ^ (row & 3)) * 16);
      bh[n] = *(const bf16x8*)((const char*)&lds[2][0] + off);
      bl[n] = *(const bf16x8*)((const char*)&lds[3][0] + off);
    }
#pragma unroll
    for (int m = 0; m < 4; m++)
#pragma unroll
      for (int n = 0; n < 4; n++) {
        acc[m][n] = __builtin_amdgcn_mfma_f32_16x16x32_bf16(ah[m], bh[n], acc[m][n], 0, 0, 0);
        acc[m][n] = __builtin_amdgcn_mfma_f32_16x16x32_bf16(al[m], bh[n], acc[m][n], 0, 0, 0);
        acc[m][n] = __builtin_amdgcn_mfma_f32_16x16x32_bf16(ah[m], bl[n], acc[m][n], 0, 0, 0);
      }
    __syncthreads();
  }

  int fq = lane >> 4;
#pragma unroll
  for (int n = 0; n < 4; n++) {
    int gc = n0 + wcol + n * 16 + fr;
    if (EPI == 0) {
      float g = bnp[gc], bt = bnp[N + gc], mu = bnp[2 * N + gc], va = bnp[3 * N + gc];
      float sc = g * rsqrtf(va + BNEPS);
#pragma unroll
      for (int m = 0; m < 4; m++)
#pragma unroll
        for (int r = 0; r < 4; r++) {
          int gr = m0 + wrow + m * 16 + fq * 4 + r;
          float y = sc * (acc[m][n][r] - mu) + bt;
          out0[(size_t)gr * N + gc] = y >= 0.f ? y : 0.2f * y;
        }
    } else {
      int O = N >> 1;
      float* dst = (gc < O) ? out0 : out1;
      int cc = (gc < O) ? gc : gc - O;
#pragma unroll
      for (int m = 0; m < 4; m++)
#pragma unroll
        for (int r = 0; r < 4; r++) {
          int gr = m0 + wrow + m * 16 + fq * 4 + r;
          dst[(size_t)gr * O + cc] = acc[m][n][r];
        }
    }
  }
}

// ---------------------------------------------------------------- gather + max_k + BN + LReLU -> bf16 hi/lo cat
__global__ void gather_max_bn(const float* __restrict__ Ab, const float* __restrict__ Bb,
                              const int* __restrict__ idx, const float* __restrict__ bnp,
                              unsigned short* __restrict__ catH, unsigned short* __restrict__ catL,
                              int co, int O) {
  int tid = threadIdx.x;
  int npb = 256 / O;
  int local_n = tid / O;
  int o = tid - local_n * O;
  int pt = blockIdx.x * npb + local_n;
  int b = pt >> 10;
  const int* ix = idx + pt * KNN;
  const float* Abase = Ab + ((size_t)(b << 10)) * O;
  float m = -INFINITY;
#pragma unroll 4
  for (int k = 0; k < KNN; k++)
    m = fmaxf(m, Abase[(size_t)ix[k] * O + o]);
  float h = m + Bb[(size_t)pt * O + o];
  float g = bnp[o], bt = bnp[O + o], mu = bnp[2 * O + o], va = bnp[3 * O + o];
  float y = g * (h - mu) * rsqrtf(va + BNEPS) + bt;
  y = y >= 0.f ? y : 0.2f * y;
  unsigned short hh = f2bf(y);
  size_t dst = (size_t)pt * 512 + co + o;
  catH[dst] = hh;
  catL[dst] = f2bf(y - bf2f(hh));
}

// ---------------------------------------------------------------- max + mean pool over N
__global__ void pool_kernel(const float* __restrict__ h5, float* __restrict__ pooled) {
  int c = blockIdx.x * 256 + threadIdx.x;
  int b = blockIdx.y;
  const float* p = h5 + (size_t)b * NPTS * 1024 + c;
  float mx = -INFINITY, sm = 0.f;
  for (int n = 0; n < NPTS; n++) {
    float v = p[(size_t)n * 1024];
    mx = fmaxf(mx, v);
    sm += v;
  }
  pooled[b * 2048 + c] = mx;
  pooled[b * 2048 + 1024 + c] = sm * (1.f / 1024.f);
}

// ---------------------------------------------------------------- FC: wave per output
__global__ void fc_kernel(const float* __restrict__ in, const float* __restrict__ w,
                          const float* __restrict__ bias, const float* __restrict__ bnp,
                          float* __restrict__ out, int Cin, int Cout, int act) {
  int g = blockIdx.x * blockDim.x + threadIdx.x;
  int wid = g >> 6, lane = g & 63;
  if (wid >= BATCH * Cout) return;
  int b = wid / Cout, o = wid - b * Cout;
  const float* xp = in + (size_t)b * Cin;
  const float* wp = w + (size_t)o * Cin;
  float s = 0.f;
  for (int c = lane; c < Cin; c += 64) s = fmaf(xp[c], wp[c], s);
#pragma unroll
  for (int off = 32; off; off >>= 1) s += __shfl_xor(s, off);
  if (lane == 0) {
    if (bias) s += bias[o];
    if (act) {
      float gm = bnp[o], bt = bnp[Cout + o], mu = bnp[2 * Cout + o], va = bnp[3 * Cout + o];
      s = gm * (s - mu) * rsqrtf(va + BNEPS) + bt;
      s = s >= 0.f ? s : 0.2f * s;
    }
    out[wid] = s;
  }
}

// ================================================================ launch
extern "C" void kernel_launch(void* const* d_in, const int* in_sizes, int n_in,
                              void* d_out, int out_size, void* d_ws, size_t ws_size,
                              hipStream_t stream) {
  const float* x   = (const float*)d_in[0];
  const float* w1  = (const float*)d_in[1];
  const float* w2  = (const float*)d_in[2];
  const float* w3  = (const float*)d_in[3];
  const float* w4  = (const float*)d_in[4];
  const float* w5  = (const float*)d_in[5];
  const float* bn1 = (const float*)d_in[6];
  const float* bn2 = (const float*)d_in[7];
  const float* bn3 = (const float*)d_in[8];
  const float* bn4 = (const float*)d_in[9];
  const float* bn5 = (const float*)d_in[10];
  const float* bn6 = (const float*)d_in[11];
  const float* bn7 = (const float*)d_in[12];
  const float* l1w = (const float*)d_in[13];
  const float* l2w = (const float*)d_in[14];
  const float* l2b = (const float*)d_in[15];
  const float* l3w = (const float*)d_in[16];
  const float* l3b = (const float*)d_in[17];
  float* out = (float*)d_out;

  float* ws = (float*)d_ws;
  size_t off = 0;
  float* xt  = ws + off; off += (size_t)BATCH * NPTS * 3;
  float* xx  = ws + off; off += (size_t)BATCH * NPTS;
  float* W2f = ws + off; off += (size_t)512 * 128;
  unsigned short* W2H = (unsigned short*)(ws + off); off += (size_t)512 * 128 / 2;
  unsigned short* W2L = (unsigned short*)(ws + off); off += (size_t)512 * 128 / 2;
  unsigned short* w5H = (unsigned short*)(ws + off); off += (size_t)1024 * 512 / 2;
  unsigned short* w5L = (unsigned short*)(ws + off); off += (size_t)1024 * 512 / 2;
  float* Ab  = ws + off; off += (size_t)BATCH * NPTS * 256;
  float* Bb  = ws + off; off += (size_t)BATCH * NPTS * 256;
  unsigned short* catH = (unsigned short*)(ws + off); off += (size_t)BATCH * NPTS * 512 / 2;
  unsigned short* catL = (unsigned short*)(ws + off); off += (size_t)BATCH * NPTS * 512 / 2;
  float* pd  = ws + off; off += (size_t)BATCH * NPTS * NPTS;   // reused as h5
  float* pooled = ws + off; off += (size_t)BATCH * 2048;
  float* f1  = ws + off; off += (size_t)BATCH * 512;
  float* f2  = ws + off; off += (size_t)BATCH * 256;
  int* idx = (int*)(ws + off);
  float* h5 = pd;

  transpose_x<<<(BATCH * NPTS * 3 + 255) / 256, 256, 0, stream>>>(x, xt);
  split_w5<<<(1024 * 512) / 256, 256, 0, stream>>>(w5, w5H, w5L);

  // ---------------- stage 1 (f32 path, K=3)
  compute_xx<<<64, 256, 0, stream>>>(xt, 3, 3, xx);
  gram_pd<<<dim3(16, 16, BATCH), 256, 0, stream>>>(xt, 3, 3, xx, pd);
  topk20<<<(BATCH * NPTS) / 4, 256, 0, stream>>>(pd, idx);
  prep_w2<<<(64 * 3 + 255) / 256, 256, 0, stream>>>(w1, W2f, W2H, W2L, 3, 64);
  gemm_ab_f32<<<dim3(2, (BATCH * NPTS) / 64), 256, 0, stream>>>(xt, W2f, Ab, Bb, 3, 64);
  gather_max_bn<<<(BATCH * NPTS) / 4, 256, 0, stream>>>(Ab, Bb, idx, bn1, catH, catL, 0, 64);

  // ---------------- stages 2..4 (bf16x3 MFMA path)
  struct Stage { int co; int C; int O; const float* w; const float* bnp; int hco; };
  Stage st[3] = {
    {0,   64,  64,  w2, bn2, 64},
    {64,  64,  128, w3, bn3, 128},
    {128, 128, 256, w4, bn4, 256},
  };
  for (int s = 0; s < 3; s++) {
    int C = st[s].C, O = st[s].O, co = st[s].co;
    compute_xx_bf<<<64, 256, 0, stream>>>(catH + co, catL + co, 512, C, xx);
    gram_mfma<<<dim3(8, 8, BATCH), 256, 0, stream>>>(catH + co, catL + co, 512, C, xx, pd);
    topk20<<<(BATCH * NPTS) / 4, 256, 0, stream>>>(pd, idx);
    prep_w2<<<(O * C + 255) / 256, 256, 0, stream>>>(st[s].w, W2f, W2H, W2L, C, O);
    mfma_gemm<1><<<dim3(2 * O / 128, (BATCH * NPTS) / 128), 256, 0, stream>>>(
        catH + co, catL + co, 512, W2H, W2L, C, C, 2 * O, nullptr, Ab, Bb);
    int npb = 256 / O;
    gather_max_bn<<<(BATCH * NPTS) / npb, 256, 0, stream>>>(Ab, Bb, idx, st[s].bnp, catH, catL, st[s].hco, O);
  }

  // ---------------- w5 GEMM (bf16x3 MFMA) + BN5 + LReLU
  mfma_gemm<0><<<dim3(8, (BATCH * NPTS) / 128), 256, 0, stream>>>(
      catH, catL, 512, w5H, w5L, 512, 512, 1024, bn5, h5, nullptr);

  pool_kernel<<<dim3(4, BATCH), 256, 0, stream>>>(h5, pooled);

  fc_kernel<<<(BATCH * 512 * 64) / 256, 256, 0, stream>>>(pooled, l1w, nullptr, bn6, f1, 2048, 512, 1);
  fc_kernel<<<(BATCH * 256 * 64) / 256, 256, 0, stream>>>(f1, l2w, l2b, bn7, f2, 512, 256, 1);
  fc_kernel<<<(BATCH * 40 * 64 + 255) / 256, 256, 0, stream>>>(f2, l3w, l3b, nullptr, out, 256, 40, 0);
}

// Round 4
// 522.461 us; speedup vs baseline: 1.9444x; 1.3275x over previous
//
#include <hip/hip_runtime.h>
#include <math.h>

#define BATCH 16
#define NPTS  1024
#define KNN   20
#define BNEPS 1e-5f

typedef __attribute__((ext_vector_type(8))) short bf16x8;
typedef __attribute__((ext_vector_type(4))) float f32x4;

__device__ __forceinline__ float bf2f(unsigned short h) {
  return __uint_as_float(((unsigned int)h) << 16);
}
__device__ __forceinline__ unsigned short f2bf(float f) {
  unsigned int u = __float_as_uint(f);
  u += 0x7fffu + ((u >> 16) & 1u);
  return (unsigned short)(u >> 16);
}

// ---------------------------------------------------------------- transpose
__global__ void transpose_x(const float* __restrict__ x, float* __restrict__ xt) {
  int i = blockIdx.x * 256 + threadIdx.x;
  if (i >= BATCH * NPTS * 3) return;
  int b = i / (NPTS * 3);
  int r = i - b * (NPTS * 3);
  int n = r / 3;
  int c = r - n * 3;
  xt[i] = x[(b * 3 + c) * NPTS + n];
}

// ---------------------------------------------------------------- w5 split to bf16 hi/lo
__global__ void split_w5(const float* __restrict__ w5, unsigned short* __restrict__ H,
                         unsigned short* __restrict__ L) {
  int i = blockIdx.x * 256 + threadIdx.x;
  if (i >= 1024 * 512) return;
  float v = w5[i];
  unsigned short h = f2bf(v);
  H[i] = h;
  L[i] = f2bf(v - bf2f(h));
}

// ---------------------------------------------------------------- xx = ||x||^2 (f32 feat)
__global__ void compute_xx(const float* __restrict__ feat, int ld, int C, float* __restrict__ xx) {
  int i = blockIdx.x * 256 + threadIdx.x;
  if (i >= BATCH * NPTS) return;
  const float* f = feat + (size_t)i * ld;
  float s = 0.f;
  for (int c = 0; c < C; c++) s = fmaf(f[c], f[c], s);
  xx[i] = s;
}

// ---------------------------------------------------------------- xx from bf16 hi/lo feat (vectorized)
__global__ void compute_xx_bf(const unsigned short* __restrict__ H, const unsigned short* __restrict__ L,
                              int ld, int C, float* __restrict__ xx) {
  int i = blockIdx.x * 256 + threadIdx.x;
  if (i >= BATCH * NPTS) return;
  const bf16x8* hp = (const bf16x8*)(H + (size_t)i * ld);
  const bf16x8* lp = (const bf16x8*)(L + (size_t)i * ld);
  float s = 0.f;
  for (int c8 = 0; c8 < C / 8; c8++) {
    bf16x8 h8 = hp[c8];
    bf16x8 l8 = lp[c8];
#pragma unroll
    for (int e = 0; e < 8; e++) {
      float a = bf2f((unsigned short)h8[e]) + bf2f((unsigned short)l8[e]);
      s = fmaf(a, a, s);
    }
  }
  xx[i] = s;
}

// ---------------------------------------------------------------- pd = 2*X.X^T - xx_n - xx_m (f32 feat, stage 1)
__global__ void gram_pd(const float* __restrict__ feat, int ld, int C, const float* __restrict__ xx,
                        float* __restrict__ pd) {
  __shared__ float As[16][68];
  __shared__ float Bs[16][68];
  int b = blockIdx.z;
  const float* xb = xx + b * NPTS;
  int m0 = blockIdx.y * 64, n0 = blockIdx.x * 64;
  int tid = threadIdx.x, tx = tid & 15, ty = tid >> 4;
  float acc[4][4] = {};
  for (int k0 = 0; k0 < C; k0 += 16) {
#pragma unroll
    for (int l = 0; l < 4; l++) {
      int e = tid + l * 256;
      int m = e >> 4, k = e & 15;
      float av = 0.f, bv = 0.f;
      if (k0 + k < C) {
        av = feat[(size_t)(b * NPTS + m0 + m) * ld + k0 + k];
        bv = feat[(size_t)(b * NPTS + n0 + m) * ld + k0 + k];
      }
      As[k][m] = av;
      Bs[k][m] = bv;
    }
    __syncthreads();
#pragma unroll
    for (int kk = 0; kk < 16; kk++) {
      float4 ra = *(const float4*)&As[kk][ty * 4];
      float4 rb = *(const float4*)&Bs[kk][tx * 4];
      float a[4] = {ra.x, ra.y, ra.z, ra.w};
      float w[4] = {rb.x, rb.y, rb.z, rb.w};
#pragma unroll
      for (int i2 = 0; i2 < 4; i2++)
#pragma unroll
        for (int j = 0; j < 4; j++)
          acc[i2][j] = fmaf(a[i2], w[j], acc[i2][j]);
    }
    __syncthreads();
  }
#pragma unroll
  for (int i2 = 0; i2 < 4; i2++) {
    int m = m0 + ty * 4 + i2;
    float xm = xb[m];
#pragma unroll
    for (int j = 0; j < 4; j++) {
      int n = n0 + tx * 4 + j;
      pd[((size_t)b * NPTS + m) * NPTS + n] = fmaf(2.f, acc[i2][j], -xm) - xb[n];
    }
  }
}

// ---------------------------------------------------------------- Gram via bf16x3 MFMA (stages 2-4)
__global__ __launch_bounds__(256) void gram_mfma(
    const unsigned short* __restrict__ H, const unsigned short* __restrict__ L,
    int ld, int C, const float* __restrict__ xx, float* __restrict__ pd) {
  __shared__ unsigned short lds[4][128 * 32];
  int tid = threadIdx.x;
  int lane = tid & 63, w = tid >> 6;
  int b = blockIdx.z;
  int n0 = blockIdx.x * 128, m0 = blockIdx.y * 128;
  int base = b * NPTS;
  int wrow = (w >> 1) * 64, wcol = (w & 1) * 64;

  f32x4 acc[4][4];
#pragma unroll
  for (int m = 0; m < 4; m++)
#pragma unroll
    for (int n = 0; n < 4; n++) acc[m][n] = (f32x4){0.f, 0.f, 0.f, 0.f};

  const unsigned short* gsrc = (w == 0 || w == 2) ? H : L;
  int b0 = (w < 2) ? m0 : n0;
  int srow = lane >> 2;
  int physChunk = lane & 3;
  int fr = lane & 15, ko = lane >> 4;

  for (int kt = 0; kt < C; kt += 32) {
#pragma unroll
    for (int i = 0; i < 8; i++) {
      int row = i * 16 + srow;
      int lchunk = physChunk ^ (row & 3);
      const unsigned short* g = gsrc + (size_t)(base + b0 + row) * ld + kt + lchunk * 8;
      unsigned short* l = &lds[w][i * 512];
      __builtin_amdgcn_global_load_lds(
          (const __attribute__((address_space(1))) unsigned int*)g,
          (__attribute__((address_space(3))) unsigned int*)l, 16, 0, 0);
    }
    __syncthreads();

    bf16x8 ah[4], al[4], bh[4], bl[4];
#pragma unroll
    for (int m = 0; m < 4; m++) {
      int row = wrow + m * 16 + fr;
      int off = row * 64 + ((ko ^ (row & 3)) * 16);
      ah[m] = *(const bf16x8*)((const char*)&lds[0][0] + off);
      al[m] = *(const bf16x8*)((const char*)&lds[1][0] + off);
    }
#pragma unroll
    for (int n = 0; n < 4; n++) {
      int row = wcol + n * 16 + fr;
      int off = row * 64 + ((ko ^ (row & 3)) * 16);
      bh[n] = *(const bf16x8*)((const char*)&lds[2][0] + off);
      bl[n] = *(const bf16x8*)((const char*)&lds[3][0] + off);
    }
#pragma unroll
    for (int m = 0; m < 4; m++)
#pragma unroll
      for (int n = 0; n < 4; n++) {
        acc[m][n] = __builtin_amdgcn_mfma_f32_16x16x32_bf16(ah[m], bh[n], acc[m][n], 0, 0, 0);
        acc[m][n] = __builtin_amdgcn_mfma_f32_16x16x32_bf16(al[m], bh[n], acc[m][n], 0, 0, 0);
        acc[m][n] = __builtin_amdgcn_mfma_f32_16x16x32_bf16(ah[m], bl[n], acc[m][n], 0, 0, 0);
      }
    __syncthreads();
  }

  int fq = lane >> 4;
#pragma unroll
  for (int n = 0; n < 4; n++) {
    int gc = n0 + wcol + n * 16 + fr;
    float xn = xx[base + gc];
#pragma unroll
    for (int m = 0; m < 4; m++)
#pragma unroll
      for (int r = 0; r < 4; r++) {
        int gr = m0 + wrow + m * 16 + fq * 4 + r;
        pd[((size_t)(base + gr)) * NPTS + gc] = fmaf(2.f, acc[m][n][r], -xx[base + gr]) - xn;
      }
  }
}

// ---------------------------------------------------------------- top-20 SET per row via radix-select
// key = monotone uint map of float; bisect threshold X; emit {key>X} + lowest-index equals.
// idx order is irrelevant downstream (unordered gather-max), set matches lax.top_k semantics.
__global__ void topk20(const float* __restrict__ pd, int* __restrict__ idx) {
  int tid = threadIdx.x, lane = tid & 63, w = tid >> 6;
  int row = blockIdx.x * 4 + w;
  const float* p = pd + (size_t)row * NPTS;
  unsigned key[16];
#pragma unroll
  for (int s = 0; s < 16; s++) {
    unsigned b = __float_as_uint(p[lane + s * 64]);
    key[s] = b ^ ((((int)b >> 31) | 0x80000000u));
  }

  unsigned P = 0;
  bool found = false;
  for (int bit = 31; bit >= 0; --bit) {
    unsigned T = P | (1u << bit);
    int c = 0;
#pragma unroll
    for (int s = 0; s < 16; s++)
      c += __popcll(__ballot(key[s] >= T));
    if (c >= 20) {
      P = T;
      if (c == 20) { found = true; break; }
    }
  }
  // X = P. Write all key > X (order-free), then key == X in ascending (s,lane) = ascending index.
  unsigned long long ltmask = (1ull << lane) - 1ull;
  int* o = idx + row * KNN;
  int base = 0;
#pragma unroll
  for (int s = 0; s < 16; s++) {
    unsigned long long m = __ballot(key[s] > P);
    if (key[s] > P) {
      int pos = base + __popcll(m & ltmask);
      o[pos] = s * 64 + lane;
    }
    base += __popcll(m);
  }
#pragma unroll
  for (int s = 0; s < 16; s++) {
    unsigned long long m = __ballot(key[s] == P);
    if (key[s] == P) {
      int pos = base + __popcll(m & ltmask);
      if (pos < KNN) o[pos] = s * 64 + lane;
    }
    base += __popcll(m);
  }
}

// ---------------------------------------------------------------- W2 = [wl ; wr-wl] (f32 + bf16 hi/lo)
__global__ void prep_w2(const float* __restrict__ w, float* __restrict__ W2f,
                        unsigned short* __restrict__ W2H, unsigned short* __restrict__ W2L,
                        int C, int O) {
  int i = blockIdx.x * 256 + threadIdx.x;
  if (i >= O * C) return;
  int o = i / C, c = i - o * C;
  float wl = w[o * 2 * C + c];
  float d  = w[o * 2 * C + C + c] - wl;
  W2f[(size_t)o * C + c]       = wl;
  W2f[(size_t)(O + o) * C + c] = d;
  unsigned short h1 = f2bf(wl);
  W2H[(size_t)o * C + c] = h1;
  W2L[(size_t)o * C + c] = f2bf(wl - bf2f(h1));
  unsigned short h2 = f2bf(d);
  W2H[(size_t)(O + o) * C + c] = h2;
  W2L[(size_t)(O + o) * C + c] = f2bf(d - bf2f(h2));
}

// ---------------------------------------------------------------- f32 GEMM for stage 1 (K=3)
__global__ void gemm_ab_f32(const float* __restrict__ feat, const float* __restrict__ W2,
                            float* __restrict__ Ab, float* __restrict__ Bb, int K, int O) {
  __shared__ float As[16][68];
  __shared__ float Ws[16][68];
  int n0 = blockIdx.x * 64, m0 = blockIdx.y * 64;
  int tid = threadIdx.x, tx = tid & 15, ty = tid >> 4;
  float acc[4][4] = {};
  for (int k0 = 0; k0 < K; k0 += 16) {
#pragma unroll
    for (int l = 0; l < 4; l++) {
      int e = tid + l * 256;
      int m = e >> 4, k = e & 15;
      As[k][m] = (k0 + k < K) ? feat[(size_t)(m0 + m) * K + k0 + k] : 0.f;
      Ws[k][m] = (k0 + k < K) ? W2[(size_t)(n0 + m) * K + k0 + k] : 0.f;
    }
    __syncthreads();
#pragma unroll
    for (int kk = 0; kk < 16; kk++) {
      float4 ra = *(const float4*)&As[kk][ty * 4];
      float4 rb = *(const float4*)&Ws[kk][tx * 4];
      float a[4] = {ra.x, ra.y, ra.z, ra.w};
      float w[4] = {rb.x, rb.y, rb.z, rb.w};
#pragma unroll
      for (int i2 = 0; i2 < 4; i2++)
#pragma unroll
        for (int j = 0; j < 4; j++)
          acc[i2][j] = fmaf(a[i2], w[j], acc[i2][j]);
    }
    __syncthreads();
  }
#pragma unroll
  for (int i2 = 0; i2 < 4; i2++) {
    int row = m0 + ty * 4 + i2;
#pragma unroll
    for (int j = 0; j < 4; j++) {
      int col = n0 + tx * 4 + j;
      if (col < O) Ab[(size_t)row * O + col] = acc[i2][j];
      else         Bb[(size_t)row * O + (col - O)] = acc[i2][j];
    }
  }
}

// ---------------------------------------------------------------- bf16x3 MFMA GEMM: C = A*B^T
template<int EPI>
__global__ __launch_bounds__(256) void mfma_gemm(
    const unsigned short* __restrict__ AH, const unsigned short* __restrict__ AL, int lda,
    const unsigned short* __restrict__ BH, const unsigned short* __restrict__ BL, int ldb,
    int K, int N, const float* __restrict__ bnp,
    float* __restrict__ out0, float* __restrict__ out1) {
  __shared__ unsigned short lds[4][128 * 32];
  int tid = threadIdx.x;
  int lane = tid & 63, w = tid >> 6;
  int n0 = blockIdx.x * 128, m0 = blockIdx.y * 128;
  int wrow = (w >> 1) * 64, wcol = (w & 1) * 64;

  f32x4 acc[4][4];
#pragma unroll
  for (int m = 0; m < 4; m++)
#pragma unroll
    for (int n = 0; n < 4; n++) acc[m][n] = (f32x4){0.f, 0.f, 0.f, 0.f};

  const unsigned short* gsrc = (w == 0) ? AH : (w == 1) ? AL : (w == 2) ? BH : BL;
  int ld = (w < 2) ? lda : ldb;
  int b0 = (w < 2) ? m0 : n0;
  int srow = lane >> 2;
  int physChunk = lane & 3;
  int fr = lane & 15, ko = lane >> 4;

  for (int kt = 0; kt < K; kt += 32) {
#pragma unroll
    for (int i = 0; i < 8; i++) {
      int row = i * 16 + srow;
      int lchunk = physChunk ^ (row & 3);
      const unsigned short* g = gsrc + (size_t)(b0 + row) * ld + kt + lchunk * 8;
      unsigned short* l = &lds[w][i * 512];
      __builtin_amdgcn_global_load_lds(
          (const __attribute__((address_space(1))) unsigned int*)g,
          (__attribute__((address_space(3))) unsigned int*)l, 16, 0, 0);
    }
    __syncthreads();

    bf16x8 ah[4], al[4], bh[4], bl[4];
#pragma unroll
    for (int m = 0; m < 4; m++) {
      int row = wrow + m * 16 + fr;
      int off = row * 64 + ((ko ^ (row & 3)) * 16);
      ah[m] = *(const bf16x8*)((const char*)&lds[0][0] + off);
      al[m] = *(const bf16x8*)((const char*)&lds[1][0] + off);
    }
#pragma unroll
    for (int n = 0; n < 4; n++) {
      int row = wcol + n * 16 + fr;
      int off = row * 64 + ((ko ^ (row & 3)) * 16);
      bh[n] = *(const bf16x8*)((const char*)&lds[2][0] + off);
      bl[n] = *(const bf16x8*)((const char*)&lds[3][0] + off);
    }
#pragma unroll
    for (int m = 0; m < 4; m++)
#pragma unroll
      for (int n = 0; n < 4; n++) {
        acc[m][n] = __builtin_amdgcn_mfma_f32_16x16x32_bf16(ah[m], bh[n], acc[m][n], 0, 0, 0);
        acc[m][n] = __builtin_amdgcn_mfma_f32_16x16x32_bf16(al[m], bh[n], acc[m][n], 0, 0, 0);
        acc[m][n] = __builtin_amdgcn_mfma_f32_16x16x32_bf16(ah[m], bl[n], acc[m][n], 0, 0, 0);
      }
    __syncthreads();
  }

  int fq = lane >> 4;
#pragma unroll
  for (int n = 0; n < 4; n++) {
    int gc = n0 + wcol + n * 16 + fr;
    if (EPI == 0) {
      float g = bnp[gc], bt = bnp[N + gc], mu = bnp[2 * N + gc], va = bnp[3 * N + gc];
      float sc = g * rsqrtf(va + BNEPS);
#pragma unroll
      for (int m = 0; m < 4; m++)
#pragma unroll
        for (int r = 0; r < 4; r++) {
          int gr = m0 + wrow + m * 16 + fq * 4 + r;
          float y = sc * (acc[m][n][r] - mu) + bt;
          out0[(size_t)gr * N + gc] = y >= 0.f ? y : 0.2f * y;
        }
    } else {
      int O = N >> 1;
      float* dst = (gc < O) ? out0 : out1;
      int cc = (gc < O) ? gc : gc - O;
#pragma unroll
      for (int m = 0; m < 4; m++)
#pragma unroll
        for (int r = 0; r < 4; r++) {
          int gr = m0 + wrow + m * 16 + fq * 4 + r;
          dst[(size_t)gr * O + cc] = acc[m][n][r];
        }
    }
  }
}

// ---------------------------------------------------------------- gather + max_k + BN + LReLU -> bf16 hi/lo cat
__global__ void gather_max_bn(const float* __restrict__ Ab, const float* __restrict__ Bb,
                              const int* __restrict__ idx, const float* __restrict__ bnp,
                              unsigned short* __restrict__ catH, unsigned short* __restrict__ catL,
                              int co, int O) {
  int tid = threadIdx.x;
  int npb = 256 / O;
  int local_n = tid / O;
  int o = tid - local_n * O;
  int pt = blockIdx.x * npb + local_n;
  int b = pt >> 10;
  const int* ix = idx + pt * KNN;
  const float* Abase = Ab + ((size_t)(b << 10)) * O;
  float m = -INFINITY;
#pragma unroll 4
  for (int k = 0; k < KNN; k++)
    m = fmaxf(m, Abase[(size_t)ix[k] * O + o]);
  float h = m + Bb[(size_t)pt * O + o];
  float g = bnp[o], bt = bnp[O + o], mu = bnp[2 * O + o], va = bnp[3 * O + o];
  float y = g * (h - mu) * rsqrtf(va + BNEPS) + bt;
  y = y >= 0.f ? y : 0.2f * y;
  unsigned short hh = f2bf(y);
  size_t dst = (size_t)pt * 512 + co + o;
  catH[dst] = hh;
  catL[dst] = f2bf(y - bf2f(hh));
}

// ---------------------------------------------------------------- max + mean pool over N
__global__ void pool_kernel(const float* __restrict__ h5, float* __restrict__ pooled) {
  int c = blockIdx.x * 256 + threadIdx.x;
  int b = blockIdx.y;
  const float* p = h5 + (size_t)b * NPTS * 1024 + c;
  float mx = -INFINITY, sm = 0.f;
  for (int n = 0; n < NPTS; n++) {
    float v = p[(size_t)n * 1024];
    mx = fmaxf(mx, v);
    sm += v;
  }
  pooled[b * 2048 + c] = mx;
  pooled[b * 2048 + 1024 + c] = sm * (1.f / 1024.f);
}

// ---------------------------------------------------------------- FC: wave per output
__global__ void fc_kernel(const float* __restrict__ in, const float* __restrict__ w,
                          const float* __restrict__ bias, const float* __restrict__ bnp,
                          float* __restrict__ out, int Cin, int Cout, int act) {
  int g = blockIdx.x * blockDim.x + threadIdx.x;
  int wid = g >> 6, lane = g & 63;
  if (wid >= BATCH * Cout) return;
  int b = wid / Cout, o = wid - b * Cout;
  const float* xp = in + (size_t)b * Cin;
  const float* wp = w + (size_t)o * Cin;
  float s = 0.f;
  for (int c = lane; c < Cin; c += 64) s = fmaf(xp[c], wp[c], s);
#pragma unroll
  for (int off = 32; off; off >>= 1) s += __shfl_xor(s, off);
  if (lane == 0) {
    if (bias) s += bias[o];
    if (act) {
      float gm = bnp[o], bt = bnp[Cout + o], mu = bnp[2 * Cout + o], va = bnp[3 * Cout + o];
      s = gm * (s - mu) * rsqrtf(va + BNEPS) + bt;
      s = s >= 0.f ? s : 0.2f * s;
    }
    out[wid] = s;
  }
}

// ================================================================ launch
extern "C" void kernel_launch(void* const* d_in, const int* in_sizes, int n_in,
                              void* d_out, int out_size, void* d_ws, size_t ws_size,
                              hipStream_t stream) {
  const float* x   = (const float*)d_in[0];
  const float* w1  = (const float*)d_in[1];
  const float* w2  = (const float*)d_in[2];
  const float* w3  = (const float*)d_in[3];
  const float* w4  = (const float*)d_in[4];
  const float* w5  = (const float*)d_in[5];
  const float* bn1 = (const float*)d_in[6];
  const float* bn2 = (const float*)d_in[7];
  const float* bn3 = (const float*)d_in[8];
  const float* bn4 = (const float*)d_in[9];
  const float* bn5 = (const float*)d_in[10];
  const float* bn6 = (const float*)d_in[11];
  const float* bn7 = (const float*)d_in[12];
  const float* l1w = (const float*)d_in[13];
  const float* l2w = (const float*)d_in[14];
  const float* l2b = (const float*)d_in[15];
  const float* l3w = (const float*)d_in[16];
  const float* l3b = (const float*)d_in[17];
  float* out = (float*)d_out;

  float* ws = (float*)d_ws;
  size_t off = 0;
  float* xt  = ws + off; off += (size_t)BATCH * NPTS * 3;
  float* xx  = ws + off; off += (size_t)BATCH * NPTS;
  float* W2f = ws + off; off += (size_t)512 * 128;
  unsigned short* W2H = (unsigned short*)(ws + off); off += (size_t)512 * 128 / 2;
  unsigned short* W2L = (unsigned short*)(ws + off); off += (size_t)512 * 128 / 2;
  unsigned short* w5H = (unsigned short*)(ws + off); off += (size_t)1024 * 512 / 2;
  unsigned short* w5L = (unsigned short*)(ws + off); off += (size_t)1024 * 512 / 2;
  float* Ab  = ws + off; off += (size_t)BATCH * NPTS * 256;
  float* Bb  = ws + off; off += (size_t)BATCH * NPTS * 256;
  unsigned short* catH = (unsigned short*)(ws + off); off += (size_t)BATCH * NPTS * 512 / 2;
  unsigned short* catL = (unsigned short*)(ws + off); off += (size_t)BATCH * NPTS * 512 / 2;
  float* pd  = ws + off; off += (size_t)BATCH * NPTS * NPTS;   // reused as h5
  float* pooled = ws + off; off += (size_t)BATCH * 2048;
  float* f1  = ws + off; off += (size_t)BATCH * 512;
  float* f2  = ws + off; off += (size_t)BATCH * 256;
  int* idx = (int*)(ws + off);
  float* h5 = pd;

  transpose_x<<<(BATCH * NPTS * 3 + 255) / 256, 256, 0, stream>>>(x, xt);
  split_w5<<<(1024 * 512) / 256, 256, 0, stream>>>(w5, w5H, w5L);

  // ---------------- stage 1 (f32 path, K=3)
  compute_xx<<<64, 256, 0, stream>>>(xt, 3, 3, xx);
  gram_pd<<<dim3(16, 16, BATCH), 256, 0, stream>>>(xt, 3, 3, xx, pd);
  topk20<<<(BATCH * NPTS) / 4, 256, 0, stream>>>(pd, idx);
  prep_w2<<<(64 * 3 + 255) / 256, 256, 0, stream>>>(w1, W2f, W2H, W2L, 3, 64);
  gemm_ab_f32<<<dim3(2, (BATCH * NPTS) / 64), 256, 0, stream>>>(xt, W2f, Ab, Bb, 3, 64);
  gather_max_bn<<<(BATCH * NPTS) / 4, 256, 0, stream>>>(Ab, Bb, idx, bn1, catH, catL, 0, 64);

  // ---------------- stages 2..4 (bf16x3 MFMA path)
  struct Stage { int co; int C; int O; const float* w; const float* bnp; int hco; };
  Stage st[3] = {
    {0,   64,  64,  w2, bn2, 64},
    {64,  64,  128, w3, bn3, 128},
    {128, 128, 256, w4, bn4, 256},
  };
  for (int s = 0; s < 3; s++) {
    int C = st[s].C, O = st[s].O, co = st[s].co;
    compute_xx_bf<<<64, 256, 0, stream>>>(catH + co, catL + co, 512, C, xx);
    gram_mfma<<<dim3(8, 8, BATCH), 256, 0, stream>>>(catH + co, catL + co, 512, C, xx, pd);
    topk20<<<(BATCH * NPTS) / 4, 256, 0, stream>>>(pd, idx);
    prep_w2<<<(O * C + 255) / 256, 256, 0, stream>>>(st[s].w, W2f, W2H, W2L, C, O);
    mfma_gemm<1><<<dim3(2 * O / 128, (BATCH * NPTS) / 128), 256, 0, stream>>>(
        catH + co, catL + co, 512, W2H, W2L, C, C, 2 * O, nullptr, Ab, Bb);
    int npb = 256 / O;
    gather_max_bn<<<(BATCH * NPTS) / npb, 256, 0, stream>>>(Ab, Bb, idx, st[s].bnp, catH, catL, st[s].hco, O);
  }

  // ---------------- w5 GEMM (bf16x3 MFMA) + BN5 + LReLU
  mfma_gemm<0><<<dim3(8, (BATCH * NPTS) / 128), 256, 0, stream>>>(
      catH, catL, 512, w5H, w5L, 512, 512, 1024, bn5, h5, nullptr);

  pool_kernel<<<dim3(4, BATCH), 256, 0, stream>>>(h5, pooled);

  fc_kernel<<<(BATCH * 512 * 64) / 256, 256, 0, stream>>>(pooled, l1w, nullptr, bn6, f1, 2048, 512, 1);
  fc_kernel<<<(BATCH * 256 * 64) / 256, 256, 0, stream>>>(f1, l2w, l2b, bn7, f2, 512, 256, 1);
  fc_kernel<<<(BATCH * 40 * 64 + 255) / 256, 256, 0, stream>>>(f2, l3w, l3b, nullptr, out, 256, 40, 0);
}

// Round 5
// 455.469 us; speedup vs baseline: 2.2304x; 1.1471x over previous
//
#include <hip/hip_runtime.h>
#include <math.h>

#define BATCH 16
#define NPTS  1024
#define KNN   20
#define BNEPS 1e-5f

typedef __attribute__((ext_vector_type(8))) short bf16x8;
typedef __attribute__((ext_vector_type(4))) float f32x4;

__device__ __forceinline__ float bf2f(unsigned short h) {
  return __uint_as_float(((unsigned int)h) << 16);
}
__device__ __forceinline__ unsigned short f2bf(float f) {
  unsigned int u = __float_as_uint(f);
  u += 0x7fffu + ((u >> 16) & 1u);
  return (unsigned short)(u >> 16);
}

// ---------------------------------------------------------------- transpose
__global__ void transpose_x(const float* __restrict__ x, float* __restrict__ xt) {
  int i = blockIdx.x * 256 + threadIdx.x;
  if (i >= BATCH * NPTS * 3) return;
  int b = i / (NPTS * 3);
  int r = i - b * (NPTS * 3);
  int n = r / 3;
  int c = r - n * 3;
  xt[i] = x[(b * 3 + c) * NPTS + n];
}

// ---------------------------------------------------------------- w5 split to bf16 hi/lo
__global__ void split_w5(const float* __restrict__ w5, unsigned short* __restrict__ H,
                         unsigned short* __restrict__ L) {
  int i = blockIdx.x * 256 + threadIdx.x;
  if (i >= 1024 * 512) return;
  float v = w5[i];
  unsigned short h = f2bf(v);
  H[i] = h;
  L[i] = f2bf(v - bf2f(h));
}

// ---------------------------------------------------------------- xx = ||x||^2 (f32 feat)
__global__ void compute_xx(const float* __restrict__ feat, int ld, int C, float* __restrict__ xx) {
  int i = blockIdx.x * 256 + threadIdx.x;
  if (i >= BATCH * NPTS) return;
  const float* f = feat + (size_t)i * ld;
  float s = 0.f;
  for (int c = 0; c < C; c++) s = fmaf(f[c], f[c], s);
  xx[i] = s;
}

// ---------------------------------------------------------------- xx from bf16 hi/lo feat (vectorized)
__global__ void compute_xx_bf(const unsigned short* __restrict__ H, const unsigned short* __restrict__ L,
                              int ld, int C, float* __restrict__ xx) {
  int i = blockIdx.x * 256 + threadIdx.x;
  if (i >= BATCH * NPTS) return;
  const bf16x8* hp = (const bf16x8*)(H + (size_t)i * ld);
  const bf16x8* lp = (const bf16x8*)(L + (size_t)i * ld);
  float s = 0.f;
  for (int c8 = 0; c8 < C / 8; c8++) {
    bf16x8 h8 = hp[c8];
    bf16x8 l8 = lp[c8];
#pragma unroll
    for (int e = 0; e < 8; e++) {
      float a = bf2f((unsigned short)h8[e]) + bf2f((unsigned short)l8[e]);
      s = fmaf(a, a, s);
    }
  }
  xx[i] = s;
}

// ---------------------------------------------------------------- pd = 2*X.X^T - xx_n - xx_m (f32 feat, stage 1)
__global__ void gram_pd(const float* __restrict__ feat, int ld, int C, const float* __restrict__ xx,
                        float* __restrict__ pd) {
  __shared__ float As[16][68];
  __shared__ float Bs[16][68];
  int b = blockIdx.z;
  const float* xb = xx + b * NPTS;
  int m0 = blockIdx.y * 64, n0 = blockIdx.x * 64;
  int tid = threadIdx.x, tx = tid & 15, ty = tid >> 4;
  float acc[4][4] = {};
  for (int k0 = 0; k0 < C; k0 += 16) {
#pragma unroll
    for (int l = 0; l < 4; l++) {
      int e = tid + l * 256;
      int m = e >> 4, k = e & 15;
      float av = 0.f, bv = 0.f;
      if (k0 + k < C) {
        av = feat[(size_t)(b * NPTS + m0 + m) * ld + k0 + k];
        bv = feat[(size_t)(b * NPTS + n0 + m) * ld + k0 + k];
      }
      As[k][m] = av;
      Bs[k][m] = bv;
    }
    __syncthreads();
#pragma unroll
    for (int kk = 0; kk < 16; kk++) {
      float4 ra = *(const float4*)&As[kk][ty * 4];
      float4 rb = *(const float4*)&Bs[kk][tx * 4];
      float a[4] = {ra.x, ra.y, ra.z, ra.w};
      float w[4] = {rb.x, rb.y, rb.z, rb.w};
#pragma unroll
      for (int i2 = 0; i2 < 4; i2++)
#pragma unroll
        for (int j = 0; j < 4; j++)
          acc[i2][j] = fmaf(a[i2], w[j], acc[i2][j]);
    }
    __syncthreads();
  }
#pragma unroll
  for (int i2 = 0; i2 < 4; i2++) {
    int m = m0 + ty * 4 + i2;
    float xm = xb[m];
#pragma unroll
    for (int j = 0; j < 4; j++) {
      int n = n0 + tx * 4 + j;
      pd[((size_t)b * NPTS + m) * NPTS + n] = fmaf(2.f, acc[i2][j], -xm) - xb[n];
    }
  }
}

// ---------------------------------------------------------------- Gram via bf16x3 MFMA (stages 2-4)
// XCD-chunked swizzle: each XCD owns 2 whole batches (1024 blocks, 128/XCD).
__global__ __launch_bounds__(256) void gram_mfma(
    const unsigned short* __restrict__ H, const unsigned short* __restrict__ L,
    int ld, int C, const float* __restrict__ xx, float* __restrict__ pd) {
  __shared__ unsigned short lds[4][128 * 32];
  int tid = threadIdx.x;
  int lane = tid & 63, w = tid >> 6;
  int d = blockIdx.x + 8 * blockIdx.y + 64 * blockIdx.z;   // grid (8,8,16)
  int nd = (d & 7) * 128 + (d >> 3);
  int b = nd >> 6;
  int rem = nd & 63;
  int m0 = (rem >> 3) * 128, n0 = (rem & 7) * 128;
  int base = b * NPTS;
  int wrow = (w >> 1) * 64, wcol = (w & 1) * 64;

  f32x4 acc[4][4];
#pragma unroll
  for (int m = 0; m < 4; m++)
#pragma unroll
    for (int n = 0; n < 4; n++) acc[m][n] = (f32x4){0.f, 0.f, 0.f, 0.f};

  const unsigned short* gsrc = (w == 0 || w == 2) ? H : L;
  int b0 = (w < 2) ? m0 : n0;
  int srow = lane >> 2;
  int physChunk = lane & 3;
  int fr = lane & 15, ko = lane >> 4;

  for (int kt = 0; kt < C; kt += 32) {
#pragma unroll
    for (int i = 0; i < 8; i++) {
      int row = i * 16 + srow;
      int lchunk = physChunk ^ (row & 3);
      const unsigned short* g = gsrc + (size_t)(base + b0 + row) * ld + kt + lchunk * 8;
      unsigned short* l = &lds[w][i * 512];
      __builtin_amdgcn_global_load_lds(
          (const __attribute__((address_space(1))) unsigned int*)g,
          (__attribute__((address_space(3))) unsigned int*)l, 16, 0, 0);
    }
    __syncthreads();

    bf16x8 ah[4], al[4], bh[4], bl[4];
#pragma unroll
    for (int m = 0; m < 4; m++) {
      int row = wrow + m * 16 + fr;
      int off = row * 64 + ((ko ^ (row & 3)) * 16);
      ah[m] = *(const bf16x8*)((const char*)&lds[0][0] + off);
      al[m] = *(const bf16x8*)((const char*)&lds[1][0] + off);
    }
#pragma unroll
    for (int n = 0; n < 4; n++) {
      int row = wcol + n * 16 + fr;
      int off = row * 64 + ((ko ^ (row & 3)) * 16);
      bh[n] = *(const bf16x8*)((const char*)&lds[2][0] + off);
      bl[n] = *(const bf16x8*)((const char*)&lds[3][0] + off);
    }
#pragma unroll
    for (int m = 0; m < 4; m++)
#pragma unroll
      for (int n = 0; n < 4; n++) {
        acc[m][n] = __builtin_amdgcn_mfma_f32_16x16x32_bf16(ah[m], bh[n], acc[m][n], 0, 0, 0);
        acc[m][n] = __builtin_amdgcn_mfma_f32_16x16x32_bf16(al[m], bh[n], acc[m][n], 0, 0, 0);
        acc[m][n] = __builtin_amdgcn_mfma_f32_16x16x32_bf16(ah[m], bl[n], acc[m][n], 0, 0, 0);
      }
    __syncthreads();
  }

  int fq = lane >> 4;
#pragma unroll
  for (int n = 0; n < 4; n++) {
    int gc = n0 + wcol + n * 16 + fr;
    float xn = xx[base + gc];
#pragma unroll
    for (int m = 0; m < 4; m++)
#pragma unroll
      for (int r = 0; r < 4; r++) {
        int gr = m0 + wrow + m * 16 + fq * 4 + r;
        pd[((size_t)(base + gr)) * NPTS + gc] = fmaf(2.f, acc[m][n][r], -xx[base + gr]) - xn;
      }
  }
}

// ---------------------------------------------------------------- top-20 SET per row via radix-select
__global__ void topk20(const float* __restrict__ pd, int* __restrict__ idx) {
  int tid = threadIdx.x, lane = tid & 63, w = tid >> 6;
  int row = blockIdx.x * 4 + w;
  const float* p = pd + (size_t)row * NPTS;
  unsigned key[16];
#pragma unroll
  for (int s = 0; s < 16; s++) {
    unsigned b = __float_as_uint(p[lane + s * 64]);
    key[s] = b ^ ((((int)b >> 31) | 0x80000000u));
  }

  unsigned P = 0;
  for (int bit = 31; bit >= 0; --bit) {
    unsigned T = P | (1u << bit);
    int c = 0;
#pragma unroll
    for (int s = 0; s < 16; s++)
      c += __popcll(__ballot(key[s] >= T));
    if (c >= 20) {
      P = T;
      if (c == 20) break;
    }
  }
  unsigned long long ltmask = (1ull << lane) - 1ull;
  int* o = idx + row * KNN;
  int base = 0;
#pragma unroll
  for (int s = 0; s < 16; s++) {
    unsigned long long m = __ballot(key[s] > P);
    if (key[s] > P) {
      int pos = base + __popcll(m & ltmask);
      o[pos] = s * 64 + lane;
    }
    base += __popcll(m);
  }
#pragma unroll
  for (int s = 0; s < 16; s++) {
    unsigned long long m = __ballot(key[s] == P);
    if (key[s] == P) {
      int pos = base + __popcll(m & ltmask);
      if (pos < KNN) o[pos] = s * 64 + lane;
    }
    base += __popcll(m);
  }
}

// ---------------------------------------------------------------- W2 = [wl ; wr-wl] (f32 + bf16 hi/lo)
__global__ void prep_w2(const float* __restrict__ w, float* __restrict__ W2f,
                        unsigned short* __restrict__ W2H, unsigned short* __restrict__ W2L,
                        int C, int O) {
  int i = blockIdx.x * 256 + threadIdx.x;
  if (i >= O * C) return;
  int o = i / C, c = i - o * C;
  float wl = w[o * 2 * C + c];
  float d  = w[o * 2 * C + C + c] - wl;
  W2f[(size_t)o * C + c]       = wl;
  W2f[(size_t)(O + o) * C + c] = d;
  unsigned short h1 = f2bf(wl);
  W2H[(size_t)o * C + c] = h1;
  W2L[(size_t)o * C + c] = f2bf(wl - bf2f(h1));
  unsigned short h2 = f2bf(d);
  W2H[(size_t)(O + o) * C + c] = h2;
  W2L[(size_t)(O + o) * C + c] = f2bf(d - bf2f(h2));
}

// ---------------------------------------------------------------- f32 GEMM for stage 1 (K=3)
__global__ void gemm_ab_f32(const float* __restrict__ feat, const float* __restrict__ W2,
                            float* __restrict__ Ab, float* __restrict__ Bb, int K, int O) {
  __shared__ float As[16][68];
  __shared__ float Ws[16][68];
  int n0 = blockIdx.x * 64, m0 = blockIdx.y * 64;
  int tid = threadIdx.x, tx = tid & 15, ty = tid >> 4;
  float acc[4][4] = {};
  for (int k0 = 0; k0 < K; k0 += 16) {
#pragma unroll
    for (int l = 0; l < 4; l++) {
      int e = tid + l * 256;
      int m = e >> 4, k = e & 15;
      As[k][m] = (k0 + k < K) ? feat[(size_t)(m0 + m) * K + k0 + k] : 0.f;
      Ws[k][m] = (k0 + k < K) ? W2[(size_t)(n0 + m) * K + k0 + k] : 0.f;
    }
    __syncthreads();
#pragma unroll
    for (int kk = 0; kk < 16; kk++) {
      float4 ra = *(const float4*)&As[kk][ty * 4];
      float4 rb = *(const float4*)&Ws[kk][tx * 4];
      float a[4] = {ra.x, ra.y, ra.z, ra.w};
      float w[4] = {rb.x, rb.y, rb.z, rb.w};
#pragma unroll
      for (int i2 = 0; i2 < 4; i2++)
#pragma unroll
        for (int j = 0; j < 4; j++)
          acc[i2][j] = fmaf(a[i2], w[j], acc[i2][j]);
    }
    __syncthreads();
  }
#pragma unroll
  for (int i2 = 0; i2 < 4; i2++) {
    int row = m0 + ty * 4 + i2;
#pragma unroll
    for (int j = 0; j < 4; j++) {
      int col = n0 + tx * 4 + j;
      if (col < O) Ab[(size_t)row * O + col] = acc[i2][j];
      else         Bb[(size_t)row * O + (col - O)] = acc[i2][j];
    }
  }
}

// ---------------------------------------------------------------- bf16x3 MFMA GEMM: C = A*B^T
// EPI=1: split cols O=N/2 -> out0/out1 (raw acc).
// EPI=2: BN(bnp)+LReLU then per-block col max/sum over 128 rows -> out0=pmax, out1=psum
//        partial row-block index = m0>>7, layout [128][1024].
template<int EPI>
__global__ __launch_bounds__(256) void mfma_gemm(
    const unsigned short* __restrict__ AH, const unsigned short* __restrict__ AL, int lda,
    const unsigned short* __restrict__ BH, const unsigned short* __restrict__ BL, int ldb,
    int K, int N, const float* __restrict__ bnp,
    float* __restrict__ out0, float* __restrict__ out1) {
  __shared__ unsigned short lds[4][128 * 32];
  __shared__ float pm[128];
  __shared__ float ps[128];
  int tid = threadIdx.x;
  int lane = tid & 63, w = tid >> 6;
  // XCD-chunked bijective swizzle (total blocks % 8 == 0 for all launches)
  int total = gridDim.x * gridDim.y;
  int d = blockIdx.x + gridDim.x * blockIdx.y;
  int nd = (d & 7) * (total >> 3) + (d >> 3);
  int n0 = (nd % gridDim.x) * 128;
  int m0 = (nd / gridDim.x) * 128;
  int wrow = (w >> 1) * 64, wcol = (w & 1) * 64;

  f32x4 acc[4][4];
#pragma unroll
  for (int m = 0; m < 4; m++)
#pragma unroll
    for (int n = 0; n < 4; n++) acc[m][n] = (f32x4){0.f, 0.f, 0.f, 0.f};

  const unsigned short* gsrc = (w == 0) ? AH : (w == 1) ? AL : (w == 2) ? BH : BL;
  int ld = (w < 2) ? lda : ldb;
  int b0 = (w < 2) ? m0 : n0;
  int srow = lane >> 2;
  int physChunk = lane & 3;
  int fr = lane & 15, ko = lane >> 4;

  for (int kt = 0; kt < K; kt += 32) {
#pragma unroll
    for (int i = 0; i < 8; i++) {
      int row = i * 16 + srow;
      int lchunk = physChunk ^ (row & 3);
      const unsigned short* g = gsrc + (size_t)(b0 + row) * ld + kt + lchunk * 8;
      unsigned short* l = &lds[w][i * 512];
      __builtin_amdgcn_global_load_lds(
          (const __attribute__((address_space(1))) unsigned int*)g,
          (__attribute__((address_space(3))) unsigned int*)l, 16, 0, 0);
    }
    __syncthreads();

    bf16x8 ah[4], al[4], bh[4], bl[4];
#pragma unroll
    for (int m = 0; m < 4; m++) {
      int row = wrow + m * 16 + fr;
      int off = row * 64 + ((ko ^ (row & 3)) * 16);
      ah[m] = *(const bf16x8*)((const char*)&lds[0][0] + off);
      al[m] = *(const bf16x8*)((const char*)&lds[1][0] + off);
    }
#pragma unroll
    for (int n = 0; n < 4; n++) {
      int row = wcol + n * 16 + fr;
      int off = row * 64 + ((ko ^ (row & 3)) * 16);
      bh[n] = *(const bf16x8*)((const char*)&lds[2][0] + off);
      bl[n] = *(const bf16x8*)((const char*)&lds[3][0] + off);
    }
#pragma unroll
    for (int m = 0; m < 4; m++)
#pragma unroll
      for (int n = 0; n < 4; n++) {
        acc[m][n] = __builtin_amdgcn_mfma_f32_16x16x32_bf16(ah[m], bh[n], acc[m][n], 0, 0, 0);
        acc[m][n] = __builtin_amdgcn_mfma_f32_16x16x32_bf16(al[m], bh[n], acc[m][n], 0, 0, 0);
        acc[m][n] = __builtin_amdgcn_mfma_f32_16x16x32_bf16(ah[m], bl[n], acc[m][n], 0, 0, 0);
      }
    __syncthreads();
  }

  int fq = lane >> 4;
  if (EPI == 1) {
#pragma unroll
    for (int n = 0; n < 4; n++) {
      int gc = n0 + wcol + n * 16 + fr;
      int O = N >> 1;
      float* dst = (gc < O) ? out0 : out1;
      int cc = (gc < O) ? gc : gc - O;
#pragma unroll
      for (int m = 0; m < 4; m++)
#pragma unroll
        for (int r = 0; r < 4; r++) {
          int gr = m0 + wrow + m * 16 + fq * 4 + r;
          dst[(size_t)gr * O + cc] = acc[m][n][r];
        }
    }
  } else {
    // BN + LReLU + col-pool (max,sum) over this block's 128 rows
    float cmax[4], csum[4];
#pragma unroll
    for (int n = 0; n < 4; n++) {
      int gc = n0 + wcol + n * 16 + fr;
      float g = bnp[gc], bt = bnp[N + gc], mu = bnp[2 * N + gc], va = bnp[3 * N + gc];
      float sc = g * rsqrtf(va + BNEPS);
      float mx = -INFINITY, sm = 0.f;
#pragma unroll
      for (int m = 0; m < 4; m++)
#pragma unroll
        for (int r = 0; r < 4; r++) {
          float y = sc * (acc[m][n][r] - mu) + bt;
          y = y >= 0.f ? y : 0.2f * y;
          mx = fmaxf(mx, y);
          sm += y;
        }
      // reduce across fq (lanes ^16, ^32 share the same column)
      mx = fmaxf(mx, __shfl_xor(mx, 16));
      mx = fmaxf(mx, __shfl_xor(mx, 32));
      sm += __shfl_xor(sm, 16);
      sm += __shfl_xor(sm, 32);
      cmax[n] = mx;
      csum[n] = sm;
    }
    // cross-wave combine: waves 2,3 (wrow=64) publish, waves 0,1 merge+store
    if (w >= 2 && fq == 0) {
#pragma unroll
      for (int n = 0; n < 4; n++) {
        pm[wcol + n * 16 + fr] = cmax[n];
        ps[wcol + n * 16 + fr] = csum[n];
      }
    }
    __syncthreads();
    if (w < 2 && fq == 0) {
      int rb = m0 >> 7;
#pragma unroll
      for (int n = 0; n < 4; n++) {
        int cc = wcol + n * 16 + fr;
        int gc = n0 + cc;
        out0[(size_t)rb * 1024 + gc] = fmaxf(cmax[n], pm[cc]);
        out1[(size_t)rb * 1024 + gc] = csum[n] + ps[cc];
      }
    }
  }
}

// ---------------------------------------------------------------- fold 8 row-block partials per batch
__global__ void reduce_pool(const float* __restrict__ pmax, const float* __restrict__ psum,
                            float* __restrict__ pooled) {
  int c = blockIdx.x * 256 + threadIdx.x;   // 0..1023
  int b = blockIdx.y;
  float mx = -INFINITY, sm = 0.f;
#pragma unroll
  for (int i = 0; i < 8; i++) {
    int rb = b * 8 + i;
    mx = fmaxf(mx, pmax[(size_t)rb * 1024 + c]);
    sm += psum[(size_t)rb * 1024 + c];
  }
  pooled[b * 2048 + c] = mx;
  pooled[b * 2048 + 1024 + c] = sm * (1.f / 1024.f);
}

// ---------------------------------------------------------------- gather + max_k + BN + LReLU -> bf16 hi/lo cat
__global__ void gather_max_bn(const float* __restrict__ Ab, const float* __restrict__ Bb,
                              const int* __restrict__ idx, const float* __restrict__ bnp,
                              unsigned short* __restrict__ catH, unsigned short* __restrict__ catL,
                              int co, int O) {
  int tid = threadIdx.x;
  int npb = 256 / O;
  int local_n = tid / O;
  int o = tid - local_n * O;
  int pt = blockIdx.x * npb + local_n;
  int b = pt >> 10;
  const int* ix = idx + pt * KNN;
  const float* Abase = Ab + ((size_t)(b << 10)) * O;
  float m = -INFINITY;
#pragma unroll 4
  for (int k = 0; k < KNN; k++)
    m = fmaxf(m, Abase[(size_t)ix[k] * O + o]);
  float h = m + Bb[(size_t)pt * O + o];
  float g = bnp[o], bt = bnp[O + o], mu = bnp[2 * O + o], va = bnp[3 * O + o];
  float y = g * (h - mu) * rsqrtf(va + BNEPS) + bt;
  y = y >= 0.f ? y : 0.2f * y;
  unsigned short hh = f2bf(y);
  size_t dst = (size_t)pt * 512 + co + o;
  catH[dst] = hh;
  catL[dst] = f2bf(y - bf2f(hh));
}

// ---------------------------------------------------------------- FC: wave per output
__global__ void fc_kernel(const float* __restrict__ in, const float* __restrict__ w,
                          const float* __restrict__ bias, const float* __restrict__ bnp,
                          float* __restrict__ out, int Cin, int Cout, int act) {
  int g = blockIdx.x * blockDim.x + threadIdx.x;
  int wid = g >> 6, lane = g & 63;
  if (wid >= BATCH * Cout) return;
  int b = wid / Cout, o = wid - b * Cout;
  const float* xp = in + (size_t)b * Cin;
  const float* wp = w + (size_t)o * Cin;
  float s = 0.f;
  for (int c = lane; c < Cin; c += 64) s = fmaf(xp[c], wp[c], s);
#pragma unroll
  for (int off = 32; off; off >>= 1) s += __shfl_xor(s, off);
  if (lane == 0) {
    if (bias) s += bias[o];
    if (act) {
      float gm = bnp[o], bt = bnp[Cout + o], mu = bnp[2 * Cout + o], va = bnp[3 * Cout + o];
      s = gm * (s - mu) * rsqrtf(va + BNEPS) + bt;
      s = s >= 0.f ? s : 0.2f * s;
    }
    out[wid] = s;
  }
}

// ================================================================ launch
extern "C" void kernel_launch(void* const* d_in, const int* in_sizes, int n_in,
                              void* d_out, int out_size, void* d_ws, size_t ws_size,
                              hipStream_t stream) {
  const float* x   = (const float*)d_in[0];
  const float* w1  = (const float*)d_in[1];
  const float* w2  = (const float*)d_in[2];
  const float* w3  = (const float*)d_in[3];
  const float* w4  = (const float*)d_in[4];
  const float* w5  = (const float*)d_in[5];
  const float* bn1 = (const float*)d_in[6];
  const float* bn2 = (const float*)d_in[7];
  const float* bn3 = (const float*)d_in[8];
  const float* bn4 = (const float*)d_in[9];
  const float* bn5 = (const float*)d_in[10];
  const float* bn6 = (const float*)d_in[11];
  const float* bn7 = (const float*)d_in[12];
  const float* l1w = (const float*)d_in[13];
  const float* l2w = (const float*)d_in[14];
  const float* l2b = (const float*)d_in[15];
  const float* l3w = (const float*)d_in[16];
  const float* l3b = (const float*)d_in[17];
  float* out = (float*)d_out;

  float* ws = (float*)d_ws;
  size_t off = 0;
  float* xt  = ws + off; off += (size_t)BATCH * NPTS * 3;
  float* xx  = ws + off; off += (size_t)BATCH * NPTS;
  float* W2f = ws + off; off += (size_t)512 * 128;
  unsigned short* W2H = (unsigned short*)(ws + off); off += (size_t)512 * 128 / 2;
  unsigned short* W2L = (unsigned short*)(ws + off); off += (size_t)512 * 128 / 2;
  unsigned short* w5H = (unsigned short*)(ws + off); off += (size_t)1024 * 512 / 2;
  unsigned short* w5L = (unsigned short*)(ws + off); off += (size_t)1024 * 512 / 2;
  float* Ab  = ws + off; off += (size_t)BATCH * NPTS * 256;
  float* Bb  = ws + off; off += (size_t)BATCH * NPTS * 256;
  unsigned short* catH = (unsigned short*)(ws + off); off += (size_t)BATCH * NPTS * 512 / 2;
  unsigned short* catL = (unsigned short*)(ws + off); off += (size_t)BATCH * NPTS * 512 / 2;
  float* pd  = ws + off; off += (size_t)BATCH * NPTS * NPTS;
  float* pmax = ws + off; off += (size_t)128 * 1024;
  float* psum = ws + off; off += (size_t)128 * 1024;
  float* pooled = ws + off; off += (size_t)BATCH * 2048;
  float* f1  = ws + off; off += (size_t)BATCH * 512;
  float* f2  = ws + off; off += (size_t)BATCH * 256;
  int* idx = (int*)(ws + off);

  transpose_x<<<(BATCH * NPTS * 3 + 255) / 256, 256, 0, stream>>>(x, xt);
  split_w5<<<(1024 * 512) / 256, 256, 0, stream>>>(w5, w5H, w5L);

  // ---------------- stage 1 (f32 path, K=3)
  compute_xx<<<64, 256, 0, stream>>>(xt, 3, 3, xx);
  gram_pd<<<dim3(16, 16, BATCH), 256, 0, stream>>>(xt, 3, 3, xx, pd);
  topk20<<<(BATCH * NPTS) / 4, 256, 0, stream>>>(pd, idx);
  prep_w2<<<(64 * 3 + 255) / 256, 256, 0, stream>>>(w1, W2f, W2H, W2L, 3, 64);
  gemm_ab_f32<<<dim3(2, (BATCH * NPTS) / 64), 256, 0, stream>>>(xt, W2f, Ab, Bb, 3, 64);
  gather_max_bn<<<(BATCH * NPTS) / 4, 256, 0, stream>>>(Ab, Bb, idx, bn1, catH, catL, 0, 64);

  // ---------------- stages 2..4 (bf16x3 MFMA path)
  struct Stage { int co; int C; int O; const float* w; const float* bnp; int hco; };
  Stage st[3] = {
    {0,   64,  64,  w2, bn2, 64},
    {64,  64,  128, w3, bn3, 128},
    {128, 128, 256, w4, bn4, 256},
  };
  for (int s = 0; s < 3; s++) {
    int C = st[s].C, O = st[s].O, co = st[s].co;
    compute_xx_bf<<<64, 256, 0, stream>>>(catH + co, catL + co, 512, C, xx);
    gram_mfma<<<dim3(8, 8, BATCH), 256, 0, stream>>>(catH + co, catL + co, 512, C, xx, pd);
    topk20<<<(BATCH * NPTS) / 4, 256, 0, stream>>>(pd, idx);
    prep_w2<<<(O * C + 255) / 256, 256, 0, stream>>>(st[s].w, W2f, W2H, W2L, C, O);
    mfma_gemm<1><<<dim3(2 * O / 128, (BATCH * NPTS) / 128), 256, 0, stream>>>(
        catH + co, catL + co, 512, W2H, W2L, C, C, 2 * O, nullptr, Ab, Bb);
    int npb = 256 / O;
    gather_max_bn<<<(BATCH * NPTS) / npb, 256, 0, stream>>>(Ab, Bb, idx, st[s].bnp, catH, catL, st[s].hco, O);
  }

  // ---------------- w5 GEMM + BN5 + LReLU + fused max/mean pool
  mfma_gemm<2><<<dim3(8, (BATCH * NPTS) / 128), 256, 0, stream>>>(
      catH, catL, 512, w5H, w5L, 512, 512, 1024, bn5, pmax, psum);
  reduce_pool<<<dim3(4, BATCH), 256, 0, stream>>>(pmax, psum, pooled);

  fc_kernel<<<(BATCH * 512 * 64) / 256, 256, 0, stream>>>(pooled, l1w, nullptr, bn6, f1, 2048, 512, 1);
  fc_kernel<<<(BATCH * 256 * 64) / 256, 256, 0, stream>>>(f1, l2w, l2b, bn7, f2, 512, 256, 1);
  fc_kernel<<<(BATCH * 40 * 64 + 255) / 256, 256, 0, stream>>>(f2, l3w, l3b, nullptr, out, 256, 40, 0);
}

// Round 6
// 343.003 us; speedup vs baseline: 2.9617x; 1.3279x over previous
//
#include <hip/hip_runtime.h>
#include <math.h>

#define BATCH 16
#define NPTS  1024
#define KNN   20
#define BNEPS 1e-5f

typedef __attribute__((ext_vector_type(8))) short bf16x8;
typedef __attribute__((ext_vector_type(4))) float f32x4;
typedef __attribute__((ext_vector_type(4))) unsigned short u16x4;

__device__ __forceinline__ float bf2f(unsigned short h) {
  return __uint_as_float(((unsigned int)h) << 16);
}
__device__ __forceinline__ unsigned short f2bf(float f) {
  unsigned int u = __float_as_uint(f);
  u += 0x7fffu + ((u >> 16) & 1u);
  return (unsigned short)(u >> 16);
}

// ---------------------------------------------------------------- transpose
__global__ void transpose_x(const float* __restrict__ x, float* __restrict__ xt) {
  int i = blockIdx.x * 256 + threadIdx.x;
  if (i >= BATCH * NPTS * 3) return;
  int b = i / (NPTS * 3);
  int r = i - b * (NPTS * 3);
  int n = r / 3;
  int c = r - n * 3;
  xt[i] = x[(b * 3 + c) * NPTS + n];
}

// ---------------------------------------------------------------- w5 split to bf16 hi/lo
__global__ void split_w5(const float* __restrict__ w5, unsigned short* __restrict__ H,
                         unsigned short* __restrict__ L) {
  int i = blockIdx.x * 256 + threadIdx.x;
  if (i >= 1024 * 512) return;
  float v = w5[i];
  unsigned short h = f2bf(v);
  H[i] = h;
  L[i] = f2bf(v - bf2f(h));
}

// ---------------------------------------------------------------- xx = ||x||^2 (f32 feat, stage 1)
__global__ void compute_xx(const float* __restrict__ feat, int ld, int C, float* __restrict__ xx) {
  int i = blockIdx.x * 256 + threadIdx.x;
  if (i >= BATCH * NPTS) return;
  const float* f = feat + (size_t)i * ld;
  float s = 0.f;
  for (int c = 0; c < C; c++) s = fmaf(f[c], f[c], s);
  xx[i] = s;
}

// ---------------------------------------------------------------- pd = 2*X.X^T - xx_n - xx_m (f32 feat, stage 1)
__global__ void gram_pd(const float* __restrict__ feat, int ld, int C, const float* __restrict__ xx,
                        float* __restrict__ pd) {
  __shared__ float As[16][68];
  __shared__ float Bs[16][68];
  int b = blockIdx.z;
  const float* xb = xx + b * NPTS;
  int m0 = blockIdx.y * 64, n0 = blockIdx.x * 64;
  int tid = threadIdx.x, tx = tid & 15, ty = tid >> 4;
  float acc[4][4] = {};
  for (int k0 = 0; k0 < C; k0 += 16) {
#pragma unroll
    for (int l = 0; l < 4; l++) {
      int e = tid + l * 256;
      int m = e >> 4, k = e & 15;
      float av = 0.f, bv = 0.f;
      if (k0 + k < C) {
        av = feat[(size_t)(b * NPTS + m0 + m) * ld + k0 + k];
        bv = feat[(size_t)(b * NPTS + n0 + m) * ld + k0 + k];
      }
      As[k][m] = av;
      Bs[k][m] = bv;
    }
    __syncthreads();
#pragma unroll
    for (int kk = 0; kk < 16; kk++) {
      float4 ra = *(const float4*)&As[kk][ty * 4];
      float4 rb = *(const float4*)&Bs[kk][tx * 4];
      float a[4] = {ra.x, ra.y, ra.z, ra.w};
      float w[4] = {rb.x, rb.y, rb.z, rb.w};
#pragma unroll
      for (int i2 = 0; i2 < 4; i2++)
#pragma unroll
        for (int j = 0; j < 4; j++)
          acc[i2][j] = fmaf(a[i2], w[j], acc[i2][j]);
    }
    __syncthreads();
  }
#pragma unroll
  for (int i2 = 0; i2 < 4; i2++) {
    int m = m0 + ty * 4 + i2;
    float xm = xb[m];
#pragma unroll
    for (int j = 0; j < 4; j++) {
      int n = n0 + tx * 4 + j;
      pd[((size_t)b * NPTS + m) * NPTS + n] = fmaf(2.f, acc[i2][j], -xm) - xb[n];
    }
  }
}

// ---------------------------------------------------------------- Gram via bf16x3 MFMA (stages 2-4)
__global__ __launch_bounds__(256) void gram_mfma(
    const unsigned short* __restrict__ H, const unsigned short* __restrict__ L,
    int ld, int C, const float* __restrict__ xx, float* __restrict__ pd) {
  __shared__ unsigned short lds[4][128 * 32];
  int tid = threadIdx.x;
  int lane = tid & 63, w = tid >> 6;
  int d = blockIdx.x + 8 * blockIdx.y + 64 * blockIdx.z;   // grid (8,8,16)
  int nd = (d & 7) * 128 + (d >> 3);
  int b = nd >> 6;
  int rem = nd & 63;
  int m0 = (rem >> 3) * 128, n0 = (rem & 7) * 128;
  int base = b * NPTS;
  int wrow = (w >> 1) * 64, wcol = (w & 1) * 64;

  f32x4 acc[4][4];
#pragma unroll
  for (int m = 0; m < 4; m++)
#pragma unroll
    for (int n = 0; n < 4; n++) acc[m][n] = (f32x4){0.f, 0.f, 0.f, 0.f};

  const unsigned short* gsrc = (w == 0 || w == 2) ? H : L;
  int b0 = (w < 2) ? m0 : n0;
  int srow = lane >> 2;
  int physChunk = lane & 3;
  int fr = lane & 15, ko = lane >> 4;

  for (int kt = 0; kt < C; kt += 32) {
#pragma unroll
    for (int i = 0; i < 8; i++) {
      int row = i * 16 + srow;
      int lchunk = physChunk ^ (row & 3);
      const unsigned short* g = gsrc + (size_t)(base + b0 + row) * ld + kt + lchunk * 8;
      unsigned short* l = &lds[w][i * 512];
      __builtin_amdgcn_global_load_lds(
          (const __attribute__((address_space(1))) unsigned int*)g,
          (__attribute__((address_space(3))) unsigned int*)l, 16, 0, 0);
    }
    __syncthreads();

    bf16x8 ah[4], al[4], bh[4], bl[4];
#pragma unroll
    for (int m = 0; m < 4; m++) {
      int row = wrow + m * 16 + fr;
      int off = row * 64 + ((ko ^ (row & 3)) * 16);
      ah[m] = *(const bf16x8*)((const char*)&lds[0][0] + off);
      al[m] = *(const bf16x8*)((const char*)&lds[1][0] + off);
    }
#pragma unroll
    for (int n = 0; n < 4; n++) {
      int row = wcol + n * 16 + fr;
      int off = row * 64 + ((ko ^ (row & 3)) * 16);
      bh[n] = *(const bf16x8*)((const char*)&lds[2][0] + off);
      bl[n] = *(const bf16x8*)((const char*)&lds[3][0] + off);
    }
#pragma unroll
    for (int m = 0; m < 4; m++)
#pragma unroll
      for (int n = 0; n < 4; n++) {
        acc[m][n] = __builtin_amdgcn_mfma_f32_16x16x32_bf16(ah[m], bh[n], acc[m][n], 0, 0, 0);
        acc[m][n] = __builtin_amdgcn_mfma_f32_16x16x32_bf16(al[m], bh[n], acc[m][n], 0, 0, 0);
        acc[m][n] = __builtin_amdgcn_mfma_f32_16x16x32_bf16(ah[m], bl[n], acc[m][n], 0, 0, 0);
      }
    __syncthreads();
  }

  int fq = lane >> 4;
#pragma unroll
  for (int n = 0; n < 4; n++) {
    int gc = n0 + wcol + n * 16 + fr;
    float xn = xx[base + gc];
#pragma unroll
    for (int m = 0; m < 4; m++)
#pragma unroll
      for (int r = 0; r < 4; r++) {
        int gr = m0 + wrow + m * 16 + fq * 4 + r;
        pd[((size_t)(base + gr)) * NPTS + gc] = fmaf(2.f, acc[m][n][r], -xx[base + gr]) - xn;
      }
  }
}

// ---------------------------------------------------------------- top-20 SET per row via radix-select
__global__ void topk20(const float* __restrict__ pd, int* __restrict__ idx) {
  int tid = threadIdx.x, lane = tid & 63, w = tid >> 6;
  int row = blockIdx.x * 4 + w;
  const float* p = pd + (size_t)row * NPTS;
  unsigned key[16];
#pragma unroll
  for (int s = 0; s < 16; s++) {
    unsigned b = __float_as_uint(p[lane + s * 64]);
    key[s] = b ^ ((((int)b >> 31) | 0x80000000u));
  }

  unsigned P = 0;
  for (int bit = 31; bit >= 0; --bit) {
    unsigned T = P | (1u << bit);
    int c = 0;
#pragma unroll
    for (int s = 0; s < 16; s++)
      c += __popcll(__ballot(key[s] >= T));
    if (c >= 20) {
      P = T;
      if (c == 20) break;
    }
  }
  unsigned long long ltmask = (1ull << lane) - 1ull;
  int* o = idx + row * KNN;
  int base = 0;
#pragma unroll
  for (int s = 0; s < 16; s++) {
    unsigned long long m = __ballot(key[s] > P);
    if (key[s] > P) {
      int pos = base + __popcll(m & ltmask);
      o[pos] = s * 64 + lane;
    }
    base += __popcll(m);
  }
#pragma unroll
  for (int s = 0; s < 16; s++) {
    unsigned long long m = __ballot(key[s] == P);
    if (key[s] == P) {
      int pos = base + __popcll(m & ltmask);
      if (pos < KNN) o[pos] = s * 64 + lane;
    }
    base += __popcll(m);
  }
}

// ---------------------------------------------------------------- W2 = [wl ; wr-wl] (f32 + bf16 hi/lo)
__global__ void prep_w2(const float* __restrict__ w, float* __restrict__ W2f,
                        unsigned short* __restrict__ W2H, unsigned short* __restrict__ W2L,
                        int C, int O) {
  int i = blockIdx.x * 256 + threadIdx.x;
  if (i >= O * C) return;
  int o = i / C, c = i - o * C;
  float wl = w[o * 2 * C + c];
  float d  = w[o * 2 * C + C + c] - wl;
  W2f[(size_t)o * C + c]       = wl;
  W2f[(size_t)(O + o) * C + c] = d;
  unsigned short h1 = f2bf(wl);
  W2H[(size_t)o * C + c] = h1;
  W2L[(size_t)o * C + c] = f2bf(wl - bf2f(h1));
  unsigned short h2 = f2bf(d);
  W2H[(size_t)(O + o) * C + c] = h2;
  W2L[(size_t)(O + o) * C + c] = f2bf(d - bf2f(h2));
}

// ---------------------------------------------------------------- f32 GEMM for stage 1 (K=3)
__global__ void gemm_ab_f32(const float* __restrict__ feat, const float* __restrict__ W2,
                            float* __restrict__ Ab, float* __restrict__ Bb, int K, int O) {
  __shared__ float As[16][68];
  __shared__ float Ws[16][68];
  int n0 = blockIdx.x * 64, m0 = blockIdx.y * 64;
  int tid = threadIdx.x, tx = tid & 15, ty = tid >> 4;
  float acc[4][4] = {};
  for (int k0 = 0; k0 < K; k0 += 16) {
#pragma unroll
    for (int l = 0; l < 4; l++) {
      int e = tid + l * 256;
      int m = e >> 4, k = e & 15;
      As[k][m] = (k0 + k < K) ? feat[(size_t)(m0 + m) * K + k0 + k] : 0.f;
      Ws[k][m] = (k0 + k < K) ? W2[(size_t)(n0 + m) * K + k0 + k] : 0.f;
    }
    __syncthreads();
#pragma unroll
    for (int kk = 0; kk < 16; kk++) {
      float4 ra = *(const float4*)&As[kk][ty * 4];
      float4 rb = *(const float4*)&Ws[kk][tx * 4];
      float a[4] = {ra.x, ra.y, ra.z, ra.w};
      float w[4] = {rb.x, rb.y, rb.z, rb.w};
#pragma unroll
      for (int i2 = 0; i2 < 4; i2++)
#pragma unroll
        for (int j = 0; j < 4; j++)
          acc[i2][j] = fmaf(a[i2], w[j], acc[i2][j]);
    }
    __syncthreads();
  }
#pragma unroll
  for (int i2 = 0; i2 < 4; i2++) {
    int row = m0 + ty * 4 + i2;
#pragma unroll
    for (int j = 0; j < 4; j++) {
      int col = n0 + tx * 4 + j;
      if (col < O) Ab[(size_t)row * O + col] = acc[i2][j];
      else         Bb[(size_t)row * O + (col - O)] = acc[i2][j];
    }
  }
}

// ---------------------------------------------------------------- bf16x3 MFMA GEMM: C = A*B^T
// EPI=1: split cols O=N/2 -> out0/out1 (raw acc).
// EPI=2: BN+LReLU then per-block col max/sum -> out0=pmax, out1=psum [128][1024]
template<int EPI>
__global__ __launch_bounds__(256) void mfma_gemm(
    const unsigned short* __restrict__ AH, const unsigned short* __restrict__ AL, int lda,
    const unsigned short* __restrict__ BH, const unsigned short* __restrict__ BL, int ldb,
    int K, int N, const float* __restrict__ bnp,
    float* __restrict__ out0, float* __restrict__ out1) {
  __shared__ unsigned short lds[4][128 * 32];
  __shared__ float pm[128];
  __shared__ float ps[128];
  int tid = threadIdx.x;
  int lane = tid & 63, w = tid >> 6;
  int total = gridDim.x * gridDim.y;
  int d = blockIdx.x + gridDim.x * blockIdx.y;
  int nd = (d & 7) * (total >> 3) + (d >> 3);
  int n0 = (nd % gridDim.x) * 128;
  int m0 = (nd / gridDim.x) * 128;
  int wrow = (w >> 1) * 64, wcol = (w & 1) * 64;

  f32x4 acc[4][4];
#pragma unroll
  for (int m = 0; m < 4; m++)
#pragma unroll
    for (int n = 0; n < 4; n++) acc[m][n] = (f32x4){0.f, 0.f, 0.f, 0.f};

  const unsigned short* gsrc = (w == 0) ? AH : (w == 1) ? AL : (w == 2) ? BH : BL;
  int ld = (w < 2) ? lda : ldb;
  int b0 = (w < 2) ? m0 : n0;
  int srow = lane >> 2;
  int physChunk = lane & 3;
  int fr = lane & 15, ko = lane >> 4;

  for (int kt = 0; kt < K; kt += 32) {
#pragma unroll
    for (int i = 0; i < 8; i++) {
      int row = i * 16 + srow;
      int lchunk = physChunk ^ (row & 3);
      const unsigned short* g = gsrc + (size_t)(b0 + row) * ld + kt + lchunk * 8;
      unsigned short* l = &lds[w][i * 512];
      __builtin_amdgcn_global_load_lds(
          (const __attribute__((address_space(1))) unsigned int*)g,
          (__attribute__((address_space(3))) unsigned int*)l, 16, 0, 0);
    }
    __syncthreads();

    bf16x8 ah[4], al[4], bh[4], bl[4];
#pragma unroll
    for (int m = 0; m < 4; m++) {
      int row = wrow + m * 16 + fr;
      int off = row * 64 + ((ko ^ (row & 3)) * 16);
      ah[m] = *(const bf16x8*)((const char*)&lds[0][0] + off);
      al[m] = *(const bf16x8*)((const char*)&lds[1][0] + off);
    }
#pragma unroll
    for (int n = 0; n < 4; n++) {
      int row = wcol + n * 16 + fr;
      int off = row * 64 + ((ko ^ (row & 3)) * 16);
      bh[n] = *(const bf16x8*)((const char*)&lds[2][0] + off);
      bl[n] = *(const bf16x8*)((const char*)&lds[3][0] + off);
    }
#pragma unroll
    for (int m = 0; m < 4; m++)
#pragma unroll
      for (int n = 0; n < 4; n++) {
        acc[m][n] = __builtin_amdgcn_mfma_f32_16x16x32_bf16(ah[m], bh[n], acc[m][n], 0, 0, 0);
        acc[m][n] = __builtin_amdgcn_mfma_f32_16x16x32_bf16(al[m], bh[n], acc[m][n], 0, 0, 0);
        acc[m][n] = __builtin_amdgcn_mfma_f32_16x16x32_bf16(ah[m], bl[n], acc[m][n], 0, 0, 0);
      }
    __syncthreads();
  }

  int fq = lane >> 4;
  if (EPI == 1) {
#pragma unroll
    for (int n = 0; n < 4; n++) {
      int gc = n0 + wcol + n * 16 + fr;
      int O = N >> 1;
      float* dst = (gc < O) ? out0 : out1;
      int cc = (gc < O) ? gc : gc - O;
#pragma unroll
      for (int m = 0; m < 4; m++)
#pragma unroll
        for (int r = 0; r < 4; r++) {
          int gr = m0 + wrow + m * 16 + fq * 4 + r;
          dst[(size_t)gr * O + cc] = acc[m][n][r];
        }
    }
  } else {
    float cmax[4], csum[4];
#pragma unroll
    for (int n = 0; n < 4; n++) {
      int gc = n0 + wcol + n * 16 + fr;
      float g = bnp[gc], bt = bnp[N + gc], mu = bnp[2 * N + gc], va = bnp[3 * N + gc];
      float sc = g * rsqrtf(va + BNEPS);
      float mx = -INFINITY, sm = 0.f;
#pragma unroll
      for (int m = 0; m < 4; m++)
#pragma unroll
        for (int r = 0; r < 4; r++) {
          float y = sc * (acc[m][n][r] - mu) + bt;
          y = y >= 0.f ? y : 0.2f * y;
          mx = fmaxf(mx, y);
          sm += y;
        }
      mx = fmaxf(mx, __shfl_xor(mx, 16));
      mx = fmaxf(mx, __shfl_xor(mx, 32));
      sm += __shfl_xor(sm, 16);
      sm += __shfl_xor(sm, 32);
      cmax[n] = mx;
      csum[n] = sm;
    }
    if (w >= 2 && fq == 0) {
#pragma unroll
      for (int n = 0; n < 4; n++) {
        pm[wcol + n * 16 + fr] = cmax[n];
        ps[wcol + n * 16 + fr] = csum[n];
      }
    }
    __syncthreads();
    if (w < 2 && fq == 0) {
      int rb = m0 >> 7;
#pragma unroll
      for (int n = 0; n < 4; n++) {
        int cc = wcol + n * 16 + fr;
        int gc = n0 + cc;
        out0[(size_t)rb * 1024 + gc] = fmaxf(cmax[n], pm[cc]);
        out1[(size_t)rb * 1024 + gc] = csum[n] + ps[cc];
      }
    }
  }
}

// ---------------------------------------------------------------- fold 8 row-block partials per batch
__global__ void reduce_pool(const float* __restrict__ pmax, const float* __restrict__ psum,
                            float* __restrict__ pooled) {
  int c = blockIdx.x * 256 + threadIdx.x;
  int b = blockIdx.y;
  float mx = -INFINITY, sm = 0.f;
#pragma unroll
  for (int i = 0; i < 8; i++) {
    int rb = b * 8 + i;
    mx = fmaxf(mx, pmax[(size_t)rb * 1024 + c]);
    sm += psum[(size_t)rb * 1024 + c];
  }
  pooled[b * 2048 + c] = mx;
  pooled[b * 2048 + 1024 + c] = sm * (1.f / 1024.f);
}

// ---------------------------------------------------------------- gather + max_k + BN + LReLU -> bf16 hi/lo cat
// float4 per lane; LPP = O/4 lanes per point; XCD-chunked swizzle; optional fused
// xx = sum (hi+lo)^2 for the NEXT stage (bit-identical to the old compute_xx_bf).
template<int O, int XXOUT>
__global__ void gather_max_bn(const float* __restrict__ Ab, const float* __restrict__ Bb,
                              const int* __restrict__ idx, const float* __restrict__ bnp,
                              unsigned short* __restrict__ catH, unsigned short* __restrict__ catL,
                              float* __restrict__ xx, int co) {
  constexpr int LPP = O / 4;            // lanes per point
  constexpr int PPB = 1024 / O;         // points per 256-thread block
  int tid = threadIdx.x;
  int lp = tid / LPP;
  int cl = tid - lp * LPP;
  int nblk = gridDim.x;
  int d = blockIdx.x;
  int nd = (d & 7) * (nblk >> 3) + (d >> 3);   // XCD-chunked (nblk % 8 == 0)
  int pt = nd * PPB + lp;
  int b = pt >> 10;
  const int* ix = idx + pt * KNN;
  const float4* Ab4 = (const float4*)Ab + (size_t)(b << 10) * LPP;

  float4 mx = {-INFINITY, -INFINITY, -INFINITY, -INFINITY};
#pragma unroll
  for (int k = 0; k < KNN; k++) {
    float4 v = Ab4[(size_t)ix[k] * LPP + cl];
    mx.x = fmaxf(mx.x, v.x);
    mx.y = fmaxf(mx.y, v.y);
    mx.z = fmaxf(mx.z, v.z);
    mx.w = fmaxf(mx.w, v.w);
  }
  float4 bb = ((const float4*)Bb)[(size_t)pt * LPP + cl];
  int o = cl * 4;
  float4 gg = *(const float4*)(bnp + o);
  float4 bt = *(const float4*)(bnp + O + o);
  float4 mu = *(const float4*)(bnp + 2 * O + o);
  float4 va = *(const float4*)(bnp + 3 * O + o);

  float h[4] = {mx.x + bb.x, mx.y + bb.y, mx.z + bb.z, mx.w + bb.w};
  float G[4] = {gg.x, gg.y, gg.z, gg.w};
  float B[4] = {bt.x, bt.y, bt.z, bt.w};
  float M[4] = {mu.x, mu.y, mu.z, mu.w};
  float V[4] = {va.x, va.y, va.z, va.w};

  u16x4 hh, ll;
  float xs = 0.f;
#pragma unroll
  for (int e = 0; e < 4; e++) {
    float y = G[e] * (h[e] - M[e]) * rsqrtf(V[e] + BNEPS) + B[e];
    y = y >= 0.f ? y : 0.2f * y;
    unsigned short yh = f2bf(y);
    float fh = bf2f(yh);
    unsigned short yl = f2bf(y - fh);
    hh[e] = yh;
    ll[e] = yl;
    if (XXOUT) {
      float a = fh + bf2f(yl);
      xs = fmaf(a, a, xs);
    }
  }
  size_t dst = (size_t)pt * 512 + co + o;
  *(u16x4*)(catH + dst) = hh;
  *(u16x4*)(catL + dst) = ll;

  if (XXOUT) {
#pragma unroll
    for (int s = 1; s < LPP; s <<= 1) xs += __shfl_xor(xs, s);
    if (cl == 0) xx[pt] = xs;
  }
}

// ---------------------------------------------------------------- FC: wave per output
__global__ void fc_kernel(const float* __restrict__ in, const float* __restrict__ w,
                          const float* __restrict__ bias, const float* __restrict__ bnp,
                          float* __restrict__ out, int Cin, int Cout, int act) {
  int g = blockIdx.x * blockDim.x + threadIdx.x;
  int wid = g >> 6, lane = g & 63;
  if (wid >= BATCH * Cout) return;
  int b = wid / Cout, o = wid - b * Cout;
  const float* xp = in + (size_t)b * Cin;
  const float* wp = w + (size_t)o * Cin;
  float s = 0.f;
  for (int c = lane; c < Cin; c += 64) s = fmaf(xp[c], wp[c], s);
#pragma unroll
  for (int off = 32; off; off >>= 1) s += __shfl_xor(s, off);
  if (lane == 0) {
    if (bias) s += bias[o];
    if (act) {
      float gm = bnp[o], bt = bnp[Cout + o], mu = bnp[2 * Cout + o], va = bnp[3 * Cout + o];
      s = gm * (s - mu) * rsqrtf(va + BNEPS) + bt;
      s = s >= 0.f ? s : 0.2f * s;
    }
    out[wid] = s;
  }
}

// ================================================================ launch
extern "C" void kernel_launch(void* const* d_in, const int* in_sizes, int n_in,
                              void* d_out, int out_size, void* d_ws, size_t ws_size,
                              hipStream_t stream) {
  const float* x   = (const float*)d_in[0];
  const float* w1  = (const float*)d_in[1];
  const float* w2  = (const float*)d_in[2];
  const float* w3  = (const float*)d_in[3];
  const float* w4  = (const float*)d_in[4];
  const float* w5  = (const float*)d_in[5];
  const float* bn1 = (const float*)d_in[6];
  const float* bn2 = (const float*)d_in[7];
  const float* bn3 = (const float*)d_in[8];
  const float* bn4 = (const float*)d_in[9];
  const float* bn5 = (const float*)d_in[10];
  const float* bn6 = (const float*)d_in[11];
  const float* bn7 = (const float*)d_in[12];
  const float* l1w = (const float*)d_in[13];
  const float* l2w = (const float*)d_in[14];
  const float* l2b = (const float*)d_in[15];
  const float* l3w = (const float*)d_in[16];
  const float* l3b = (const float*)d_in[17];
  float* out = (float*)d_out;

  float* ws = (float*)d_ws;
  size_t off = 0;
  float* xt  = ws + off; off += (size_t)BATCH * NPTS * 3;
  float* xx  = ws + off; off += (size_t)BATCH * NPTS;
  float* W2f = ws + off; off += (size_t)512 * 128;
  unsigned short* W2H = (unsigned short*)(ws + off); off += (size_t)512 * 128 / 2;
  unsigned short* W2L = (unsigned short*)(ws + off); off += (size_t)512 * 128 / 2;
  unsigned short* w5H = (unsigned short*)(ws + off); off += (size_t)1024 * 512 / 2;
  unsigned short* w5L = (unsigned short*)(ws + off); off += (size_t)1024 * 512 / 2;
  float* Ab  = ws + off; off += (size_t)BATCH * NPTS * 256;
  float* Bb  = ws + off; off += (size_t)BATCH * NPTS * 256;
  unsigned short* catH = (unsigned short*)(ws + off); off += (size_t)BATCH * NPTS * 512 / 2;
  unsigned short* catL = (unsigned short*)(ws + off); off += (size_t)BATCH * NPTS * 512 / 2;
  float* pd  = ws + off; off += (size_t)BATCH * NPTS * NPTS;
  float* pmax = ws + off; off += (size_t)128 * 1024;
  float* psum = ws + off; off += (size_t)128 * 1024;
  float* pooled = ws + off; off += (size_t)BATCH * 2048;
  float* f1  = ws + off; off += (size_t)BATCH * 512;
  float* f2  = ws + off; off += (size_t)BATCH * 256;
  int* idx = (int*)(ws + off);

  transpose_x<<<(BATCH * NPTS * 3 + 255) / 256, 256, 0, stream>>>(x, xt);
  split_w5<<<(1024 * 512) / 256, 256, 0, stream>>>(w5, w5H, w5L);

  // ---------------- stage 1 (f32 path, K=3)
  compute_xx<<<64, 256, 0, stream>>>(xt, 3, 3, xx);
  gram_pd<<<dim3(16, 16, BATCH), 256, 0, stream>>>(xt, 3, 3, xx, pd);
  topk20<<<(BATCH * NPTS) / 4, 256, 0, stream>>>(pd, idx);
  prep_w2<<<(64 * 3 + 255) / 256, 256, 0, stream>>>(w1, W2f, W2H, W2L, 3, 64);
  gemm_ab_f32<<<dim3(2, (BATCH * NPTS) / 64), 256, 0, stream>>>(xt, W2f, Ab, Bb, 3, 64);
  gather_max_bn<64, 1><<<1024, 256, 0, stream>>>(Ab, Bb, idx, bn1, catH, catL, xx, 0);

  // ---------------- stage 2 (C=64 -> O=64)
  gram_mfma<<<dim3(8, 8, BATCH), 256, 0, stream>>>(catH + 0, catL + 0, 512, 64, xx, pd);
  topk20<<<(BATCH * NPTS) / 4, 256, 0, stream>>>(pd, idx);
  prep_w2<<<(64 * 64 + 255) / 256, 256, 0, stream>>>(w2, W2f, W2H, W2L, 64, 64);
  mfma_gemm<1><<<dim3(1, (BATCH * NPTS) / 128), 256, 0, stream>>>(
      catH + 0, catL + 0, 512, W2H, W2L, 64, 64, 128, nullptr, Ab, Bb);
  gather_max_bn<64, 1><<<1024, 256, 0, stream>>>(Ab, Bb, idx, bn2, catH, catL, xx, 64);

  // ---------------- stage 3 (C=64 -> O=128)
  gram_mfma<<<dim3(8, 8, BATCH), 256, 0, stream>>>(catH + 64, catL + 64, 512, 64, xx, pd);
  topk20<<<(BATCH * NPTS) / 4, 256, 0, stream>>>(pd, idx);
  prep_w2<<<(128 * 64 + 255) / 256, 256, 0, stream>>>(w3, W2f, W2H, W2L, 64, 128);
  mfma_gemm<1><<<dim3(2, (BATCH * NPTS) / 128), 256, 0, stream>>>(
      catH + 64, catL + 64, 512, W2H, W2L, 64, 64, 256, nullptr, Ab, Bb);
  gather_max_bn<128, 1><<<2048, 256, 0, stream>>>(Ab, Bb, idx, bn3, catH, catL, xx, 128);

  // ---------------- stage 4 (C=128 -> O=256)
  gram_mfma<<<dim3(8, 8, BATCH), 256, 0, stream>>>(catH + 128, catL + 128, 512, 128, xx, pd);
  topk20<<<(BATCH * NPTS) / 4, 256, 0, stream>>>(pd, idx);
  prep_w2<<<(256 * 128 + 255) / 256, 256, 0, stream>>>(w4, W2f, W2H, W2L, 128, 256);
  mfma_gemm<1><<<dim3(4, (BATCH * NPTS) / 128), 256, 0, stream>>>(
      catH + 128, catL + 128, 512, W2H, W2L, 128, 128, 512, nullptr, Ab, Bb);
  gather_max_bn<256, 0><<<4096, 256, 0, stream>>>(Ab, Bb, idx, bn4, catH, catL, nullptr, 256);

  // ---------------- w5 GEMM + BN5 + LReLU + fused max/mean pool
  mfma_gemm<2><<<dim3(8, (BATCH * NPTS) / 128), 256, 0, stream>>>(
      catH, catL, 512, w5H, w5L, 512, 512, 1024, bn5, pmax, psum);
  reduce_pool<<<dim3(4, BATCH), 256, 0, stream>>>(pmax, psum, pooled);

  fc_kernel<<<(BATCH * 512 * 64) / 256, 256, 0, stream>>>(pooled, l1w, nullptr, bn6, f1, 2048, 512, 1);
  fc_kernel<<<(BATCH * 256 * 64) / 256, 256, 0, stream>>>(f1, l2w, l2b, bn7, f2, 512, 256, 1);
  fc_kernel<<<(BATCH * 40 * 64 + 255) / 256, 256, 0, stream>>>(f2, l3w, l3b, nullptr, out, 256, 40, 0);
}

// Round 7
// 324.891 us; speedup vs baseline: 3.1268x; 1.0557x over previous
//
#include <hip/hip_runtime.h>
#include <math.h>

#define BATCH 16
#define NPTS  1024
#define KNN   20
#define BNEPS 1e-5f

typedef __attribute__((ext_vector_type(8))) short bf16x8;
typedef __attribute__((ext_vector_type(4))) float f32x4;
typedef __attribute__((ext_vector_type(4))) unsigned short u16x4;

__device__ __forceinline__ float bf2f(unsigned short h) {
  return __uint_as_float(((unsigned int)h) << 16);
}
__device__ __forceinline__ unsigned short f2bf(float f) {
  unsigned int u = __float_as_uint(f);
  u += 0x7fffu + ((u >> 16) & 1u);
  return (unsigned short)(u >> 16);
}

// ---------------------------------------------------------------- transpose
__global__ void transpose_x(const float* __restrict__ x, float* __restrict__ xt) {
  int i = blockIdx.x * 256 + threadIdx.x;
  if (i >= BATCH * NPTS * 3) return;
  int b = i / (NPTS * 3);
  int r = i - b * (NPTS * 3);
  int n = r / 3;
  int c = r - n * 3;
  xt[i] = x[(b * 3 + c) * NPTS + n];
}

// ---------------------------------------------------------------- all weight prep in one launch
// blocks: [0,2048) w5 split; [2048] stage1 W2f; then s2(16), s3(32), s4(128)
__global__ void prep_all(const float* __restrict__ w1, const float* __restrict__ w2,
                         const float* __restrict__ w3, const float* __restrict__ w4,
                         const float* __restrict__ w5,
                         float* __restrict__ W2f1,
                         unsigned short* __restrict__ W2H2, unsigned short* __restrict__ W2L2,
                         unsigned short* __restrict__ W2H3, unsigned short* __restrict__ W2L3,
                         unsigned short* __restrict__ W2H4, unsigned short* __restrict__ W2L4,
                         unsigned short* __restrict__ w5H, unsigned short* __restrict__ w5L) {
  int blk = blockIdx.x;
  int t = threadIdx.x;
  if (blk < 2048) {
    int i = blk * 256 + t;
    float v = w5[i];
    unsigned short h = f2bf(v);
    w5H[i] = h;
    w5L[i] = f2bf(v - bf2f(h));
    return;
  }
  blk -= 2048;
  if (blk < 1) {
    int i = t;
    if (i < 192) {
      int o = i / 3, c = i - o * 3;
      float wl = w1[o * 6 + c];
      float d = w1[o * 6 + 3 + c] - wl;
      W2f1[o * 3 + c] = wl;
      W2f1[(64 + o) * 3 + c] = d;
    }
    return;
  }
  blk -= 1;
  const float* w;
  unsigned short *H, *L;
  int C, O;
  if (blk < 16)      { w = w2; H = W2H2; L = W2L2; C = 64;  O = 64; }
  else if (blk < 48) { w = w3; H = W2H3; L = W2L3; C = 64;  O = 128; blk -= 16; }
  else               { w = w4; H = W2H4; L = W2L4; C = 128; O = 256; blk -= 48; }
  int i = blk * 256 + t;
  int o = i / C, c = i - o * C;
  float wl = w[o * 2 * C + c];
  float d  = w[o * 2 * C + C + c] - wl;
  unsigned short h1 = f2bf(wl);
  H[(size_t)o * C + c] = h1;
  L[(size_t)o * C + c] = f2bf(wl - bf2f(h1));
  unsigned short h2 = f2bf(d);
  H[(size_t)(O + o) * C + c] = h2;
  L[(size_t)(O + o) * C + c] = f2bf(d - bf2f(h2));
}

// ---------------------------------------------------------------- stage-1 fused knn (K=3): pd in-register + radix top-20
// Bit-identical fmaf ordering to the old compute_xx + gram_pd path.
__global__ __launch_bounds__(256) void knn3_topk(const float* __restrict__ xt, int* __restrict__ idx) {
  __shared__ float cx[NPTS], cy[NPTS], cz[NPTS], cn[NPTS];
  int tid = threadIdx.x, lane = tid & 63, w = tid >> 6;
  int pt0 = blockIdx.x * 16;
  int b = pt0 >> 10;
  const float* F = xt + (size_t)b * NPTS * 3;
  for (int p = tid; p < NPTS; p += 256) {
    float x = F[p * 3 + 0], y = F[p * 3 + 1], z = F[p * 3 + 2];
    cx[p] = x; cy[p] = y; cz[p] = z;
    float s = 0.f;
    s = fmaf(x, x, s); s = fmaf(y, y, s); s = fmaf(z, z, s);
    cn[p] = s;
  }
  __syncthreads();
  for (int rr = 0; rr < 4; rr++) {
    int pt = pt0 + w * 4 + rr;
    int lr = pt & 1023;
    float rx = cx[lr], ry = cy[lr], rz = cz[lr], rn = cn[lr];
    unsigned key[16];
#pragma unroll
    for (int s = 0; s < 16; s++) {
      int col = lane + s * 64;
      float acc = 0.f;
      acc = fmaf(rx, cx[col], acc);
      acc = fmaf(ry, cy[col], acc);
      acc = fmaf(rz, cz[col], acc);
      float pdv = fmaf(2.f, acc, -rn) - cn[col];
      unsigned bb = __float_as_uint(pdv);
      key[s] = bb ^ ((((int)bb >> 31) | 0x80000000u));
    }
    unsigned P = 0;
    for (int bit = 31; bit >= 0; --bit) {
      unsigned T = P | (1u << bit);
      int c = 0;
#pragma unroll
      for (int s = 0; s < 16; s++)
        c += __popcll(__ballot(key[s] >= T));
      if (c >= 20) {
        P = T;
        if (c == 20) break;
      }
    }
    unsigned long long ltmask = (1ull << lane) - 1ull;
    int* o = idx + pt * KNN;
    int base = 0;
#pragma unroll
    for (int s = 0; s < 16; s++) {
      unsigned long long m = __ballot(key[s] > P);
      if (key[s] > P) o[base + __popcll(m & ltmask)] = s * 64 + lane;
      base += __popcll(m);
    }
#pragma unroll
    for (int s = 0; s < 16; s++) {
      unsigned long long m = __ballot(key[s] == P);
      if (key[s] == P) {
        int pos = base + __popcll(m & ltmask);
        if (pos < KNN) o[pos] = s * 64 + lane;
      }
      base += __popcll(m);
    }
  }
}

// ---------------------------------------------------------------- Gram via bf16x3 MFMA (stages 2-4)
__global__ __launch_bounds__(256) void gram_mfma(
    const unsigned short* __restrict__ H, const unsigned short* __restrict__ L,
    int ld, int C, const float* __restrict__ xx, float* __restrict__ pd) {
  __shared__ unsigned short lds[4][128 * 32];
  int tid = threadIdx.x;
  int lane = tid & 63, w = tid >> 6;
  int d = blockIdx.x + 8 * blockIdx.y + 64 * blockIdx.z;   // grid (8,8,16)
  int nd = (d & 7) * 128 + (d >> 3);
  int b = nd >> 6;
  int rem = nd & 63;
  int m0 = (rem >> 3) * 128, n0 = (rem & 7) * 128;
  int base = b * NPTS;
  int wrow = (w >> 1) * 64, wcol = (w & 1) * 64;

  f32x4 acc[4][4];
#pragma unroll
  for (int m = 0; m < 4; m++)
#pragma unroll
    for (int n = 0; n < 4; n++) acc[m][n] = (f32x4){0.f, 0.f, 0.f, 0.f};

  const unsigned short* gsrc = (w == 0 || w == 2) ? H : L;
  int b0 = (w < 2) ? m0 : n0;
  int srow = lane >> 2;
  int physChunk = lane & 3;
  int fr = lane & 15, ko = lane >> 4;
  // 2-way bank swizzle: slot = chunk ^ (r&3) ^ ((r>>2)&3)
  int lsw = (srow & 3) ^ ((srow >> 2) & 3);
  int lchunk = physChunk ^ lsw;
  int koX = ko ^ ((fr & 3) ^ ((fr >> 2) & 3));

  for (int kt = 0; kt < C; kt += 32) {
#pragma unroll
    for (int i = 0; i < 8; i++) {
      int row = i * 16 + srow;
      const unsigned short* g = gsrc + (size_t)(base + b0 + row) * ld + kt + lchunk * 8;
      unsigned short* l = &lds[w][i * 512];
      __builtin_amdgcn_global_load_lds(
          (const __attribute__((address_space(1))) unsigned int*)g,
          (__attribute__((address_space(3))) unsigned int*)l, 16, 0, 0);
    }
    __syncthreads();

    bf16x8 ah[4], al[4], bh[4], bl[4];
#pragma unroll
    for (int m = 0; m < 4; m++) {
      int row = wrow + m * 16 + fr;
      int off = row * 64 + koX * 16;
      ah[m] = *(const bf16x8*)((const char*)&lds[0][0] + off);
      al[m] = *(const bf16x8*)((const char*)&lds[1][0] + off);
    }
#pragma unroll
    for (int n = 0; n < 4; n++) {
      int row = wcol + n * 16 + fr;
      int off = row * 64 + koX * 16;
      bh[n] = *(const bf16x8*)((const char*)&lds[2][0] + off);
      bl[n] = *(const bf16x8*)((const char*)&lds[3][0] + off);
    }
#pragma unroll
    for (int m = 0; m < 4; m++)
#pragma unroll
      for (int n = 0; n < 4; n++) {
        acc[m][n] = __builtin_amdgcn_mfma_f32_16x16x32_bf16(ah[m], bh[n], acc[m][n], 0, 0, 0);
        acc[m][n] = __builtin_amdgcn_mfma_f32_16x16x32_bf16(al[m], bh[n], acc[m][n], 0, 0, 0);
        acc[m][n] = __builtin_amdgcn_mfma_f32_16x16x32_bf16(ah[m], bl[n], acc[m][n], 0, 0, 0);
      }
    __syncthreads();
  }

  int fq = lane >> 4;
#pragma unroll
  for (int n = 0; n < 4; n++) {
    int gc = n0 + wcol + n * 16 + fr;
    float xn = xx[base + gc];
#pragma unroll
    for (int m = 0; m < 4; m++)
#pragma unroll
      for (int r = 0; r < 4; r++) {
        int gr = m0 + wrow + m * 16 + fq * 4 + r;
        pd[((size_t)(base + gr)) * NPTS + gc] = fmaf(2.f, acc[m][n][r], -xx[base + gr]) - xn;
      }
  }
}

// ---------------------------------------------------------------- top-20 SET per row via radix-select
__global__ void topk20(const float* __restrict__ pd, int* __restrict__ idx) {
  int tid = threadIdx.x, lane = tid & 63, w = tid >> 6;
  int row = blockIdx.x * 4 + w;
  const float* p = pd + (size_t)row * NPTS;
  unsigned key[16];
#pragma unroll
  for (int s = 0; s < 16; s++) {
    unsigned b = __float_as_uint(p[lane + s * 64]);
    key[s] = b ^ ((((int)b >> 31) | 0x80000000u));
  }

  unsigned P = 0;
  for (int bit = 31; bit >= 0; --bit) {
    unsigned T = P | (1u << bit);
    int c = 0;
#pragma unroll
    for (int s = 0; s < 16; s++)
      c += __popcll(__ballot(key[s] >= T));
    if (c >= 20) {
      P = T;
      if (c == 20) break;
    }
  }
  unsigned long long ltmask = (1ull << lane) - 1ull;
  int* o = idx + row * KNN;
  int base = 0;
#pragma unroll
  for (int s = 0; s < 16; s++) {
    unsigned long long m = __ballot(key[s] > P);
    if (key[s] > P) {
      int pos = base + __popcll(m & ltmask);
      o[pos] = s * 64 + lane;
    }
    base += __popcll(m);
  }
#pragma unroll
  for (int s = 0; s < 16; s++) {
    unsigned long long m = __ballot(key[s] == P);
    if (key[s] == P) {
      int pos = base + __popcll(m & ltmask);
      if (pos < KNN) o[pos] = s * 64 + lane;
    }
    base += __popcll(m);
  }
}

// ---------------------------------------------------------------- f32 GEMM for stage 1 (K=3)
__global__ void gemm_ab_f32(const float* __restrict__ feat, const float* __restrict__ W2,
                            float* __restrict__ Ab, float* __restrict__ Bb, int K, int O) {
  __shared__ float As[16][68];
  __shared__ float Ws[16][68];
  int n0 = blockIdx.x * 64, m0 = blockIdx.y * 64;
  int tid = threadIdx.x, tx = tid & 15, ty = tid >> 4;
  float acc[4][4] = {};
  for (int k0 = 0; k0 < K; k0 += 16) {
#pragma unroll
    for (int l = 0; l < 4; l++) {
      int e = tid + l * 256;
      int m = e >> 4, k = e & 15;
      As[k][m] = (k0 + k < K) ? feat[(size_t)(m0 + m) * K + k0 + k] : 0.f;
      Ws[k][m] = (k0 + k < K) ? W2[(size_t)(n0 + m) * K + k0 + k] : 0.f;
    }
    __syncthreads();
#pragma unroll
    for (int kk = 0; kk < 16; kk++) {
      float4 ra = *(const float4*)&As[kk][ty * 4];
      float4 rb = *(const float4*)&Ws[kk][tx * 4];
      float a[4] = {ra.x, ra.y, ra.z, ra.w};
      float w[4] = {rb.x, rb.y, rb.z, rb.w};
#pragma unroll
      for (int i2 = 0; i2 < 4; i2++)
#pragma unroll
        for (int j = 0; j < 4; j++)
          acc[i2][j] = fmaf(a[i2], w[j], acc[i2][j]);
    }
    __syncthreads();
  }
#pragma unroll
  for (int i2 = 0; i2 < 4; i2++) {
    int row = m0 + ty * 4 + i2;
#pragma unroll
    for (int j = 0; j < 4; j++) {
      int col = n0 + tx * 4 + j;
      if (col < O) Ab[(size_t)row * O + col] = acc[i2][j];
      else         Bb[(size_t)row * O + (col - O)] = acc[i2][j];
    }
  }
}

// ---------------------------------------------------------------- bf16x3 MFMA GEMM: C = A*B^T
// EPI=1: split cols O=N/2 -> out0/out1 (raw acc).
// EPI=2: BN+LReLU then per-block col max/sum -> out0=pmax, out1=psum [128][1024]
template<int EPI>
__global__ __launch_bounds__(256) void mfma_gemm(
    const unsigned short* __restrict__ AH, const unsigned short* __restrict__ AL, int lda,
    const unsigned short* __restrict__ BH, const unsigned short* __restrict__ BL, int ldb,
    int K, int N, const float* __restrict__ bnp,
    float* __restrict__ out0, float* __restrict__ out1) {
  __shared__ unsigned short lds[4][128 * 32];
  __shared__ float pm[128];
  __shared__ float ps[128];
  int tid = threadIdx.x;
  int lane = tid & 63, w = tid >> 6;
  int total = gridDim.x * gridDim.y;
  int d = blockIdx.x + gridDim.x * blockIdx.y;
  int nd = (d & 7) * (total >> 3) + (d >> 3);
  int n0 = (nd % gridDim.x) * 128;
  int m0 = (nd / gridDim.x) * 128;
  int wrow = (w >> 1) * 64, wcol = (w & 1) * 64;

  f32x4 acc[4][4];
#pragma unroll
  for (int m = 0; m < 4; m++)
#pragma unroll
    for (int n = 0; n < 4; n++) acc[m][n] = (f32x4){0.f, 0.f, 0.f, 0.f};

  const unsigned short* gsrc = (w == 0) ? AH : (w == 1) ? AL : (w == 2) ? BH : BL;
  int ld = (w < 2) ? lda : ldb;
  int b0 = (w < 2) ? m0 : n0;
  int srow = lane >> 2;
  int physChunk = lane & 3;
  int fr = lane & 15, ko = lane >> 4;
  int lsw = (srow & 3) ^ ((srow >> 2) & 3);
  int lchunk = physChunk ^ lsw;
  int koX = ko ^ ((fr & 3) ^ ((fr >> 2) & 3));

  for (int kt = 0; kt < K; kt += 32) {
#pragma unroll
    for (int i = 0; i < 8; i++) {
      int row = i * 16 + srow;
      const unsigned short* g = gsrc + (size_t)(b0 + row) * ld + kt + lchunk * 8;
      unsigned short* l = &lds[w][i * 512];
      __builtin_amdgcn_global_load_lds(
          (const __attribute__((address_space(1))) unsigned int*)g,
          (__attribute__((address_space(3))) unsigned int*)l, 16, 0, 0);
    }
    __syncthreads();

    bf16x8 ah[4], al[4], bh[4], bl[4];
#pragma unroll
    for (int m = 0; m < 4; m++) {
      int row = wrow + m * 16 + fr;
      int off = row * 64 + koX * 16;
      ah[m] = *(const bf16x8*)((const char*)&lds[0][0] + off);
      al[m] = *(const bf16x8*)((const char*)&lds[1][0] + off);
    }
#pragma unroll
    for (int n = 0; n < 4; n++) {
      int row = wcol + n * 16 + fr;
      int off = row * 64 + koX * 16;
      bh[n] = *(const bf16x8*)((const char*)&lds[2][0] + off);
      bl[n] = *(const bf16x8*)((const char*)&lds[3][0] + off);
    }
#pragma unroll
    for (int m = 0; m < 4; m++)
#pragma unroll
      for (int n = 0; n < 4; n++) {
        acc[m][n] = __builtin_amdgcn_mfma_f32_16x16x32_bf16(ah[m], bh[n], acc[m][n], 0, 0, 0);
        acc[m][n] = __builtin_amdgcn_mfma_f32_16x16x32_bf16(al[m], bh[n], acc[m][n], 0, 0, 0);
        acc[m][n] = __builtin_amdgcn_mfma_f32_16x16x32_bf16(ah[m], bl[n], acc[m][n], 0, 0, 0);
      }
    __syncthreads();
  }

  int fq = lane >> 4;
  if (EPI == 1) {
#pragma unroll
    for (int n = 0; n < 4; n++) {
      int gc = n0 + wcol + n * 16 + fr;
      int O = N >> 1;
      float* dst = (gc < O) ? out0 : out1;
      int cc = (gc < O) ? gc : gc - O;
#pragma unroll
      for (int m = 0; m < 4; m++)
#pragma unroll
        for (int r = 0; r < 4; r++) {
          int gr = m0 + wrow + m * 16 + fq * 4 + r;
          dst[(size_t)gr * O + cc] = acc[m][n][r];
        }
    }
  } else {
    float cmax[4], csum[4];
#pragma unroll
    for (int n = 0; n < 4; n++) {
      int gc = n0 + wcol + n * 16 + fr;
      float g = bnp[gc], bt = bnp[N + gc], mu = bnp[2 * N + gc], va = bnp[3 * N + gc];
      float sc = g * rsqrtf(va + BNEPS);
      float mx = -INFINITY, sm = 0.f;
#pragma unroll
      for (int m = 0; m < 4; m++)
#pragma unroll
        for (int r = 0; r < 4; r++) {
          float y = sc * (acc[m][n][r] - mu) + bt;
          y = y >= 0.f ? y : 0.2f * y;
          mx = fmaxf(mx, y);
          sm += y;
        }
      mx = fmaxf(mx, __shfl_xor(mx, 16));
      mx = fmaxf(mx, __shfl_xor(mx, 32));
      sm += __shfl_xor(sm, 16);
      sm += __shfl_xor(sm, 32);
      cmax[n] = mx;
      csum[n] = sm;
    }
    if (w >= 2 && fq == 0) {
#pragma unroll
      for (int n = 0; n < 4; n++) {
        pm[wcol + n * 16 + fr] = cmax[n];
        ps[wcol + n * 16 + fr] = csum[n];
      }
    }
    __syncthreads();
    if (w < 2 && fq == 0) {
      int rb = m0 >> 7;
#pragma unroll
      for (int n = 0; n < 4; n++) {
        int cc = wcol + n * 16 + fr;
        int gc = n0 + cc;
        out0[(size_t)rb * 1024 + gc] = fmaxf(cmax[n], pm[cc]);
        out1[(size_t)rb * 1024 + gc] = csum[n] + ps[cc];
      }
    }
  }
}

// ---------------------------------------------------------------- fold 8 row-block partials per batch
__global__ void reduce_pool(const float* __restrict__ pmax, const float* __restrict__ psum,
                            float* __restrict__ pooled) {
  int c = blockIdx.x * 256 + threadIdx.x;
  int b = blockIdx.y;
  float mx = -INFINITY, sm = 0.f;
#pragma unroll
  for (int i = 0; i < 8; i++) {
    int rb = b * 8 + i;
    mx = fmaxf(mx, pmax[(size_t)rb * 1024 + c]);
    sm += psum[(size_t)rb * 1024 + c];
  }
  pooled[b * 2048 + c] = mx;
  pooled[b * 2048 + 1024 + c] = sm * (1.f / 1024.f);
}

// ---------------------------------------------------------------- gather + max_k + BN + LReLU -> bf16 hi/lo cat
template<int O, int XXOUT>
__global__ void gather_max_bn(const float* __restrict__ Ab, const float* __restrict__ Bb,
                              const int* __restrict__ idx, const float* __restrict__ bnp,
                              unsigned short* __restrict__ catH, unsigned short* __restrict__ catL,
                              float* __restrict__ xx, int co) {
  constexpr int LPP = O / 4;
  constexpr int PPB = 1024 / O;
  int tid = threadIdx.x;
  int lp = tid / LPP;
  int cl = tid - lp * LPP;
  int nblk = gridDim.x;
  int d = blockIdx.x;
  int nd = (d & 7) * (nblk >> 3) + (d >> 3);
  int pt = nd * PPB + lp;
  int b = pt >> 10;
  const int* ix = idx + pt * KNN;
  const float4* Ab4 = (const float4*)Ab + (size_t)(b << 10) * LPP;

  float4 mx = {-INFINITY, -INFINITY, -INFINITY, -INFINITY};
#pragma unroll
  for (int k = 0; k < KNN; k++) {
    float4 v = Ab4[(size_t)ix[k] * LPP + cl];
    mx.x = fmaxf(mx.x, v.x);
    mx.y = fmaxf(mx.y, v.y);
    mx.z = fmaxf(mx.z, v.z);
    mx.w = fmaxf(mx.w, v.w);
  }
  float4 bb = ((const float4*)Bb)[(size_t)pt * LPP + cl];
  int o = cl * 4;
  float4 gg = *(const float4*)(bnp + o);
  float4 bt = *(const float4*)(bnp + O + o);
  float4 mu = *(const float4*)(bnp + 2 * O + o);
  float4 va = *(const float4*)(bnp + 3 * O + o);

  float h[4] = {mx.x + bb.x, mx.y + bb.y, mx.z + bb.z, mx.w + bb.w};
  float G[4] = {gg.x, gg.y, gg.z, gg.w};
  float B[4] = {bt.x, bt.y, bt.z, bt.w};
  float M[4] = {mu.x, mu.y, mu.z, mu.w};
  float V[4] = {va.x, va.y, va.z, va.w};

  u16x4 hh, ll;
  float xs = 0.f;
#pragma unroll
  for (int e = 0; e < 4; e++) {
    float y = G[e] * (h[e] - M[e]) * rsqrtf(V[e] + BNEPS) + B[e];
    y = y >= 0.f ? y : 0.2f * y;
    unsigned short yh = f2bf(y);
    float fh = bf2f(yh);
    unsigned short yl = f2bf(y - fh);
    hh[e] = yh;
    ll[e] = yl;
    if (XXOUT) {
      float a = fh + bf2f(yl);
      xs = fmaf(a, a, xs);
    }
  }
  size_t dst = (size_t)pt * 512 + co + o;
  *(u16x4*)(catH + dst) = hh;
  *(u16x4*)(catL + dst) = ll;

  if (XXOUT) {
#pragma unroll
    for (int s = 1; s < LPP; s <<= 1) xs += __shfl_xor(xs, s);
    if (cl == 0) xx[pt] = xs;
  }
}

// ---------------------------------------------------------------- FC: wave per output
__global__ void fc_kernel(const float* __restrict__ in, const float* __restrict__ w,
                          const float* __restrict__ bias, const float* __restrict__ bnp,
                          float* __restrict__ out, int Cin, int Cout, int act) {
  int g = blockIdx.x * blockDim.x + threadIdx.x;
  int wid = g >> 6, lane = g & 63;
  if (wid >= BATCH * Cout) return;
  int b = wid / Cout, o = wid - b * Cout;
  const float* xp = in + (size_t)b * Cin;
  const float* wp = w + (size_t)o * Cin;
  float s = 0.f;
  for (int c = lane; c < Cin; c += 64) s = fmaf(xp[c], wp[c], s);
#pragma unroll
  for (int off = 32; off; off >>= 1) s += __shfl_xor(s, off);
  if (lane == 0) {
    if (bias) s += bias[o];
    if (act) {
      float gm = bnp[o], bt = bnp[Cout + o], mu = bnp[2 * Cout + o], va = bnp[3 * Cout + o];
      s = gm * (s - mu) * rsqrtf(va + BNEPS) + bt;
      s = s >= 0.f ? s : 0.2f * s;
    }
    out[wid] = s;
  }
}

// ================================================================ launch
extern "C" void kernel_launch(void* const* d_in, const int* in_sizes, int n_in,
                              void* d_out, int out_size, void* d_ws, size_t ws_size,
                              hipStream_t stream) {
  const float* x   = (const float*)d_in[0];
  const float* w1  = (const float*)d_in[1];
  const float* w2  = (const float*)d_in[2];
  const float* w3  = (const float*)d_in[3];
  const float* w4  = (const float*)d_in[4];
  const float* w5  = (const float*)d_in[5];
  const float* bn1 = (const float*)d_in[6];
  const float* bn2 = (const float*)d_in[7];
  const float* bn3 = (const float*)d_in[8];
  const float* bn4 = (const float*)d_in[9];
  const float* bn5 = (const float*)d_in[10];
  const float* bn6 = (const float*)d_in[11];
  const float* bn7 = (const float*)d_in[12];
  const float* l1w = (const float*)d_in[13];
  const float* l2w = (const float*)d_in[14];
  const float* l2b = (const float*)d_in[15];
  const float* l3w = (const float*)d_in[16];
  const float* l3b = (const float*)d_in[17];
  float* out = (float*)d_out;

  float* ws = (float*)d_ws;
  size_t off = 0;
  float* xt  = ws + off; off += (size_t)BATCH * NPTS * 3;
  float* xx  = ws + off; off += (size_t)BATCH * NPTS;
  float* W2f1 = ws + off; off += 384;
  unsigned short* W2H2 = (unsigned short*)(ws + off); off += 8192 / 2;
  unsigned short* W2L2 = (unsigned short*)(ws + off); off += 8192 / 2;
  unsigned short* W2H3 = (unsigned short*)(ws + off); off += 16384 / 2;
  unsigned short* W2L3 = (unsigned short*)(ws + off); off += 16384 / 2;
  unsigned short* W2H4 = (unsigned short*)(ws + off); off += 65536 / 2;
  unsigned short* W2L4 = (unsigned short*)(ws + off); off += 65536 / 2;
  unsigned short* w5H = (unsigned short*)(ws + off); off += (size_t)1024 * 512 / 2;
  unsigned short* w5L = (unsigned short*)(ws + off); off += (size_t)1024 * 512 / 2;
  float* Ab  = ws + off; off += (size_t)BATCH * NPTS * 256;
  float* Bb  = ws + off; off += (size_t)BATCH * NPTS * 256;
  unsigned short* catH = (unsigned short*)(ws + off); off += (size_t)BATCH * NPTS * 512 / 2;
  unsigned short* catL = (unsigned short*)(ws + off); off += (size_t)BATCH * NPTS * 512 / 2;
  float* pd  = ws + off; off += (size_t)BATCH * NPTS * NPTS;
  float* pmax = ws + off; off += (size_t)128 * 1024;
  float* psum = ws + off; off += (size_t)128 * 1024;
  float* pooled = ws + off; off += (size_t)BATCH * 2048;
  float* f1  = ws + off; off += (size_t)BATCH * 512;
  float* f2  = ws + off; off += (size_t)BATCH * 256;
  int* idx = (int*)(ws + off);

  prep_all<<<2225, 256, 0, stream>>>(w1, w2, w3, w4, w5, W2f1,
                                     W2H2, W2L2, W2H3, W2L3, W2H4, W2L4, w5H, w5L);
  transpose_x<<<(BATCH * NPTS * 3 + 255) / 256, 256, 0, stream>>>(x, xt);

  // ---------------- stage 1 (K=3): fused pd+topk, then f32 GEMM + gather
  knn3_topk<<<1024, 256, 0, stream>>>(xt, idx);
  gemm_ab_f32<<<dim3(2, (BATCH * NPTS) / 64), 256, 0, stream>>>(xt, W2f1, Ab, Bb, 3, 64);
  gather_max_bn<64, 1><<<1024, 256, 0, stream>>>(Ab, Bb, idx, bn1, catH, catL, xx, 0);

  // ---------------- stage 2 (C=64 -> O=64)
  gram_mfma<<<dim3(8, 8, BATCH), 256, 0, stream>>>(catH + 0, catL + 0, 512, 64, xx, pd);
  topk20<<<(BATCH * NPTS) / 4, 256, 0, stream>>>(pd, idx);
  mfma_gemm<1><<<dim3(1, (BATCH * NPTS) / 128), 256, 0, stream>>>(
      catH + 0, catL + 0, 512, W2H2, W2L2, 64, 64, 128, nullptr, Ab, Bb);
  gather_max_bn<64, 1><<<1024, 256, 0, stream>>>(Ab, Bb, idx, bn2, catH, catL, xx, 64);

  // ---------------- stage 3 (C=64 -> O=128)
  gram_mfma<<<dim3(8, 8, BATCH), 256, 0, stream>>>(catH + 64, catL + 64, 512, 64, xx, pd);
  topk20<<<(BATCH * NPTS) / 4, 256, 0, stream>>>(pd, idx);
  mfma_gemm<1><<<dim3(2, (BATCH * NPTS) / 128), 256, 0, stream>>>(
      catH + 64, catL + 64, 512, W2H3, W2L3, 64, 64, 256, nullptr, Ab, Bb);
  gather_max_bn<128, 1><<<2048, 256, 0, stream>>>(Ab, Bb, idx, bn3, catH, catL, xx, 128);

  // ---------------- stage 4 (C=128 -> O=256)
  gram_mfma<<<dim3(8, 8, BATCH), 256, 0, stream>>>(catH + 128, catL + 128, 512, 128, xx, pd);
  topk20<<<(BATCH * NPTS) / 4, 256, 0, stream>>>(pd, idx);
  mfma_gemm<1><<<dim3(4, (BATCH * NPTS) / 128), 256, 0, stream>>>(
      catH + 128, catL + 128, 512, W2H4, W2L4, 128, 128, 512, nullptr, Ab, Bb);
  gather_max_bn<256, 0><<<4096, 256, 0, stream>>>(Ab, Bb, idx, bn4, catH, catL, nullptr, 256);

  // ---------------- w5 GEMM + BN5 + LReLU + fused max/mean pool
  mfma_gemm<2><<<dim3(8, (BATCH * NPTS) / 128), 256, 0, stream>>>(
      catH, catL, 512, w5H, w5L, 512, 512, 1024, bn5, pmax, psum);
  reduce_pool<<<dim3(4, BATCH), 256, 0, stream>>>(pmax, psum, pooled);

  fc_kernel<<<(BATCH * 512 * 64) / 256, 256, 0, stream>>>(pooled, l1w, nullptr, bn6, f1, 2048, 512, 1);
  fc_kernel<<<(BATCH * 256 * 64) / 256, 256, 0, stream>>>(f1, l2w, l2b, bn7, f2, 512, 256, 1);
  fc_kernel<<<(BATCH * 40 * 64 + 255) / 256, 256, 0, stream>>>(f2, l3w, l3b, nullptr, out, 256, 40, 0);
}

// Round 8
// 322.686 us; speedup vs baseline: 3.1482x; 1.0068x over previous
//
#include <hip/hip_runtime.h>
#include <math.h>

#define BATCH 16
#define NPTS  1024
#define KNN   20
#define BNEPS 1e-5f

typedef __attribute__((ext_vector_type(8))) short bf16x8;
typedef __attribute__((ext_vector_type(4))) float f32x4;
typedef __attribute__((ext_vector_type(4))) unsigned short u16x4;

__device__ __forceinline__ float bf2f(unsigned short h) {
  return __uint_as_float(((unsigned int)h) << 16);
}
__device__ __forceinline__ unsigned short f2bf(float f) {
  unsigned int u = __float_as_uint(f);
  u += 0x7fffu + ((u >> 16) & 1u);
  return (unsigned short)(u >> 16);
}

// ---------------------------------------------------------------- transpose
__global__ void transpose_x(const float* __restrict__ x, float* __restrict__ xt) {
  int i = blockIdx.x * 256 + threadIdx.x;
  if (i >= BATCH * NPTS * 3) return;
  int b = i / (NPTS * 3);
  int r = i - b * (NPTS * 3);
  int n = r / 3;
  int c = r - n * 3;
  xt[i] = x[(b * 3 + c) * NPTS + n];
}

// ---------------------------------------------------------------- all weight prep in one launch
__global__ void prep_all(const float* __restrict__ w1, const float* __restrict__ w2,
                         const float* __restrict__ w3, const float* __restrict__ w4,
                         const float* __restrict__ w5,
                         float* __restrict__ W2f1,
                         unsigned short* __restrict__ W2H2, unsigned short* __restrict__ W2L2,
                         unsigned short* __restrict__ W2H3, unsigned short* __restrict__ W2L3,
                         unsigned short* __restrict__ W2H4, unsigned short* __restrict__ W2L4,
                         unsigned short* __restrict__ w5H, unsigned short* __restrict__ w5L) {
  int blk = blockIdx.x;
  int t = threadIdx.x;
  if (blk < 2048) {
    int i = blk * 256 + t;
    float v = w5[i];
    unsigned short h = f2bf(v);
    w5H[i] = h;
    w5L[i] = f2bf(v - bf2f(h));
    return;
  }
  blk -= 2048;
  if (blk < 1) {
    int i = t;
    if (i < 192) {
      int o = i / 3, c = i - o * 3;
      float wl = w1[o * 6 + c];
      float d = w1[o * 6 + 3 + c] - wl;
      W2f1[o * 3 + c] = wl;
      W2f1[(64 + o) * 3 + c] = d;
    }
    return;
  }
  blk -= 1;
  const float* w;
  unsigned short *H, *L;
  int C, O;
  if (blk < 16)      { w = w2; H = W2H2; L = W2L2; C = 64;  O = 64; }
  else if (blk < 48) { w = w3; H = W2H3; L = W2L3; C = 64;  O = 128; blk -= 16; }
  else               { w = w4; H = W2H4; L = W2L4; C = 128; O = 256; blk -= 48; }
  int i = blk * 256 + t;
  int o = i / C, c = i - o * C;
  float wl = w[o * 2 * C + c];
  float d  = w[o * 2 * C + C + c] - wl;
  unsigned short h1 = f2bf(wl);
  H[(size_t)o * C + c] = h1;
  L[(size_t)o * C + c] = f2bf(wl - bf2f(h1));
  unsigned short h2 = f2bf(d);
  H[(size_t)(O + o) * C + c] = h2;
  L[(size_t)(O + o) * C + c] = f2bf(d - bf2f(h2));
}

// ---------------------------------------------------------------- stage-1 fused knn (K=3)
__global__ __launch_bounds__(256) void knn3_topk(const float* __restrict__ xt, int* __restrict__ idx) {
  __shared__ float cx[NPTS], cy[NPTS], cz[NPTS], cn[NPTS];
  int tid = threadIdx.x, lane = tid & 63, w = tid >> 6;
  int pt0 = blockIdx.x * 16;
  int b = pt0 >> 10;
  const float* F = xt + (size_t)b * NPTS * 3;
  for (int p = tid; p < NPTS; p += 256) {
    float x = F[p * 3 + 0], y = F[p * 3 + 1], z = F[p * 3 + 2];
    cx[p] = x; cy[p] = y; cz[p] = z;
    float s = 0.f;
    s = fmaf(x, x, s); s = fmaf(y, y, s); s = fmaf(z, z, s);
    cn[p] = s;
  }
  __syncthreads();
  for (int rr = 0; rr < 4; rr++) {
    int pt = pt0 + w * 4 + rr;
    int lr = pt & 1023;
    float rx = cx[lr], ry = cy[lr], rz = cz[lr], rn = cn[lr];
    unsigned key[16];
#pragma unroll
    for (int s = 0; s < 16; s++) {
      int col = lane + s * 64;
      float acc = 0.f;
      acc = fmaf(rx, cx[col], acc);
      acc = fmaf(ry, cy[col], acc);
      acc = fmaf(rz, cz[col], acc);
      float pdv = fmaf(2.f, acc, -rn) - cn[col];
      unsigned bb = __float_as_uint(pdv);
      key[s] = bb ^ ((((int)bb >> 31) | 0x80000000u));
    }
    unsigned P = 0;
    for (int bit = 31; bit >= 0; --bit) {
      unsigned T = P | (1u << bit);
      int c = 0;
#pragma unroll
      for (int s = 0; s < 16; s++)
        c += __popcll(__ballot(key[s] >= T));
      if (c >= 20) {
        P = T;
        if (c == 20) break;
      }
    }
    unsigned long long ltmask = (1ull << lane) - 1ull;
    int* o = idx + pt * KNN;
    int base = 0;
#pragma unroll
    for (int s = 0; s < 16; s++) {
      unsigned long long m = __ballot(key[s] > P);
      if (key[s] > P) o[base + __popcll(m & ltmask)] = s * 64 + lane;
      base += __popcll(m);
    }
#pragma unroll
    for (int s = 0; s < 16; s++) {
      unsigned long long m = __ballot(key[s] == P);
      if (key[s] == P) {
        int pos = base + __popcll(m & ltmask);
        if (pos < KNN) o[pos] = s * 64 + lane;
      }
      base += __popcll(m);
    }
  }
}

// ---------------------------------------------------------------- Gram via bf16x3 MFMA, symmetric (upper triangle only)
// grid 576 = 16 batches x 36 triangular tiles; off-diagonal blocks also store the mirrored tile.
__global__ __launch_bounds__(256) void gram_mfma(
    const unsigned short* __restrict__ H, const unsigned short* __restrict__ L,
    int ld, int C, const float* __restrict__ xx, float* __restrict__ pd) {
  __shared__ unsigned short lds[4][128 * 32];
  int tid = threadIdx.x;
  int lane = tid & 63, w = tid >> 6;
  int d = blockIdx.x;
  int nd = (d & 7) * (gridDim.x >> 3) + (d >> 3);  // XCD-chunked; batch = nd/36 on XCD (d&7)
  int b = nd / 36;
  int t = nd - b * 36;
  int ti = 0;
  while (t >= 8 - ti) { t -= 8 - ti; ti++; }
  int m0 = ti * 128, n0 = (ti + t) * 128;
  int base = b * NPTS;
  int wrow = (w >> 1) * 64, wcol = (w & 1) * 64;

  f32x4 acc[4][4];
#pragma unroll
  for (int m = 0; m < 4; m++)
#pragma unroll
    for (int n = 0; n < 4; n++) acc[m][n] = (f32x4){0.f, 0.f, 0.f, 0.f};

  const unsigned short* gsrc = (w == 0 || w == 2) ? H : L;
  int b0 = (w < 2) ? m0 : n0;
  int srow = lane >> 2;
  int physChunk = lane & 3;
  int fr = lane & 15, ko = lane >> 4;
  int lsw = (srow & 3) ^ ((srow >> 2) & 3);
  int lchunk = physChunk ^ lsw;
  int koX = ko ^ ((fr & 3) ^ ((fr >> 2) & 3));

  for (int kt = 0; kt < C; kt += 32) {
#pragma unroll
    for (int i = 0; i < 8; i++) {
      int row = i * 16 + srow;
      const unsigned short* g = gsrc + (size_t)(base + b0 + row) * ld + kt + lchunk * 8;
      unsigned short* l = &lds[w][i * 512];
      __builtin_amdgcn_global_load_lds(
          (const __attribute__((address_space(1))) unsigned int*)g,
          (__attribute__((address_space(3))) unsigned int*)l, 16, 0, 0);
    }
    __syncthreads();

    bf16x8 ah[4], al[4], bh[4], bl[4];
#pragma unroll
    for (int m = 0; m < 4; m++) {
      int row = wrow + m * 16 + fr;
      int off = row * 64 + koX * 16;
      ah[m] = *(const bf16x8*)((const char*)&lds[0][0] + off);
      al[m] = *(const bf16x8*)((const char*)&lds[1][0] + off);
    }
#pragma unroll
    for (int n = 0; n < 4; n++) {
      int row = wcol + n * 16 + fr;
      int off = row * 64 + koX * 16;
      bh[n] = *(const bf16x8*)((const char*)&lds[2][0] + off);
      bl[n] = *(const bf16x8*)((const char*)&lds[3][0] + off);
    }
#pragma unroll
    for (int m = 0; m < 4; m++)
#pragma unroll
      for (int n = 0; n < 4; n++) {
        acc[m][n] = __builtin_amdgcn_mfma_f32_16x16x32_bf16(ah[m], bh[n], acc[m][n], 0, 0, 0);
        acc[m][n] = __builtin_amdgcn_mfma_f32_16x16x32_bf16(al[m], bh[n], acc[m][n], 0, 0, 0);
        acc[m][n] = __builtin_amdgcn_mfma_f32_16x16x32_bf16(ah[m], bl[n], acc[m][n], 0, 0, 0);
      }
    __syncthreads();
  }

  int fq = lane >> 4;
#pragma unroll
  for (int n = 0; n < 4; n++) {
    int gc = n0 + wcol + n * 16 + fr;
    float xn = xx[base + gc];
#pragma unroll
    for (int m = 0; m < 4; m++) {
      f32x4 v;
#pragma unroll
      for (int r = 0; r < 4; r++) {
        int gr = m0 + wrow + m * 16 + fq * 4 + r;
        v[r] = fmaf(2.f, acc[m][n][r], -xx[base + gr]) - xn;
        pd[((size_t)(base + gr)) * NPTS + gc] = v[r];
      }
      if (m0 != n0) {  // mirrored tile (pd symmetric); 16B contiguous per lane
        int gr0 = m0 + wrow + m * 16 + fq * 4;
        *(f32x4*)&pd[((size_t)(base + gc)) * NPTS + gr0] = v;
      }
    }
  }
}

// ---------------------------------------------------------------- top-20 SET per row via radix-select
// XCD-chunked to match gram's writer XCD (batch b written on XCD b/2) -> L2 hits.
__global__ void topk20(const float* __restrict__ pd, int* __restrict__ idx) {
  int tid = threadIdx.x, lane = tid & 63, w = tid >> 6;
  int d = blockIdx.x;
  int nd = (d & 7) * (gridDim.x >> 3) + (d >> 3);
  int row = nd * 4 + w;
  const float* p = pd + (size_t)row * NPTS;
  unsigned key[16];
#pragma unroll
  for (int s = 0; s < 16; s++) {
    unsigned b = __float_as_uint(p[lane + s * 64]);
    key[s] = b ^ ((((int)b >> 31) | 0x80000000u));
  }

  unsigned P = 0;
  for (int bit = 31; bit >= 0; --bit) {
    unsigned T = P | (1u << bit);
    int c = 0;
#pragma unroll
    for (int s = 0; s < 16; s++)
      c += __popcll(__ballot(key[s] >= T));
    if (c >= 20) {
      P = T;
      if (c == 20) break;
    }
  }
  unsigned long long ltmask = (1ull << lane) - 1ull;
  int* o = idx + row * KNN;
  int base = 0;
#pragma unroll
  for (int s = 0; s < 16; s++) {
    unsigned long long m = __ballot(key[s] > P);
    if (key[s] > P) {
      int pos = base + __popcll(m & ltmask);
      o[pos] = s * 64 + lane;
    }
    base += __popcll(m);
  }
#pragma unroll
  for (int s = 0; s < 16; s++) {
    unsigned long long m = __ballot(key[s] == P);
    if (key[s] == P) {
      int pos = base + __popcll(m & ltmask);
      if (pos < KNN) o[pos] = s * 64 + lane;
    }
    base += __popcll(m);
  }
}

// ---------------------------------------------------------------- f32 GEMM for stage 1 (K=3)
__global__ void gemm_ab_f32(const float* __restrict__ feat, const float* __restrict__ W2,
                            float* __restrict__ Ab, float* __restrict__ Bb, int K, int O) {
  __shared__ float As[16][68];
  __shared__ float Ws[16][68];
  int n0 = blockIdx.x * 64, m0 = blockIdx.y * 64;
  int tid = threadIdx.x, tx = tid & 15, ty = tid >> 4;
  float acc[4][4] = {};
  for (int k0 = 0; k0 < K; k0 += 16) {
#pragma unroll
    for (int l = 0; l < 4; l++) {
      int e = tid + l * 256;
      int m = e >> 4, k = e & 15;
      As[k][m] = (k0 + k < K) ? feat[(size_t)(m0 + m) * K + k0 + k] : 0.f;
      Ws[k][m] = (k0 + k < K) ? W2[(size_t)(n0 + m) * K + k0 + k] : 0.f;
    }
    __syncthreads();
#pragma unroll
    for (int kk = 0; kk < 16; kk++) {
      float4 ra = *(const float4*)&As[kk][ty * 4];
      float4 rb = *(const float4*)&Ws[kk][tx * 4];
      float a[4] = {ra.x, ra.y, ra.z, ra.w};
      float w[4] = {rb.x, rb.y, rb.z, rb.w};
#pragma unroll
      for (int i2 = 0; i2 < 4; i2++)
#pragma unroll
        for (int j = 0; j < 4; j++)
          acc[i2][j] = fmaf(a[i2], w[j], acc[i2][j]);
    }
    __syncthreads();
  }
#pragma unroll
  for (int i2 = 0; i2 < 4; i2++) {
    int row = m0 + ty * 4 + i2;
#pragma unroll
    for (int j = 0; j < 4; j++) {
      int col = n0 + tx * 4 + j;
      if (col < O) Ab[(size_t)row * O + col] = acc[i2][j];
      else         Bb[(size_t)row * O + (col - O)] = acc[i2][j];
    }
  }
}

// ---------------------------------------------------------------- bf16x3 MFMA GEMM: C = A*B^T
// BM = rows per block (64 or 128); N-tile fixed at 128 cols.
// EPI=1: split cols O=N/2 -> out0/out1 (raw acc).
// EPI=2 (BM=128 only): BN+LReLU then per-block col max/sum -> out0=pmax, out1=psum
template<int EPI, int BM>
__global__ __launch_bounds__(256) void mfma_gemm(
    const unsigned short* __restrict__ AH, const unsigned short* __restrict__ AL, int lda,
    const unsigned short* __restrict__ BH, const unsigned short* __restrict__ BL, int ldb,
    int K, int N, const float* __restrict__ bnp,
    float* __restrict__ out0, float* __restrict__ out1) {
  constexpr int MR = BM / 32;
  __shared__ unsigned short lds[4][128 * 32];
  __shared__ float pm[128];
  __shared__ float ps[128];
  int tid = threadIdx.x;
  int lane = tid & 63, w = tid >> 6;
  int total = gridDim.x * gridDim.y;
  int d = blockIdx.x + gridDim.x * blockIdx.y;
  int nd = (d & 7) * (total >> 3) + (d >> 3);
  int n0 = (nd % gridDim.x) * 128;
  int m0 = (nd / gridDim.x) * BM;
  int wrow = (w >> 1) * (BM / 2), wcol = (w & 1) * 64;

  f32x4 acc[MR][4];
#pragma unroll
  for (int m = 0; m < MR; m++)
#pragma unroll
    for (int n = 0; n < 4; n++) acc[m][n] = (f32x4){0.f, 0.f, 0.f, 0.f};

  const unsigned short* gsrc = (w == 0) ? AH : (w == 1) ? AL : (w == 2) ? BH : BL;
  int ld = (w < 2) ? lda : ldb;
  int b0 = (w < 2) ? m0 : n0;
  int nrow16 = (w < 2) ? (BM / 16) : 8;   // A-tile BM rows, B-tile 128 rows
  int srow = lane >> 2;
  int physChunk = lane & 3;
  int fr = lane & 15, ko = lane >> 4;
  int lsw = (srow & 3) ^ ((srow >> 2) & 3);
  int lchunk = physChunk ^ lsw;
  int koX = ko ^ ((fr & 3) ^ ((fr >> 2) & 3));

  for (int kt = 0; kt < K; kt += 32) {
    for (int i = 0; i < nrow16; i++) {
      int row = i * 16 + srow;
      const unsigned short* g = gsrc + (size_t)(b0 + row) * ld + kt + lchunk * 8;
      unsigned short* l = &lds[w][i * 512];
      __builtin_amdgcn_global_load_lds(
          (const __attribute__((address_space(1))) unsigned int*)g,
          (__attribute__((address_space(3))) unsigned int*)l, 16, 0, 0);
    }
    __syncthreads();

    bf16x8 ah[MR], al[MR], bh[4], bl[4];
#pragma unroll
    for (int m = 0; m < MR; m++) {
      int row = wrow + m * 16 + fr;
      int off = row * 64 + koX * 16;
      ah[m] = *(const bf16x8*)((const char*)&lds[0][0] + off);
      al[m] = *(const bf16x8*)((const char*)&lds[1][0] + off);
    }
#pragma unroll
    for (int n = 0; n < 4; n++) {
      int row = wcol + n * 16 + fr;
      int off = row * 64 + koX * 16;
      bh[n] = *(const bf16x8*)((const char*)&lds[2][0] + off);
      bl[n] = *(const bf16x8*)((const char*)&lds[3][0] + off);
    }
#pragma unroll
    for (int m = 0; m < MR; m++)
#pragma unroll
      for (int n = 0; n < 4; n++) {
        acc[m][n] = __builtin_amdgcn_mfma_f32_16x16x32_bf16(ah[m], bh[n], acc[m][n], 0, 0, 0);
        acc[m][n] = __builtin_amdgcn_mfma_f32_16x16x32_bf16(al[m], bh[n], acc[m][n], 0, 0, 0);
        acc[m][n] = __builtin_amdgcn_mfma_f32_16x16x32_bf16(ah[m], bl[n], acc[m][n], 0, 0, 0);
      }
    __syncthreads();
  }

  int fq = lane >> 4;
  if (EPI == 1) {
#pragma unroll
    for (int n = 0; n < 4; n++) {
      int gc = n0 + wcol + n * 16 + fr;
      int O = N >> 1;
      float* dst = (gc < O) ? out0 : out1;
      int cc = (gc < O) ? gc : gc - O;
#pragma unroll
      for (int m = 0; m < MR; m++)
#pragma unroll
        for (int r = 0; r < 4; r++) {
          int gr = m0 + wrow + m * 16 + fq * 4 + r;
          dst[(size_t)gr * O + cc] = acc[m][n][r];
        }
    }
  } else {
    float cmax[4], csum[4];
#pragma unroll
    for (int n = 0; n < 4; n++) {
      int gc = n0 + wcol + n * 16 + fr;
      float g = bnp[gc], bt = bnp[N + gc], mu = bnp[2 * N + gc], va = bnp[3 * N + gc];
      float sc = g * rsqrtf(va + BNEPS);
      float mx = -INFINITY, sm = 0.f;
#pragma unroll
      for (int m = 0; m < MR; m++)
#pragma unroll
        for (int r = 0; r < 4; r++) {
          float y = sc * (acc[m][n][r] - mu) + bt;
          y = y >= 0.f ? y : 0.2f * y;
          mx = fmaxf(mx, y);
          sm += y;
        }
      mx = fmaxf(mx, __shfl_xor(mx, 16));
      mx = fmaxf(mx, __shfl_xor(mx, 32));
      sm += __shfl_xor(sm, 16);
      sm += __shfl_xor(sm, 32);
      cmax[n] = mx;
      csum[n] = sm;
    }
    if (w >= 2 && fq == 0) {
#pragma unroll
      for (int n = 0; n < 4; n++) {
        pm[wcol + n * 16 + fr] = cmax[n];
        ps[wcol + n * 16 + fr] = csum[n];
      }
    }
    __syncthreads();
    if (w < 2 && fq == 0) {
      int rb = m0 >> 7;
#pragma unroll
      for (int n = 0; n < 4; n++) {
        int cc = wcol + n * 16 + fr;
        int gc = n0 + cc;
        out0[(size_t)rb * 1024 + gc] = fmaxf(cmax[n], pm[cc]);
        out1[(size_t)rb * 1024 + gc] = csum[n] + ps[cc];
      }
    }
  }
}

// ---------------------------------------------------------------- fold 8 row-block partials per batch
__global__ void reduce_pool(const float* __restrict__ pmax, const float* __restrict__ psum,
                            float* __restrict__ pooled) {
  int c = blockIdx.x * 256 + threadIdx.x;
  int b = blockIdx.y;
  float mx = -INFINITY, sm = 0.f;
#pragma unroll
  for (int i = 0; i < 8; i++) {
    int rb = b * 8 + i;
    mx = fmaxf(mx, pmax[(size_t)rb * 1024 + c]);
    sm += psum[(size_t)rb * 1024 + c];
  }
  pooled[b * 2048 + c] = mx;
  pooled[b * 2048 + 1024 + c] = sm * (1.f / 1024.f);
}

// ---------------------------------------------------------------- gather + max_k + BN + LReLU -> bf16 hi/lo cat
template<int O, int XXOUT>
__global__ void gather_max_bn(const float* __restrict__ Ab, const float* __restrict__ Bb,
                              const int* __restrict__ idx, const float* __restrict__ bnp,
                              unsigned short* __restrict__ catH, unsigned short* __restrict__ catL,
                              float* __restrict__ xx, int co) {
  constexpr int LPP = O / 4;
  constexpr int PPB = 1024 / O;
  int tid = threadIdx.x;
  int lp = tid / LPP;
  int cl = tid - lp * LPP;
  int nblk = gridDim.x;
  int d = blockIdx.x;
  int nd = (d & 7) * (nblk >> 3) + (d >> 3);
  int pt = nd * PPB + lp;
  int b = pt >> 10;
  const int* ix = idx + pt * KNN;
  const float4* Ab4 = (const float4*)Ab + (size_t)(b << 10) * LPP;

  float4 mx = {-INFINITY, -INFINITY, -INFINITY, -INFINITY};
#pragma unroll
  for (int k = 0; k < KNN; k++) {
    float4 v = Ab4[(size_t)ix[k] * LPP + cl];
    mx.x = fmaxf(mx.x, v.x);
    mx.y = fmaxf(mx.y, v.y);
    mx.z = fmaxf(mx.z, v.z);
    mx.w = fmaxf(mx.w, v.w);
  }
  float4 bb = ((const float4*)Bb)[(size_t)pt * LPP + cl];
  int o = cl * 4;
  float4 gg = *(const float4*)(bnp + o);
  float4 bt = *(const float4*)(bnp + O + o);
  float4 mu = *(const float4*)(bnp + 2 * O + o);
  float4 va = *(const float4*)(bnp + 3 * O + o);

  float h[4] = {mx.x + bb.x, mx.y + bb.y, mx.z + bb.z, mx.w + bb.w};
  float G[4] = {gg.x, gg.y, gg.z, gg.w};
  float B[4] = {bt.x, bt.y, bt.z, bt.w};
  float M[4] = {mu.x, mu.y, mu.z, mu.w};
  float V[4] = {va.x, va.y, va.z, va.w};

  u16x4 hh, ll;
  float xs = 0.f;
#pragma unroll
  for (int e = 0; e < 4; e++) {
    float y = G[e] * (h[e] - M[e]) * rsqrtf(V[e] + BNEPS) + B[e];
    y = y >= 0.f ? y : 0.2f * y;
    unsigned short yh = f2bf(y);
    float fh = bf2f(yh);
    unsigned short yl = f2bf(y - fh);
    hh[e] = yh;
    ll[e] = yl;
    if (XXOUT) {
      float a = fh + bf2f(yl);
      xs = fmaf(a, a, xs);
    }
  }
  size_t dst = (size_t)pt * 512 + co + o;
  *(u16x4*)(catH + dst) = hh;
  *(u16x4*)(catL + dst) = ll;

  if (XXOUT) {
#pragma unroll
    for (int s = 1; s < LPP; s <<= 1) xs += __shfl_xor(xs, s);
    if (cl == 0) xx[pt] = xs;
  }
}

// ---------------------------------------------------------------- FC: wave per output
__global__ void fc_kernel(const float* __restrict__ in, const float* __restrict__ w,
                          const float* __restrict__ bias, const float* __restrict__ bnp,
                          float* __restrict__ out, int Cin, int Cout, int act) {
  int g = blockIdx.x * blockDim.x + threadIdx.x;
  int wid = g >> 6, lane = g & 63;
  if (wid >= BATCH * Cout) return;
  int b = wid / Cout, o = wid - b * Cout;
  const float* xp = in + (size_t)b * Cin;
  const float* wp = w + (size_t)o * Cin;
  float s = 0.f;
  for (int c = lane; c < Cin; c += 64) s = fmaf(xp[c], wp[c], s);
#pragma unroll
  for (int off = 32; off; off >>= 1) s += __shfl_xor(s, off);
  if (lane == 0) {
    if (bias) s += bias[o];
    if (act) {
      float gm = bnp[o], bt = bnp[Cout + o], mu = bnp[2 * Cout + o], va = bnp[3 * Cout + o];
      s = gm * (s - mu) * rsqrtf(va + BNEPS) + bt;
      s = s >= 0.f ? s : 0.2f * s;
    }
    out[wid] = s;
  }
}

// ================================================================ launch
extern "C" void kernel_launch(void* const* d_in, const int* in_sizes, int n_in,
                              void* d_out, int out_size, void* d_ws, size_t ws_size,
                              hipStream_t stream) {
  const float* x   = (const float*)d_in[0];
  const float* w1  = (const float*)d_in[1];
  const float* w2  = (const float*)d_in[2];
  const float* w3  = (const float*)d_in[3];
  const float* w4  = (const float*)d_in[4];
  const float* w5  = (const float*)d_in[5];
  const float* bn1 = (const float*)d_in[6];
  const float* bn2 = (const float*)d_in[7];
  const float* bn3 = (const float*)d_in[8];
  const float* bn4 = (const float*)d_in[9];
  const float* bn5 = (const float*)d_in[10];
  const float* bn6 = (const float*)d_in[11];
  const float* bn7 = (const float*)d_in[12];
  const float* l1w = (const float*)d_in[13];
  const float* l2w = (const float*)d_in[14];
  const float* l2b = (const float*)d_in[15];
  const float* l3w = (const float*)d_in[16];
  const float* l3b = (const float*)d_in[17];
  float* out = (float*)d_out;

  float* ws = (float*)d_ws;
  size_t off = 0;
  float* xt  = ws + off; off += (size_t)BATCH * NPTS * 3;
  float* xx  = ws + off; off += (size_t)BATCH * NPTS;
  float* W2f1 = ws + off; off += 384;
  unsigned short* W2H2 = (unsigned short*)(ws + off); off += 8192 / 2;
  unsigned short* W2L2 = (unsigned short*)(ws + off); off += 8192 / 2;
  unsigned short* W2H3 = (unsigned short*)(ws + off); off += 16384 / 2;
  unsigned short* W2L3 = (unsigned short*)(ws + off); off += 16384 / 2;
  unsigned short* W2H4 = (unsigned short*)(ws + off); off += 65536 / 2;
  unsigned short* W2L4 = (unsigned short*)(ws + off); off += 65536 / 2;
  unsigned short* w5H = (unsigned short*)(ws + off); off += (size_t)1024 * 512 / 2;
  unsigned short* w5L = (unsigned short*)(ws + off); off += (size_t)1024 * 512 / 2;
  float* Ab  = ws + off; off += (size_t)BATCH * NPTS * 256;
  float* Bb  = ws + off; off += (size_t)BATCH * NPTS * 256;
  unsigned short* catH = (unsigned short*)(ws + off); off += (size_t)BATCH * NPTS * 512 / 2;
  unsigned short* catL = (unsigned short*)(ws + off); off += (size_t)BATCH * NPTS * 512 / 2;
  float* pd  = ws + off; off += (size_t)BATCH * NPTS * NPTS;
  float* pmax = ws + off; off += (size_t)128 * 1024;
  float* psum = ws + off; off += (size_t)128 * 1024;
  float* pooled = ws + off; off += (size_t)BATCH * 2048;
  float* f1  = ws + off; off += (size_t)BATCH * 512;
  float* f2  = ws + off; off += (size_t)BATCH * 256;
  int* idx = (int*)(ws + off);

  prep_all<<<2225, 256, 0, stream>>>(w1, w2, w3, w4, w5, W2f1,
                                     W2H2, W2L2, W2H3, W2L3, W2H4, W2L4, w5H, w5L);
  transpose_x<<<(BATCH * NPTS * 3 + 255) / 256, 256, 0, stream>>>(x, xt);

  // ---------------- stage 1 (K=3): fused pd+topk, then f32 GEMM + gather
  knn3_topk<<<1024, 256, 0, stream>>>(xt, idx);
  gemm_ab_f32<<<dim3(2, (BATCH * NPTS) / 64), 256, 0, stream>>>(xt, W2f1, Ab, Bb, 3, 64);
  gather_max_bn<64, 1><<<1024, 256, 0, stream>>>(Ab, Bb, idx, bn1, catH, catL, xx, 0);

  // ---------------- stage 2 (C=64 -> O=64)
  gram_mfma<<<576, 256, 0, stream>>>(catH + 0, catL + 0, 512, 64, xx, pd);
  topk20<<<(BATCH * NPTS) / 4, 256, 0, stream>>>(pd, idx);
  mfma_gemm<1, 64><<<dim3(1, (BATCH * NPTS) / 64), 256, 0, stream>>>(
      catH + 0, catL + 0, 512, W2H2, W2L2, 64, 64, 128, nullptr, Ab, Bb);
  gather_max_bn<64, 1><<<1024, 256, 0, stream>>>(Ab, Bb, idx, bn2, catH, catL, xx, 64);

  // ---------------- stage 3 (C=64 -> O=128)
  gram_mfma<<<576, 256, 0, stream>>>(catH + 64, catL + 64, 512, 64, xx, pd);
  topk20<<<(BATCH * NPTS) / 4, 256, 0, stream>>>(pd, idx);
  mfma_gemm<1, 64><<<dim3(2, (BATCH * NPTS) / 64), 256, 0, stream>>>(
      catH + 64, catL + 64, 512, W2H3, W2L3, 64, 64, 256, nullptr, Ab, Bb);
  gather_max_bn<128, 1><<<2048, 256, 0, stream>>>(Ab, Bb, idx, bn3, catH, catL, xx, 128);

  // ---------------- stage 4 (C=128 -> O=256)
  gram_mfma<<<576, 256, 0, stream>>>(catH + 128, catL + 128, 512, 128, xx, pd);
  topk20<<<(BATCH * NPTS) / 4, 256, 0, stream>>>(pd, idx);
  mfma_gemm<1, 128><<<dim3(4, (BATCH * NPTS) / 128), 256, 0, stream>>>(
      catH + 128, catL + 128, 512, W2H4, W2L4, 128, 128, 512, nullptr, Ab, Bb);
  gather_max_bn<256, 0><<<4096, 256, 0, stream>>>(Ab, Bb, idx, bn4, catH, catL, nullptr, 256);

  // ---------------- w5 GEMM + BN5 + LReLU + fused max/mean pool
  mfma_gemm<2, 128><<<dim3(8, (BATCH * NPTS) / 128), 256, 0, stream>>>(
      catH, catL, 512, w5H, w5L, 512, 512, 1024, bn5, pmax, psum);
  reduce_pool<<<dim3(4, BATCH), 256, 0, stream>>>(pmax, psum, pooled);

  fc_kernel<<<(BATCH * 512 * 64) / 256, 256, 0, stream>>>(pooled, l1w, nullptr, bn6, f1, 2048, 512, 1);
  fc_kernel<<<(BATCH * 256 * 64) / 256, 256, 0, stream>>>(f1, l2w, l2b, bn7, f2, 512, 256, 1);
  fc_kernel<<<(BATCH * 40 * 64 + 255) / 256, 256, 0, stream>>>(f2, l3w, l3b, nullptr, out, 256, 40, 0);
}